// Round 4
// baseline (407.481 us; speedup 1.0000x reference)
//
#include <hip/hip_runtime.h>
#include <cmath>

constexpr int IN_F  = 256;

typedef short bf16x8 __attribute__((ext_vector_type(8)));
typedef short short4v __attribute__((ext_vector_type(4)));
typedef float f32x4 __attribute__((ext_vector_type(4)));

__device__ __forceinline__ short f2bf(float f) {
    unsigned u = __float_as_uint(f);
    unsigned r = (u + 0x7FFFu + ((u >> 16) & 1)) >> 16;  // RNE
    return (short)r;
}

// ---------------- fp32 -> bf16 flat conversion (vectorized) ----------------
__global__ void cvt_bf16(const float4* __restrict__ x, short4v* __restrict__ y, int n4)
{
    int i = blockIdx.x * blockDim.x + threadIdx.x;
    if (i < n4) {
        float4 v = x[i];
        short4v o;
        o[0] = f2bf(v.x); o[1] = f2bf(v.y); o[2] = f2bf(v.z); o[3] = f2bf(v.w);
        y[i] = o;
    }
}

// ---------------- fp32 W[K,N] -> bf16 Wt[N,K] (transpose) ----------------
__global__ __launch_bounds__(256) void cvt_t_bf16(
    const float* __restrict__ W, short* __restrict__ Wt, int K, int N)
{
    __shared__ float tile[32][33];
    int bk = blockIdx.y * 32, bn = blockIdx.x * 32;
    int tx = threadIdx.x & 31, ty = threadIdx.x >> 5;  // ty 0..7
#pragma unroll
    for (int i = ty; i < 32; i += 8) tile[i][tx] = W[(size_t)(bk + i) * N + bn + tx];
    __syncthreads();
#pragma unroll
    for (int i = ty; i < 32; i += 8)
        Wt[(size_t)(bn + i) * K + bk + tx] = f2bf(tile[tx][i]);
}

// ---------------- bf16 MFMA GEMM: A[M,K] x Bt[N,K]^T -> C[M,N] fp32 ----------------
// M%128==0, N%128==0, K%32==0. 128x128 tile, 4 waves (2x2 of 64x64), BK=32.
__global__ __launch_bounds__(256) void gemm_bf16(
    const short* __restrict__ A, const short* __restrict__ Bt,
    const float* __restrict__ bias, float* __restrict__ C,
    int M, int N, int K)
{
    __shared__ short sA[128 * 32];
    __shared__ short sB[128 * 32];
    const int tid  = threadIdx.x;
    const int wave = tid >> 6, lane = tid & 63;
    const int wm = wave >> 1, wn = wave & 1;
    const int m0 = blockIdx.y * 128, n0 = blockIdx.x * 128;

    const int srow = tid >> 2;          // 0..63 (tile row within 64-row half)
    const int scol = (tid & 3) * 8;     // element offset within K-tile

    const int fr = lane & 15;           // fragment row/col within 16
    const int fq = lane >> 4;           // k-quarter

    f32x4 acc[4][4] = {};

    for (int k0 = 0; k0 < K; k0 += 32) {
        const short* ga0 = A  + (size_t)(m0 + srow) * K + k0 + scol;
        const short* ga1 = A  + (size_t)(m0 + 64 + srow) * K + k0 + scol;
        const short* gb0 = Bt + (size_t)(n0 + srow) * K + k0 + scol;
        const short* gb1 = Bt + (size_t)(n0 + 64 + srow) * K + k0 + scol;
        // each wave-call moves 1024B: LDS base = wave*512 shorts (+2048 for second half)
        __builtin_amdgcn_global_load_lds((const __attribute__((address_space(1))) void*)ga0,
            (__attribute__((address_space(3))) void*)(sA + wave * 512), 16, 0, 0);
        __builtin_amdgcn_global_load_lds((const __attribute__((address_space(1))) void*)ga1,
            (__attribute__((address_space(3))) void*)(sA + 2048 + wave * 512), 16, 0, 0);
        __builtin_amdgcn_global_load_lds((const __attribute__((address_space(1))) void*)gb0,
            (__attribute__((address_space(3))) void*)(sB + wave * 512), 16, 0, 0);
        __builtin_amdgcn_global_load_lds((const __attribute__((address_space(1))) void*)gb1,
            (__attribute__((address_space(3))) void*)(sB + 2048 + wave * 512), 16, 0, 0);
        __syncthreads();

        bf16x8 af[4], bfr[4];
#pragma unroll
        for (int m = 0; m < 4; m++)
            af[m] = *(const bf16x8*)(sA + (wm * 64 + m * 16 + fr) * 32 + fq * 8);
#pragma unroll
        for (int n = 0; n < 4; n++)
            bfr[n] = *(const bf16x8*)(sB + (wn * 64 + n * 16 + fr) * 32 + fq * 8);
#pragma unroll
        for (int m = 0; m < 4; m++)
#pragma unroll
            for (int n = 0; n < 4; n++)
                acc[m][n] = __builtin_amdgcn_mfma_f32_16x16x32_bf16(af[m], bfr[n], acc[m][n], 0, 0, 0);
        __syncthreads();
    }

#pragma unroll
    for (int n = 0; n < 4; n++) {
        int gcol = n0 + wn * 64 + n * 16 + fr;
        float bv = bias ? bias[gcol] : 0.f;
#pragma unroll
        for (int m = 0; m < 4; m++) {
#pragma unroll
            for (int j = 0; j < 4; j++) {
                int grow = m0 + wm * 64 + m * 16 + fq * 4 + j;
                C[(size_t)grow * N + gcol] = acc[m][n][j] + bv;
            }
        }
    }
}

// ---------------- GEMM (fp32, 64x64 tile, bounds-checked) — final layer only ----------------
__global__ __launch_bounds__(256) void gemm_f32(
    const float* __restrict__ A, const float* __restrict__ B,
    const float* __restrict__ bias, float* __restrict__ C,
    int M, int N, int K)
{
    const int TS = 64, KS = 16;
    __shared__ float sA[64][17];
    __shared__ float sB[16][64];
    int tid = threadIdx.x;
    int tx = tid & 15, ty = tid >> 4;
    int m0 = blockIdx.y * TS, n0 = blockIdx.x * TS;
    float acc[4][4] = {};
    for (int k0 = 0; k0 < K; k0 += KS) {
#pragma unroll
        for (int i = 0; i < 4; i++) {
            int idx = tid + i * 256;
            int mm = idx >> 4, kk = idx & 15;
            int gm = m0 + mm, gk = k0 + kk;
            sA[mm][kk] = (gm < M && gk < K) ? A[(size_t)gm * K + gk] : 0.f;
        }
#pragma unroll
        for (int i = 0; i < 4; i++) {
            int idx = tid + i * 256;
            int kk = idx >> 6, nn = idx & 63;
            int gk = k0 + kk, gn = n0 + nn;
            sB[kk][nn] = (gk < K && gn < N) ? B[(size_t)gk * N + gn] : 0.f;
        }
        __syncthreads();
#pragma unroll
        for (int kk = 0; kk < KS; kk++) {
            float ra[4], rb[4];
#pragma unroll
            for (int i = 0; i < 4; i++) ra[i] = sA[ty * 4 + i][kk];
#pragma unroll
            for (int j = 0; j < 4; j++) rb[j] = sB[kk][tx * 4 + j];
#pragma unroll
            for (int i = 0; i < 4; i++)
#pragma unroll
                for (int j = 0; j < 4; j++) acc[i][j] = fmaf(ra[i], rb[j], acc[i][j]);
        }
        __syncthreads();
    }
#pragma unroll
    for (int i = 0; i < 4; i++) {
        int gm = m0 + ty * 4 + i;
        if (gm >= M) continue;
#pragma unroll
        for (int j = 0; j < 4; j++) {
            int gn = n0 + tx * 4 + j;
            if (gn >= N) continue;
            float v = acc[i][j];
            if (bias) v += bias[gn];
            C[(size_t)gm * N + gn] = v;
        }
    }
}

// ---------------- el/er: layer 1 (C=4 heads, 512-dot per head) ----------------
__global__ __launch_bounds__(256) void el_er_1(
    const float* __restrict__ z, const float* __restrict__ al, const float* __restrict__ ar,
    float* __restrict__ el, float* __restrict__ er)
{
    int n = blockIdx.x;
    int wave = threadIdx.x >> 6, lane = threadIdx.x & 63;  // wave = head
    const float* zp  = z  + (size_t)n * 2048 + wave * 512;
    const float* alp = al + wave * 512;
    const float* arp = ar + wave * 512;
    float sl = 0.f, sr = 0.f;
    for (int k = lane; k < 512; k += 64) {
        float zv = zp[k];
        sl = fmaf(zv, alp[k], sl);
        sr = fmaf(zv, arp[k], sr);
    }
#pragma unroll
    for (int o = 32; o; o >>= 1) { sl += __shfl_down(sl, o); sr += __shfl_down(sr, o); }
    if (lane == 0) { el[n * 4 + wave] = sl; er[n * 4 + wave] = sr; }
}

// ---------------- el/er: layer 2 (C=16 = (p,h), 32-dot each) ----------------
__global__ void el_er_2(
    const float* __restrict__ z2, const float* __restrict__ al2, const float* __restrict__ ar2,
    float* __restrict__ el, float* __restrict__ er, int N)
{
    int idx = blockIdx.x * blockDim.x + threadIdx.x;  // N*16
    if (idx >= N * 16) return;
    int n = idx >> 4, c = idx & 15;
    int p = c >> 2, h = c & 3;
    const float* zp  = z2 + (size_t)n * 512 + p * 128 + h * 32;
    const float* alp = al2 + h * 32;
    const float* arp = ar2 + h * 32;
    float sl = 0.f, sr = 0.f;
#pragma unroll
    for (int k = 0; k < 32; k++) {
        float zv = zp[k];
        sl = fmaf(zv, alp[k], sl);
        sr = fmaf(zv, arp[k], sr);
    }
    el[idx] = sl;
    er[idx] = sr;
}

// ---------------- edge softmax helpers ----------------
__device__ __forceinline__ unsigned f2ord(float f) {
    unsigned u = __float_as_uint(f);
    return (u & 0x80000000u) ? ~u : (u | 0x80000000u);
}
__device__ __forceinline__ float ord2f(unsigned o) {
    unsigned u = (o & 0x80000000u) ? (o & 0x7FFFFFFFu) : ~o;
    return __uint_as_float(u);
}

template <int C>
__global__ void edge_logits(const int* __restrict__ src, const int* __restrict__ dst,
                            const float* __restrict__ el, const float* __restrict__ er,
                            float* __restrict__ ebuf, unsigned* __restrict__ emax, int E)
{
    int idx = blockIdx.x * blockDim.x + threadIdx.x;
    if (idx >= E * C) return;
    int e = idx / C, c = idx % C;
    float v = el[src[e] * C + c] + er[dst[e] * C + c];
    v = v > 0.f ? v : 0.2f * v;   // leaky_relu, slope 0.2
    ebuf[idx] = v;
    atomicMax(&emax[dst[e] * C + c], f2ord(v));
}

__global__ void finalize_max(const unsigned* __restrict__ emo, float* __restrict__ emf, int NC)
{
    int i = blockIdx.x * blockDim.x + threadIdx.x;
    if (i < NC) {
        float v = ord2f(emo[i]);
        emf[i] = isfinite(v) ? v : 0.f;
    }
}

template <int C>
__global__ void edge_exp(const int* __restrict__ dst, float* __restrict__ ebuf,
                         const float* __restrict__ emf, float* __restrict__ denom, int E)
{
    int idx = blockIdx.x * blockDim.x + threadIdx.x;
    if (idx >= E * C) return;
    int e = idx / C, c = idx % C;
    int d = dst[e];
    float ex = expf(ebuf[idx] - emf[d * C + c]);
    ebuf[idx] = ex;
    atomicAdd(&denom[d * C + c], ex);
}

// ---------------- CSR build (by dst) ----------------
__global__ void hist_kernel(const int* __restrict__ dst, int* __restrict__ deg, int E)
{
    int e = blockIdx.x * blockDim.x + threadIdx.x;
    if (e < E) atomicAdd(&deg[dst[e]], 1);
}

__global__ __launch_bounds__(1024) void scan_excl(const int* __restrict__ deg,
                                                  int* __restrict__ off, int N)
{
    __shared__ int part[1024];
    int t = threadIdx.x;
    int chunk = N >> 10;
    int base = t * chunk;
    int local[16];
    int s = 0;
    for (int i = 0; i < chunk; i++) { local[i] = s; s += deg[base + i]; }
    part[t] = s;
    __syncthreads();
    for (int o = 1; o < 1024; o <<= 1) {
        int v = (t >= o) ? part[t - o] : 0;
        __syncthreads();
        part[t] += v;
        __syncthreads();
    }
    int pre = (t == 0) ? 0 : part[t - 1];
    for (int i = 0; i < chunk; i++) off[base + i] = pre + local[i];
    if (t == 1023) off[N] = pre + s;
}

__global__ void scatter_kernel(const int* __restrict__ dst, const int* __restrict__ off,
                               int* __restrict__ cur, int* __restrict__ eid, int E)
{
    int e = blockIdx.x * blockDim.x + threadIdx.x;
    if (e < E) {
        int d = dst[e];
        int p = off[d] + atomicAdd(&cur[d], 1);
        eid[p] = e;
    }
}

// ---------------- aggregation: layer 1 (2048 f32 per node) ----------------
__global__ __launch_bounds__(256) void aggregate1(
    const int* __restrict__ off, const int* __restrict__ eid, const int* __restrict__ src,
    const float* __restrict__ ex, const float* __restrict__ denom,
    const float* __restrict__ z, float* __restrict__ acc)
{
    int n = blockIdx.x, t = threadIdx.x;
    float r[8] = {};
    int beg = off[n], end = off[n + 1];
    for (int j = beg; j < end; ++j) {
        int e = eid[j];
        const float* zs = z + (size_t)src[e] * 2048;
        float ah[4] = { ex[e * 4 + 0], ex[e * 4 + 1], ex[e * 4 + 2], ex[e * 4 + 3] };
#pragma unroll
        for (int i = 0; i < 8; ++i) {
            int col = i * 256 + t;
            r[i] = fmaf(ah[i >> 1], zs[col], r[i]);
        }
    }
#pragma unroll
    for (int i = 0; i < 8; ++i) {
        int col = i * 256 + t;
        float dn = denom[n * 4 + (i >> 1)];
        if (dn == 0.f) dn = 1.f;
        size_t o = (size_t)n * 2048 + col;
        float v = r[i] / dn + acc[o];
        acc[o] = v > 0.f ? v : 0.f;
    }
}

// ---------------- aggregation: layer 2 (512 f32 per node, C=16) ----------------
__global__ __launch_bounds__(256) void aggregate2(
    const int* __restrict__ off, const int* __restrict__ eid, const int* __restrict__ src,
    const float* __restrict__ ex, const float* __restrict__ denom,
    const float* __restrict__ z, float* __restrict__ acc)
{
    int n = blockIdx.x, t = threadIdx.x;
    float r[2] = {};
    int beg = off[n], end = off[n + 1];
    for (int j = beg; j < end; ++j) {
        int e = eid[j];
        const float* zs = z + (size_t)src[e] * 512;
#pragma unroll
        for (int i = 0; i < 2; ++i) {
            int col = i * 256 + t;
            r[i] = fmaf(ex[e * 16 + (col >> 5)], zs[col], r[i]);
        }
    }
#pragma unroll
    for (int i = 0; i < 2; ++i) {
        int col = i * 256 + t;
        float dn = denom[n * 16 + (col >> 5)];
        if (dn == 0.f) dn = 1.f;
        size_t o = (size_t)n * 512 + col;
        float v = r[i] / dn + acc[o];
        acc[o] = v > 0.f ? v : 0.f;
    }
}

// ---------------- launch ----------------
extern "C" void kernel_launch(void* const* d_in, const int* in_sizes, int n_in,
                              void* d_out, int out_size, void* d_ws, size_t ws_size,
                              hipStream_t stream)
{
    const float* feat  = (const float*)d_in[0];
    const int*   src   = (const int*)d_in[1];
    const int*   dst   = (const int*)d_in[2];
    const float* W1    = (const float*)d_in[3];
    const float* al1   = (const float*)d_in[4];
    const float* ar1   = (const float*)d_in[5];
    const float* resW1 = (const float*)d_in[6];
    const float* b1    = (const float*)d_in[7];
    const float* W2    = (const float*)d_in[8];
    const float* al2   = (const float*)d_in[9];
    const float* ar2   = (const float*)d_in[10];
    const float* resW2 = (const float*)d_in[11];
    const float* b2    = (const float*)d_in[12];
    const float* Wout  = (const float*)d_in[13];
    const float* bout  = (const float*)d_in[14];
    const int N = in_sizes[0] / IN_F;  // 8192
    const int E = in_sizes[1];         // 65536

    // ---- workspace layout ----
    char* w = (char*)d_ws;
    auto alloc = [&](size_t bytes) -> char* {
        char* p = w;
        w += (bytes + 255) & ~(size_t)255;
        return p;
    };
    float*    z1      = (float*)alloc((size_t)N * 2048 * 4);  // region A (64 MB)
    float*    acc1    = (float*)alloc((size_t)N * 2048 * 4);  // region B (64 MB)
    float*    el1     = (float*)alloc((size_t)N * 4 * 4);
    float*    er1     = (float*)alloc((size_t)N * 4 * 4);
    unsigned* emax1o  = (unsigned*)alloc((size_t)N * 4 * 4);
    float*    emax1f  = (float*)alloc((size_t)N * 4 * 4);
    float*    denom1  = (float*)alloc((size_t)N * 4 * 4);
    float*    e1      = (float*)alloc((size_t)E * 4 * 4);
    int*      deg     = (int*)alloc((size_t)N * 4);
    int*      off     = (int*)alloc((size_t)(N + 1) * 4);
    int*      cur     = (int*)alloc((size_t)N * 4);
    int*      eid     = (int*)alloc((size_t)E * 4);
    short*    featb   = (short*)alloc((size_t)N * 256 * 2);   // 4 MB
    short*    W1t     = (short*)alloc((size_t)2048 * 256 * 2);
    short*    resW1t  = (short*)alloc((size_t)2048 * 256 * 2);
    short*    W2t     = (short*)alloc((size_t)128 * 512 * 2);
    short*    resW2t  = (short*)alloc((size_t)128 * 512 * 2);

    // region A alias: h1b (written after z1 is dead)
    short* h1b = (short*)z1;                                  // 32 MB < 64 MB
    // region B alias: layer-2 buffers (acc1/h1-fp32 dead after cvt to h1b)
    char* w2 = (char*)acc1;
    auto alloc2 = [&](size_t bytes) -> char* {
        char* p = w2;
        w2 += (bytes + 255) & ~(size_t)255;
        return p;
    };
    float*    z2     = (float*)alloc2((size_t)N * 512 * 4);   // 16 MB
    float*    acc2   = (float*)alloc2((size_t)N * 512 * 4);   // 16 MB
    float*    el2    = (float*)alloc2((size_t)N * 16 * 4);
    float*    er2    = (float*)alloc2((size_t)N * 16 * 4);
    unsigned* emax2o = (unsigned*)alloc2((size_t)N * 16 * 4);
    float*    emax2f = (float*)alloc2((size_t)N * 16 * 4);
    float*    denom2 = (float*)alloc2((size_t)N * 16 * 4);
    float*    e2     = (float*)alloc2((size_t)E * 16 * 4);    // 4 MB (total ~39 MB < 64 MB)

    dim3 blk(256);

    // ===== CSR build =====
    hipMemsetAsync(deg, 0, (size_t)N * 4, stream);
    hipMemsetAsync(cur, 0, (size_t)N * 4, stream);
    hist_kernel<<<dim3((E + 255) / 256), blk, 0, stream>>>(dst, deg, E);
    scan_excl<<<dim3(1), dim3(1024), 0, stream>>>(deg, off, N);
    scatter_kernel<<<dim3((E + 255) / 256), blk, 0, stream>>>(dst, off, cur, eid, E);

    // ===== weight/feature conversion to bf16 (weights transposed to [N,K]) =====
    cvt_bf16<<<dim3((N * 256 / 4 + 255) / 256), blk, 0, stream>>>((const float4*)feat, (short4v*)featb, N * 256 / 4);
    cvt_t_bf16<<<dim3(2048 / 32, 256 / 32), blk, 0, stream>>>(W1, W1t, 256, 2048);
    cvt_t_bf16<<<dim3(2048 / 32, 256 / 32), blk, 0, stream>>>(resW1, resW1t, 256, 2048);
    cvt_t_bf16<<<dim3(128 / 32, 512 / 32), blk, 0, stream>>>(W2, W2t, 512, 128);
    cvt_t_bf16<<<dim3(128 / 32, 512 / 32), blk, 0, stream>>>(resW2, resW2t, 512, 128);

    // ===== layer 1 (MFMA) =====
    gemm_bf16<<<dim3(2048 / 128, N / 128), blk, 0, stream>>>(featb, W1t, nullptr, z1, N, 2048, 256);
    gemm_bf16<<<dim3(2048 / 128, N / 128), blk, 0, stream>>>(featb, resW1t, b1, acc1, N, 2048, 256);
    el_er_1<<<dim3(N), blk, 0, stream>>>(z1, al1, ar1, el1, er1);

    hipMemsetAsync(emax1o, 0, (size_t)N * 4 * 4, stream);
    hipMemsetAsync(denom1, 0, (size_t)N * 4 * 4, stream);
    edge_logits<4><<<dim3((E * 4 + 255) / 256), blk, 0, stream>>>(src, dst, el1, er1, e1, emax1o, E);
    finalize_max<<<dim3((N * 4 + 255) / 256), blk, 0, stream>>>(emax1o, emax1f, N * 4);
    edge_exp<4><<<dim3((E * 4 + 255) / 256), blk, 0, stream>>>(dst, e1, emax1f, denom1, E);
    aggregate1<<<dim3(N), blk, 0, stream>>>(off, eid, src, e1, denom1, z1, acc1);
    // acc1 = h1 fp32 ; z1 dead

    // h1 -> bf16 (into region A)
    cvt_bf16<<<dim3((N * 2048 / 4 + 255) / 256), blk, 0, stream>>>((const float4*)acc1, (short4v*)h1b, N * 2048 / 4);
    // acc1 (fp32 h1) now dead -> region B reused for layer-2 buffers

    // ===== layer 2 (MFMA) =====
    gemm_bf16<<<dim3(128 / 128, (N * 4) / 128), blk, 0, stream>>>(h1b, W2t, nullptr, z2, N * 4, 128, 512);
    gemm_bf16<<<dim3(128 / 128, (N * 4) / 128), blk, 0, stream>>>(h1b, resW2t, b2, acc2, N * 4, 128, 512);
    el_er_2<<<dim3((N * 16 + 255) / 256), blk, 0, stream>>>(z2, al2, ar2, el2, er2, N);

    hipMemsetAsync(emax2o, 0, (size_t)N * 16 * 4, stream);
    hipMemsetAsync(denom2, 0, (size_t)N * 16 * 4, stream);
    edge_logits<16><<<dim3((E * 16 + 255) / 256), blk, 0, stream>>>(src, dst, el2, er2, e2, emax2o, E);
    finalize_max<<<dim3((N * 16 + 255) / 256), blk, 0, stream>>>(emax2o, emax2f, N * 16);
    edge_exp<16><<<dim3((E * 16 + 255) / 256), blk, 0, stream>>>(dst, e2, emax2f, denom2, E);
    aggregate2<<<dim3(N), blk, 0, stream>>>(off, eid, src, e2, denom2, z2, acc2);
    // acc2 = h2 fp32

    // ===== final linear (fp32): out = h2 @ Wout + bout =====
    gemm_f32<<<dim3(1, N / 64), blk, 0, stream>>>(acc2, Wout, bout, (float*)d_out, N, 40, 512);
}

// Round 5
// 382.565 us; speedup vs baseline: 1.0651x; 1.0651x over previous
//
#include <hip/hip_runtime.h>
#include <cmath>

constexpr int IN_F  = 256;

typedef short bf16x8 __attribute__((ext_vector_type(8)));
typedef short short4v __attribute__((ext_vector_type(4)));
typedef float f32x4 __attribute__((ext_vector_type(4)));

__device__ __forceinline__ short f2bf(float f) {
    unsigned u = __float_as_uint(f);
    unsigned r = (u + 0x7FFFu + ((u >> 16) & 1)) >> 16;  // RNE
    return (short)r;
}
__device__ __forceinline__ float b2f(short s) {
    return __uint_as_float(((unsigned)(unsigned short)s) << 16);
}
__device__ __forceinline__ float ldx(const float* p, size_t i) { return p[i]; }
__device__ __forceinline__ float ldx(const short* p, size_t i) { return b2f(p[i]); }

// ---------------- fp32 -> bf16 flat conversion (vectorized) ----------------
__global__ void cvt_bf16(const float4* __restrict__ x, short4v* __restrict__ y, int n4)
{
    int i = blockIdx.x * blockDim.x + threadIdx.x;
    if (i < n4) {
        float4 v = x[i];
        short4v o;
        o[0] = f2bf(v.x); o[1] = f2bf(v.y); o[2] = f2bf(v.z); o[3] = f2bf(v.w);
        y[i] = o;
    }
}

// ------- fp32 W[K,N] -> bf16 Wt[Np,K] transpose, zero-pad cols N..Np -------
__global__ __launch_bounds__(256) void cvt_t_bf16(
    const float* __restrict__ W, short* __restrict__ Wt, int K, int N, int Np)
{
    __shared__ float tile[32][33];
    int bk = blockIdx.y * 32, bn = blockIdx.x * 32;
    int tx = threadIdx.x & 31, ty = threadIdx.x >> 5;  // ty 0..7
#pragma unroll
    for (int i = ty; i < 32; i += 8) {
        int gn = bn + tx;
        tile[i][tx] = (gn < N) ? W[(size_t)(bk + i) * N + gn] : 0.f;
    }
    __syncthreads();
#pragma unroll
    for (int i = ty; i < 32; i += 8)
        Wt[(size_t)(bn + i) * K + bk + tx] = f2bf(tile[tx][i]);
}

// ------- fold attention vectors through W: wal[k,h] = sum_j W[k,h*klen+j]*al[h*klen+j] -------
__global__ void fold_aw(const float* __restrict__ W, const float* __restrict__ al,
                        const float* __restrict__ ar, float* __restrict__ wal,
                        float* __restrict__ war, int K, int klen)
{
    int idx = blockIdx.x * blockDim.x + threadIdx.x;
    if (idx >= K * 4) return;
    int k = idx >> 2, h = idx & 3;
    const float* wr = W + (size_t)k * (4 * klen) + h * klen;
    const float* alp = al + h * klen;
    const float* arp = ar + h * klen;
    float sl = 0.f, sr = 0.f;
    for (int j = 0; j < klen; j++) { sl = fmaf(wr[j], alp[j], sl); sr = fmaf(wr[j], arp[j], sr); }
    wal[idx] = sl;
    war[idx] = sr;
}

// ------- el/er = X @ wal / X @ war  (one wave per row, 4 heads) -------
template <typename T>
__global__ __launch_bounds__(256) void el_er_fold(
    const T* __restrict__ X, const float4* __restrict__ wal, const float4* __restrict__ war,
    float* __restrict__ el, float* __restrict__ er, int Kdim)
{
    int row  = blockIdx.x * 4 + (threadIdx.x >> 6);
    int lane = threadIdx.x & 63;
    float sl[4] = {}, sr[4] = {};
    for (int k = lane; k < Kdim; k += 64) {
        float f = ldx(X, (size_t)row * Kdim + k);
        float4 wl = wal[k], wr = war[k];
        sl[0] = fmaf(f, wl.x, sl[0]); sl[1] = fmaf(f, wl.y, sl[1]);
        sl[2] = fmaf(f, wl.z, sl[2]); sl[3] = fmaf(f, wl.w, sl[3]);
        sr[0] = fmaf(f, wr.x, sr[0]); sr[1] = fmaf(f, wr.y, sr[1]);
        sr[2] = fmaf(f, wr.z, sr[2]); sr[3] = fmaf(f, wr.w, sr[3]);
    }
#pragma unroll
    for (int o = 32; o; o >>= 1) {
#pragma unroll
        for (int h = 0; h < 4; h++) { sl[h] += __shfl_down(sl[h], o); sr[h] += __shfl_down(sr[h], o); }
    }
    if (lane == 0) {
#pragma unroll
        for (int h = 0; h < 4; h++) { el[row * 4 + h] = sl[h]; er[row * 4 + h] = sr[h]; }
    }
}

// ---------------- bf16 MFMA GEMM: A[M,K] x Bt[N,K]^T -> C[M,*] ----------------
// M%128==0, N%128==0 (padded), K%32==0. 128x128 tile, 4 waves, BK=32.
// C dtype: out_bf16 ? bf16 : fp32 ; row stride ldc ; cols written: [0,nmax)
__global__ __launch_bounds__(256) void gemm_bf16(
    const short* __restrict__ A, const short* __restrict__ Bt,
    const float* __restrict__ bias, void* __restrict__ C,
    int M, int N, int K, int ldc, int nmax, int out_bf16)
{
    __shared__ short sA[128 * 32];
    __shared__ short sB[128 * 32];
    const int tid  = threadIdx.x;
    const int wave = tid >> 6, lane = tid & 63;
    const int wm = wave >> 1, wn = wave & 1;
    const int m0 = blockIdx.y * 128, n0 = blockIdx.x * 128;

    const int srow = tid >> 2;
    const int scol = (tid & 3) * 8;

    const int fr = lane & 15;
    const int fq = lane >> 4;

    f32x4 acc[4][4] = {};

    for (int k0 = 0; k0 < K; k0 += 32) {
        const short* ga0 = A  + (size_t)(m0 + srow) * K + k0 + scol;
        const short* ga1 = A  + (size_t)(m0 + 64 + srow) * K + k0 + scol;
        const short* gb0 = Bt + (size_t)(n0 + srow) * K + k0 + scol;
        const short* gb1 = Bt + (size_t)(n0 + 64 + srow) * K + k0 + scol;
        __builtin_amdgcn_global_load_lds((const __attribute__((address_space(1))) void*)ga0,
            (__attribute__((address_space(3))) void*)(sA + wave * 512), 16, 0, 0);
        __builtin_amdgcn_global_load_lds((const __attribute__((address_space(1))) void*)ga1,
            (__attribute__((address_space(3))) void*)(sA + 2048 + wave * 512), 16, 0, 0);
        __builtin_amdgcn_global_load_lds((const __attribute__((address_space(1))) void*)gb0,
            (__attribute__((address_space(3))) void*)(sB + wave * 512), 16, 0, 0);
        __builtin_amdgcn_global_load_lds((const __attribute__((address_space(1))) void*)gb1,
            (__attribute__((address_space(3))) void*)(sB + 2048 + wave * 512), 16, 0, 0);
        __syncthreads();

        bf16x8 af[4], bfr[4];
#pragma unroll
        for (int m = 0; m < 4; m++)
            af[m] = *(const bf16x8*)(sA + (wm * 64 + m * 16 + fr) * 32 + fq * 8);
#pragma unroll
        for (int n = 0; n < 4; n++)
            bfr[n] = *(const bf16x8*)(sB + (wn * 64 + n * 16 + fr) * 32 + fq * 8);
#pragma unroll
        for (int m = 0; m < 4; m++)
#pragma unroll
            for (int n = 0; n < 4; n++)
                acc[m][n] = __builtin_amdgcn_mfma_f32_16x16x32_bf16(af[m], bfr[n], acc[m][n], 0, 0, 0);
        __syncthreads();
    }

#pragma unroll
    for (int n = 0; n < 4; n++) {
        int gcol = n0 + wn * 64 + n * 16 + fr;
        if (gcol >= nmax) continue;
        float bv = bias ? bias[gcol] : 0.f;
#pragma unroll
        for (int m = 0; m < 4; m++) {
#pragma unroll
            for (int j = 0; j < 4; j++) {
                int grow = m0 + wm * 64 + m * 16 + fq * 4 + j;
                float v = acc[m][n][j] + bv;
                if (out_bf16) ((short*)C)[(size_t)grow * ldc + gcol] = f2bf(v);
                else          ((float*)C)[(size_t)grow * ldc + gcol] = v;
            }
        }
    }
}

// ---------------- edge softmax helpers ----------------
__device__ __forceinline__ unsigned f2ord(float f) {
    unsigned u = __float_as_uint(f);
    return (u & 0x80000000u) ? ~u : (u | 0x80000000u);
}
__device__ __forceinline__ float ord2f(unsigned o) {
    unsigned u = (o & 0x80000000u) ? (o & 0x7FFFFFFFu) : ~o;
    return __uint_as_float(u);
}

template <int C>
__global__ void edge_logits(const int* __restrict__ src, const int* __restrict__ dst,
                            const float* __restrict__ el, const float* __restrict__ er,
                            float* __restrict__ ebuf, unsigned* __restrict__ emax, int E)
{
    int idx = blockIdx.x * blockDim.x + threadIdx.x;
    if (idx >= E * C) return;
    int e = idx / C, c = idx % C;
    float v = el[src[e] * C + c] + er[dst[e] * C + c];
    v = v > 0.f ? v : 0.2f * v;   // leaky_relu, slope 0.2
    ebuf[idx] = v;
    atomicMax(&emax[dst[e] * C + c], f2ord(v));
}

__global__ void finalize_max(const unsigned* __restrict__ emo, float* __restrict__ emf, int NC)
{
    int i = blockIdx.x * blockDim.x + threadIdx.x;
    if (i < NC) {
        float v = ord2f(emo[i]);
        emf[i] = isfinite(v) ? v : 0.f;
    }
}

template <int C>
__global__ void edge_exp(const int* __restrict__ dst, float* __restrict__ ebuf,
                         const float* __restrict__ emf, float* __restrict__ denom, int E)
{
    int idx = blockIdx.x * blockDim.x + threadIdx.x;
    if (idx >= E * C) return;
    int e = idx / C, c = idx % C;
    int d = dst[e];
    float ex = expf(ebuf[idx] - emf[d * C + c]);
    ebuf[idx] = ex;
    atomicAdd(&denom[d * C + c], ex);
}

// ---------------- CSR build (by dst) ----------------
__global__ void hist_kernel(const int* __restrict__ dst, int* __restrict__ deg, int E)
{
    int e = blockIdx.x * blockDim.x + threadIdx.x;
    if (e < E) atomicAdd(&deg[dst[e]], 1);
}

__global__ __launch_bounds__(1024) void scan_excl(const int* __restrict__ deg,
                                                  int* __restrict__ off, int N)
{
    __shared__ int part[1024];
    int t = threadIdx.x;
    int chunk = N >> 10;
    int base = t * chunk;
    int local[16];
    int s = 0;
    for (int i = 0; i < chunk; i++) { local[i] = s; s += deg[base + i]; }
    part[t] = s;
    __syncthreads();
    for (int o = 1; o < 1024; o <<= 1) {
        int v = (t >= o) ? part[t - o] : 0;
        __syncthreads();
        part[t] += v;
        __syncthreads();
    }
    int pre = (t == 0) ? 0 : part[t - 1];
    for (int i = 0; i < chunk; i++) off[base + i] = pre + local[i];
    if (t == 1023) off[N] = pre + s;
}

__global__ void scatter_kernel(const int* __restrict__ dst, const int* __restrict__ off,
                               int* __restrict__ cur, int* __restrict__ eid, int E)
{
    int e = blockIdx.x * blockDim.x + threadIdx.x;
    if (e < E) {
        int d = dst[e];
        int p = off[d] + atomicAdd(&cur[d], 1);
        eid[p] = e;
    }
}

// ------- aggregation L1: bf16 z gather (16B/thread/edge), bf16 res, bf16 h1 out -------
__global__ __launch_bounds__(256) void aggregate1(
    const int* __restrict__ off, const int* __restrict__ eid, const int* __restrict__ src,
    const float* __restrict__ ex, const float* __restrict__ denom,
    const short* __restrict__ z, const short* __restrict__ res, short* __restrict__ h1)
{
    int n = blockIdx.x, t = threadIdx.x;
    int h = t >> 6;                     // cols [8t,8t+8) all in head t/64
    float r[8] = {};
    int beg = off[n], end = off[n + 1];
    for (int j = beg; j < end; ++j) {
        int e = eid[j];
        bf16x8 zv = *(const bf16x8*)(z + (size_t)src[e] * 2048 + t * 8);
        float a = ex[e * 4 + h];
#pragma unroll
        for (int i = 0; i < 8; ++i) r[i] = fmaf(a, b2f(zv[i]), r[i]);
    }
    float dn = denom[n * 4 + h];
    if (dn == 0.f) dn = 1.f;
    float inv = 1.f / dn;
    bf16x8 rv = *(const bf16x8*)(res + (size_t)n * 2048 + t * 8);
    bf16x8 ov;
#pragma unroll
    for (int i = 0; i < 8; ++i) {
        float v = r[i] * inv + b2f(rv[i]);
        ov[i] = f2bf(v > 0.f ? v : 0.f);
    }
    *(bf16x8*)(h1 + (size_t)n * 2048 + t * 8) = ov;
}

// ------- aggregation L2: bf16 z2 gather (4B/thread/edge), bf16 res2, bf16 h2 out -------
__global__ __launch_bounds__(256) void aggregate2(
    const int* __restrict__ off, const int* __restrict__ eid, const int* __restrict__ src,
    const float* __restrict__ ex, const float* __restrict__ denom,
    const short* __restrict__ z, const short* __restrict__ res, short* __restrict__ h2)
{
    int n = blockIdx.x, t = threadIdx.x;
    int c = t >> 4;                     // cols [2t,2t+2) share channel (2t)>>5
    float r0 = 0.f, r1 = 0.f;
    int beg = off[n], end = off[n + 1];
    for (int j = beg; j < end; ++j) {
        int e = eid[j];
        unsigned zv = *(const unsigned*)(z + (size_t)src[e] * 512 + t * 2);
        float a = ex[e * 16 + c];
        r0 = fmaf(a, b2f((short)(zv & 0xFFFFu)), r0);
        r1 = fmaf(a, b2f((short)(zv >> 16)), r1);
    }
    float dn = denom[n * 16 + c];
    if (dn == 0.f) dn = 1.f;
    float inv = 1.f / dn;
    unsigned rv = *(const unsigned*)(res + (size_t)n * 512 + t * 2);
    float v0 = r0 * inv + b2f((short)(rv & 0xFFFFu));
    float v1 = r1 * inv + b2f((short)(rv >> 16));
    v0 = v0 > 0.f ? v0 : 0.f;
    v1 = v1 > 0.f ? v1 : 0.f;
    unsigned o = ((unsigned)(unsigned short)f2bf(v1) << 16) | (unsigned)(unsigned short)f2bf(v0);
    *(unsigned*)(h2 + (size_t)n * 512 + t * 2) = o;
}

// ---------------- launch ----------------
extern "C" void kernel_launch(void* const* d_in, const int* in_sizes, int n_in,
                              void* d_out, int out_size, void* d_ws, size_t ws_size,
                              hipStream_t stream)
{
    const float* feat  = (const float*)d_in[0];
    const int*   src   = (const int*)d_in[1];
    const int*   dst   = (const int*)d_in[2];
    const float* W1    = (const float*)d_in[3];
    const float* al1   = (const float*)d_in[4];
    const float* ar1   = (const float*)d_in[5];
    const float* resW1 = (const float*)d_in[6];
    const float* b1    = (const float*)d_in[7];
    const float* W2    = (const float*)d_in[8];
    const float* al2   = (const float*)d_in[9];
    const float* ar2   = (const float*)d_in[10];
    const float* resW2 = (const float*)d_in[11];
    const float* b2    = (const float*)d_in[12];
    const float* Wout  = (const float*)d_in[13];
    const float* bout  = (const float*)d_in[14];
    const int N = in_sizes[0] / IN_F;  // 8192
    const int E = in_sizes[1];         // 65536

    // ---- workspace layout (no aliasing; ~133 MB) ----
    char* w = (char*)d_ws;
    auto alloc = [&](size_t bytes) -> char* {
        char* p = w;
        w += (bytes + 255) & ~(size_t)255;
        return p;
    };
    short*    z1b     = (short*)alloc((size_t)N * 2048 * 2);      // 32 MB
    short*    res1b   = (short*)alloc((size_t)N * 2048 * 2);      // 32 MB
    short*    h1b     = (short*)alloc((size_t)N * 2048 * 2);      // 32 MB
    short*    featb   = (short*)alloc((size_t)N * 256 * 2);       // 4 MB
    short*    W1t     = (short*)alloc((size_t)2048 * 256 * 2);
    short*    resW1t  = (short*)alloc((size_t)2048 * 256 * 2);
    short*    W2t     = (short*)alloc((size_t)128 * 512 * 2);
    short*    resW2t  = (short*)alloc((size_t)128 * 512 * 2);
    short*    Wtout   = (short*)alloc((size_t)128 * 512 * 2);
    float*    wal1    = (float*)alloc((size_t)256 * 4 * 4);
    float*    war1    = (float*)alloc((size_t)256 * 4 * 4);
    float*    wal2    = (float*)alloc((size_t)512 * 4 * 4);
    float*    war2    = (float*)alloc((size_t)512 * 4 * 4);
    float*    el1     = (float*)alloc((size_t)N * 4 * 4);
    float*    er1     = (float*)alloc((size_t)N * 4 * 4);
    unsigned* emax1o  = (unsigned*)alloc((size_t)N * 4 * 4);
    float*    emax1f  = (float*)alloc((size_t)N * 4 * 4);
    float*    denom1  = (float*)alloc((size_t)N * 4 * 4);
    float*    e1      = (float*)alloc((size_t)E * 4 * 4);
    int*      deg     = (int*)alloc((size_t)N * 4);
    int*      off     = (int*)alloc((size_t)(N + 1) * 4);
    int*      cur     = (int*)alloc((size_t)N * 4);
    int*      eid     = (int*)alloc((size_t)E * 4);
    short*    z2b     = (short*)alloc((size_t)N * 4 * 128 * 2);   // 8 MB
    short*    res2b   = (short*)alloc((size_t)N * 4 * 128 * 2);   // 8 MB
    short*    h2b     = (short*)alloc((size_t)N * 512 * 2);       // 8 MB
    float*    el2     = (float*)alloc((size_t)N * 16 * 4);
    float*    er2     = (float*)alloc((size_t)N * 16 * 4);
    unsigned* emax2o  = (unsigned*)alloc((size_t)N * 16 * 4);
    float*    emax2f  = (float*)alloc((size_t)N * 16 * 4);
    float*    denom2  = (float*)alloc((size_t)N * 16 * 4);
    float*    e2      = (float*)alloc((size_t)E * 16 * 4);        // 4 MB

    dim3 blk(256);

    // ===== CSR build =====
    hipMemsetAsync(deg, 0, (size_t)N * 4, stream);
    hipMemsetAsync(cur, 0, (size_t)N * 4, stream);
    hist_kernel<<<dim3((E + 255) / 256), blk, 0, stream>>>(dst, deg, E);
    scan_excl<<<dim3(1), dim3(1024), 0, stream>>>(deg, off, N);
    scatter_kernel<<<dim3((E + 255) / 256), blk, 0, stream>>>(dst, off, cur, eid, E);

    // ===== conversions & folds =====
    cvt_bf16<<<dim3((N * 256 / 4 + 255) / 256), blk, 0, stream>>>((const float4*)feat, (short4v*)featb, N * 256 / 4);
    cvt_t_bf16<<<dim3(2048 / 32, 256 / 32), blk, 0, stream>>>(W1, W1t, 256, 2048, 2048);
    cvt_t_bf16<<<dim3(2048 / 32, 256 / 32), blk, 0, stream>>>(resW1, resW1t, 256, 2048, 2048);
    cvt_t_bf16<<<dim3(128 / 32, 512 / 32), blk, 0, stream>>>(W2, W2t, 512, 128, 128);
    cvt_t_bf16<<<dim3(128 / 32, 512 / 32), blk, 0, stream>>>(resW2, resW2t, 512, 128, 128);
    cvt_t_bf16<<<dim3(128 / 32, 512 / 32), blk, 0, stream>>>(Wout, Wtout, 512, 40, 128);   // zero-padded
    fold_aw<<<dim3((256 * 4 + 255) / 256), blk, 0, stream>>>(W1, al1, ar1, wal1, war1, 256, 512);
    fold_aw<<<dim3((512 * 4 + 255) / 256), blk, 0, stream>>>(W2, al2, ar2, wal2, war2, 512, 32);

    // el1/er1 directly from fp32 features (exact w.r.t. reference linearity)
    el_er_fold<float><<<dim3(N / 4), blk, 0, stream>>>(feat, (const float4*)wal1, (const float4*)war1, el1, er1, 256);

    // ===== layer 1 GEMMs (bf16 out) =====
    gemm_bf16<<<dim3(2048 / 128, N / 128), blk, 0, stream>>>(featb, W1t, nullptr, z1b, N, 2048, 256, 2048, 2048, 1);
    gemm_bf16<<<dim3(2048 / 128, N / 128), blk, 0, stream>>>(featb, resW1t, b1, res1b, N, 2048, 256, 2048, 2048, 1);

    // ===== edge softmax L1 =====
    hipMemsetAsync(emax1o, 0, (size_t)N * 4 * 4, stream);
    hipMemsetAsync(denom1, 0, (size_t)N * 4 * 4, stream);
    edge_logits<4><<<dim3((E * 4 + 255) / 256), blk, 0, stream>>>(src, dst, el1, er1, e1, emax1o, E);
    finalize_max<<<dim3((N * 4 + 255) / 256), blk, 0, stream>>>(emax1o, emax1f, N * 4);
    edge_exp<4><<<dim3((E * 4 + 255) / 256), blk, 0, stream>>>(dst, e1, emax1f, denom1, E);
    aggregate1<<<dim3(N), blk, 0, stream>>>(off, eid, src, e1, denom1, z1b, res1b, h1b);
    // h1b = bf16 h1 [N,4,512]

    // el2/er2 from bf16 h1 via folded weights
    el_er_fold<short><<<dim3(N * 4 / 4), blk, 0, stream>>>(h1b, (const float4*)wal2, (const float4*)war2, el2, er2, 512);

    // ===== layer 2 GEMMs (bf16 out) =====
    gemm_bf16<<<dim3(128 / 128, (N * 4) / 128), blk, 0, stream>>>(h1b, W2t, nullptr, z2b, N * 4, 128, 512, 128, 128, 1);
    gemm_bf16<<<dim3(128 / 128, (N * 4) / 128), blk, 0, stream>>>(h1b, resW2t, b2, res2b, N * 4, 128, 512, 128, 128, 1);

    // ===== edge softmax L2 =====
    hipMemsetAsync(emax2o, 0, (size_t)N * 16 * 4, stream);
    hipMemsetAsync(denom2, 0, (size_t)N * 16 * 4, stream);
    edge_logits<16><<<dim3((E * 16 + 255) / 256), blk, 0, stream>>>(src, dst, el2, er2, e2, emax2o, E);
    finalize_max<<<dim3((N * 16 + 255) / 256), blk, 0, stream>>>(emax2o, emax2f, N * 16);
    edge_exp<16><<<dim3((E * 16 + 255) / 256), blk, 0, stream>>>(dst, e2, emax2f, denom2, E);
    aggregate2<<<dim3(N), blk, 0, stream>>>(off, eid, src, e2, denom2, z2b, res2b, h2b);
    // h2b = bf16 h2 [N,512]

    // ===== final linear (MFMA, Wout zero-padded to 128 cols): out = h2 @ Wout + bout =====
    gemm_bf16<<<dim3(1, N / 128), blk, 0, stream>>>(h2b, Wtout, bout, (float*)d_out, N, 128, 512, 40, 40, 0);
}

// Round 6
// 294.978 us; speedup vs baseline: 1.3814x; 1.2969x over previous
//
#include <hip/hip_runtime.h>
#include <cmath>

constexpr int IN_F  = 256;

typedef short bf16x8 __attribute__((ext_vector_type(8)));
typedef short short4v __attribute__((ext_vector_type(4)));
typedef float f32x4 __attribute__((ext_vector_type(4)));

__device__ __forceinline__ short f2bf(float f) {
    unsigned u = __float_as_uint(f);
    unsigned r = (u + 0x7FFFu + ((u >> 16) & 1)) >> 16;  // RNE
    return (short)r;
}
__device__ __forceinline__ float b2f(short s) {
    return __uint_as_float(((unsigned)(unsigned short)s) << 16);
}
__device__ __forceinline__ float ldx(const float* p, size_t i) { return p[i]; }
__device__ __forceinline__ float ldx(const short* p, size_t i) { return b2f(p[i]); }

// ---------------- fp32 -> bf16 flat conversion (vectorized) ----------------
__global__ void cvt_bf16(const float4* __restrict__ x, short4v* __restrict__ y, int n4)
{
    int i = blockIdx.x * blockDim.x + threadIdx.x;
    if (i < n4) {
        float4 v = x[i];
        short4v o;
        o[0] = f2bf(v.x); o[1] = f2bf(v.y); o[2] = f2bf(v.z); o[3] = f2bf(v.w);
        y[i] = o;
    }
}

// ------- fp32 W[K,N] -> bf16 Wt[Np,K] transpose, zero-pad cols N..Np -------
__global__ __launch_bounds__(256) void cvt_t_bf16(
    const float* __restrict__ W, short* __restrict__ Wt, int K, int N, int Np)
{
    __shared__ float tile[32][33];
    int bk = blockIdx.y * 32, bn = blockIdx.x * 32;
    int tx = threadIdx.x & 31, ty = threadIdx.x >> 5;  // ty 0..7
#pragma unroll
    for (int i = ty; i < 32; i += 8) {
        int gn = bn + tx;
        tile[i][tx] = (gn < N) ? W[(size_t)(bk + i) * N + gn] : 0.f;
    }
    __syncthreads();
#pragma unroll
    for (int i = ty; i < 32; i += 8)
        Wt[(size_t)(bn + i) * K + bk + tx] = f2bf(tile[tx][i]);
}

// ------- fold attention vectors through W: wal[k,h] = sum_j W[k,h*klen+j]*al[h*klen+j] -------
// one WAVE per (k,h) output: lane-strided loads + butterfly reduce (latency fix)
__global__ __launch_bounds__(256) void fold_aw(
    const float* __restrict__ W, const float* __restrict__ al,
    const float* __restrict__ ar, float* __restrict__ wal,
    float* __restrict__ war, int K, int klen)
{
    int wid  = (blockIdx.x * blockDim.x + threadIdx.x) >> 6;  // = k*4+h
    int lane = threadIdx.x & 63;
    if (wid >= K * 4) return;
    int k = wid >> 2, h = wid & 3;
    const float* wr  = W  + (size_t)k * (4 * klen) + h * klen;
    const float* alp = al + h * klen;
    const float* arp = ar + h * klen;
    float sl = 0.f, sr = 0.f;
    for (int j = lane; j < klen; j += 64) {
        float wv = wr[j];
        sl = fmaf(wv, alp[j], sl);
        sr = fmaf(wv, arp[j], sr);
    }
#pragma unroll
    for (int o = 32; o; o >>= 1) { sl += __shfl_down(sl, o); sr += __shfl_down(sr, o); }
    if (lane == 0) { wal[wid] = sl; war[wid] = sr; }
}

// ------- el/er = X @ wal / X @ war  (one wave per row, 4 heads) -------
template <typename T>
__global__ __launch_bounds__(256) void el_er_fold(
    const T* __restrict__ X, const float4* __restrict__ wal, const float4* __restrict__ war,
    float* __restrict__ el, float* __restrict__ er, int Kdim)
{
    int row  = blockIdx.x * 4 + (threadIdx.x >> 6);
    int lane = threadIdx.x & 63;
    float sl[4] = {}, sr[4] = {};
    for (int k = lane; k < Kdim; k += 64) {
        float f = ldx(X, (size_t)row * Kdim + k);
        float4 wl = wal[k], wr = war[k];
        sl[0] = fmaf(f, wl.x, sl[0]); sl[1] = fmaf(f, wl.y, sl[1]);
        sl[2] = fmaf(f, wl.z, sl[2]); sl[3] = fmaf(f, wl.w, sl[3]);
        sr[0] = fmaf(f, wr.x, sr[0]); sr[1] = fmaf(f, wr.y, sr[1]);
        sr[2] = fmaf(f, wr.z, sr[2]); sr[3] = fmaf(f, wr.w, sr[3]);
    }
#pragma unroll
    for (int o = 32; o; o >>= 1) {
#pragma unroll
        for (int h = 0; h < 4; h++) { sl[h] += __shfl_down(sl[h], o); sr[h] += __shfl_down(sr[h], o); }
    }
    if (lane == 0) {
#pragma unroll
        for (int h = 0; h < 4; h++) { el[row * 4 + h] = sl[h]; er[row * 4 + h] = sr[h]; }
    }
}

// ---------------- bf16 MFMA GEMM: A[M,K] x Bt[N,K]^T -> C[M,*] ----------------
// M%128==0, N%128==0 (padded), K%32==0. 128x128 tile, 4 waves, BK=32.
// C dtype: out_bf16 ? bf16 : fp32 ; row stride ldc ; cols written: [0,nmax)
__global__ __launch_bounds__(256) void gemm_bf16(
    const short* __restrict__ A, const short* __restrict__ Bt,
    const float* __restrict__ bias, void* __restrict__ C,
    int M, int N, int K, int ldc, int nmax, int out_bf16)
{
    __shared__ short sA[128 * 32];
    __shared__ short sB[128 * 32];
    const int tid  = threadIdx.x;
    const int wave = tid >> 6, lane = tid & 63;
    const int wm = wave >> 1, wn = wave & 1;
    const int m0 = blockIdx.y * 128, n0 = blockIdx.x * 128;

    const int srow = tid >> 2;
    const int scol = (tid & 3) * 8;

    const int fr = lane & 15;
    const int fq = lane >> 4;

    f32x4 acc[4][4] = {};

    for (int k0 = 0; k0 < K; k0 += 32) {
        const short* ga0 = A  + (size_t)(m0 + srow) * K + k0 + scol;
        const short* ga1 = A  + (size_t)(m0 + 64 + srow) * K + k0 + scol;
        const short* gb0 = Bt + (size_t)(n0 + srow) * K + k0 + scol;
        const short* gb1 = Bt + (size_t)(n0 + 64 + srow) * K + k0 + scol;
        __builtin_amdgcn_global_load_lds((const __attribute__((address_space(1))) void*)ga0,
            (__attribute__((address_space(3))) void*)(sA + wave * 512), 16, 0, 0);
        __builtin_amdgcn_global_load_lds((const __attribute__((address_space(1))) void*)ga1,
            (__attribute__((address_space(3))) void*)(sA + 2048 + wave * 512), 16, 0, 0);
        __builtin_amdgcn_global_load_lds((const __attribute__((address_space(1))) void*)gb0,
            (__attribute__((address_space(3))) void*)(sB + wave * 512), 16, 0, 0);
        __builtin_amdgcn_global_load_lds((const __attribute__((address_space(1))) void*)gb1,
            (__attribute__((address_space(3))) void*)(sB + 2048 + wave * 512), 16, 0, 0);
        __syncthreads();

        bf16x8 af[4], bfr[4];
#pragma unroll
        for (int m = 0; m < 4; m++)
            af[m] = *(const bf16x8*)(sA + (wm * 64 + m * 16 + fr) * 32 + fq * 8);
#pragma unroll
        for (int n = 0; n < 4; n++)
            bfr[n] = *(const bf16x8*)(sB + (wn * 64 + n * 16 + fr) * 32 + fq * 8);
#pragma unroll
        for (int m = 0; m < 4; m++)
#pragma unroll
            for (int n = 0; n < 4; n++)
                acc[m][n] = __builtin_amdgcn_mfma_f32_16x16x32_bf16(af[m], bfr[n], acc[m][n], 0, 0, 0);
        __syncthreads();
    }

#pragma unroll
    for (int n = 0; n < 4; n++) {
        int gcol = n0 + wn * 64 + n * 16 + fr;
        if (gcol >= nmax) continue;
        float bv = bias ? bias[gcol] : 0.f;
#pragma unroll
        for (int m = 0; m < 4; m++) {
#pragma unroll
            for (int j = 0; j < 4; j++) {
                int grow = m0 + wm * 64 + m * 16 + fq * 4 + j;
                float v = acc[m][n][j] + bv;
                if (out_bf16) ((short*)C)[(size_t)grow * ldc + gcol] = f2bf(v);
                else          ((float*)C)[(size_t)grow * ldc + gcol] = v;
            }
        }
    }
}

// ---------------- edge softmax helpers ----------------
__device__ __forceinline__ unsigned f2ord(float f) {
    unsigned u = __float_as_uint(f);
    return (u & 0x80000000u) ? ~u : (u | 0x80000000u);
}
__device__ __forceinline__ float ord2f(unsigned o) {
    unsigned u = (o & 0x80000000u) ? (o & 0x7FFFFFFFu) : ~o;
    return __uint_as_float(u);
}

template <int C>
__global__ void edge_logits(const int* __restrict__ src, const int* __restrict__ dst,
                            const float* __restrict__ el, const float* __restrict__ er,
                            float* __restrict__ ebuf, unsigned* __restrict__ emax, int E)
{
    int idx = blockIdx.x * blockDim.x + threadIdx.x;
    if (idx >= E * C) return;
    int e = idx / C, c = idx % C;
    float v = el[src[e] * C + c] + er[dst[e] * C + c];
    v = v > 0.f ? v : 0.2f * v;   // leaky_relu, slope 0.2
    ebuf[idx] = v;
    atomicMax(&emax[dst[e] * C + c], f2ord(v));
}

__global__ void finalize_max(const unsigned* __restrict__ emo, float* __restrict__ emf, int NC)
{
    int i = blockIdx.x * blockDim.x + threadIdx.x;
    if (i < NC) {
        float v = ord2f(emo[i]);
        emf[i] = isfinite(v) ? v : 0.f;
    }
}

template <int C>
__global__ void edge_exp(const int* __restrict__ dst, float* __restrict__ ebuf,
                         const float* __restrict__ emf, float* __restrict__ denom, int E)
{
    int idx = blockIdx.x * blockDim.x + threadIdx.x;
    if (idx >= E * C) return;
    int e = idx / C, c = idx % C;
    int d = dst[e];
    float ex = expf(ebuf[idx] - emf[d * C + c]);
    ebuf[idx] = ex;
    atomicAdd(&denom[d * C + c], ex);
}

// ---------------- CSR build (by dst) ----------------
__global__ void hist_kernel(const int* __restrict__ dst, int* __restrict__ deg, int E)
{
    int e = blockIdx.x * blockDim.x + threadIdx.x;
    if (e < E) atomicAdd(&deg[dst[e]], 1);
}

__global__ __launch_bounds__(1024) void scan_excl(const int* __restrict__ deg,
                                                  int* __restrict__ off, int N)
{
    __shared__ int part[1024];
    int t = threadIdx.x;
    int chunk = N >> 10;
    int base = t * chunk;
    int local[16];
    int s = 0;
    for (int i = 0; i < chunk; i++) { local[i] = s; s += deg[base + i]; }
    part[t] = s;
    __syncthreads();
    for (int o = 1; o < 1024; o <<= 1) {
        int v = (t >= o) ? part[t - o] : 0;
        __syncthreads();
        part[t] += v;
        __syncthreads();
    }
    int pre = (t == 0) ? 0 : part[t - 1];
    for (int i = 0; i < chunk; i++) off[base + i] = pre + local[i];
    if (t == 1023) off[N] = pre + s;
}

__global__ void scatter_kernel(const int* __restrict__ dst, const int* __restrict__ off,
                               int* __restrict__ cur, int* __restrict__ eid, int E)
{
    int e = blockIdx.x * blockDim.x + threadIdx.x;
    if (e < E) {
        int d = dst[e];
        int p = off[d] + atomicAdd(&cur[d], 1);
        eid[p] = e;
    }
}

// ------- aggregation L1: bf16 z gather (16B/thread/edge), bf16 res, bf16 h1 out -------
__global__ __launch_bounds__(256) void aggregate1(
    const int* __restrict__ off, const int* __restrict__ eid, const int* __restrict__ src,
    const float* __restrict__ ex, const float* __restrict__ denom,
    const short* __restrict__ z, const short* __restrict__ res, short* __restrict__ h1)
{
    int n = blockIdx.x, t = threadIdx.x;
    int h = t >> 6;                     // cols [8t,8t+8) all in head t/64
    float r[8] = {};
    int beg = off[n], end = off[n + 1];
    for (int j = beg; j < end; ++j) {
        int e = eid[j];
        bf16x8 zv = *(const bf16x8*)(z + (size_t)src[e] * 2048 + t * 8);
        float a = ex[e * 4 + h];
#pragma unroll
        for (int i = 0; i < 8; ++i) r[i] = fmaf(a, b2f(zv[i]), r[i]);
    }
    float dn = denom[n * 4 + h];
    if (dn == 0.f) dn = 1.f;
    float inv = 1.f / dn;
    bf16x8 rv = *(const bf16x8*)(res + (size_t)n * 2048 + t * 8);
    bf16x8 ov;
#pragma unroll
    for (int i = 0; i < 8; ++i) {
        float v = r[i] * inv + b2f(rv[i]);
        ov[i] = f2bf(v > 0.f ? v : 0.f);
    }
    *(bf16x8*)(h1 + (size_t)n * 2048 + t * 8) = ov;
}

// ------- aggregation L2: bf16 z2 gather (4B/thread/edge), bf16 res2, bf16 h2 out -------
__global__ __launch_bounds__(256) void aggregate2(
    const int* __restrict__ off, const int* __restrict__ eid, const int* __restrict__ src,
    const float* __restrict__ ex, const float* __restrict__ denom,
    const short* __restrict__ z, const short* __restrict__ res, short* __restrict__ h2)
{
    int n = blockIdx.x, t = threadIdx.x;
    int c = t >> 4;                     // cols [2t,2t+2) share channel (2t)>>5
    float r0 = 0.f, r1 = 0.f;
    int beg = off[n], end = off[n + 1];
    for (int j = beg; j < end; ++j) {
        int e = eid[j];
        unsigned zv = *(const unsigned*)(z + (size_t)src[e] * 512 + t * 2);
        float a = ex[e * 16 + c];
        r0 = fmaf(a, b2f((short)(zv & 0xFFFFu)), r0);
        r1 = fmaf(a, b2f((short)(zv >> 16)), r1);
    }
    float dn = denom[n * 16 + c];
    if (dn == 0.f) dn = 1.f;
    float inv = 1.f / dn;
    unsigned rv = *(const unsigned*)(res + (size_t)n * 512 + t * 2);
    float v0 = r0 * inv + b2f((short)(rv & 0xFFFFu));
    float v1 = r1 * inv + b2f((short)(rv >> 16));
    v0 = v0 > 0.f ? v0 : 0.f;
    v1 = v1 > 0.f ? v1 : 0.f;
    unsigned o = ((unsigned)(unsigned short)f2bf(v1) << 16) | (unsigned)(unsigned short)f2bf(v0);
    *(unsigned*)(h2 + (size_t)n * 512 + t * 2) = o;
}

// ---------------- launch ----------------
extern "C" void kernel_launch(void* const* d_in, const int* in_sizes, int n_in,
                              void* d_out, int out_size, void* d_ws, size_t ws_size,
                              hipStream_t stream)
{
    const float* feat  = (const float*)d_in[0];
    const int*   src   = (const int*)d_in[1];
    const int*   dst   = (const int*)d_in[2];
    const float* W1    = (const float*)d_in[3];
    const float* al1   = (const float*)d_in[4];
    const float* ar1   = (const float*)d_in[5];
    const float* resW1 = (const float*)d_in[6];
    const float* b1    = (const float*)d_in[7];
    const float* W2    = (const float*)d_in[8];
    const float* al2   = (const float*)d_in[9];
    const float* ar2   = (const float*)d_in[10];
    const float* resW2 = (const float*)d_in[11];
    const float* b2    = (const float*)d_in[12];
    const float* Wout  = (const float*)d_in[13];
    const float* bout  = (const float*)d_in[14];
    const int N = in_sizes[0] / IN_F;  // 8192
    const int E = in_sizes[1];         // 65536

    // ---- workspace layout (no aliasing; ~133 MB) ----
    char* w = (char*)d_ws;
    auto alloc = [&](size_t bytes) -> char* {
        char* p = w;
        w += (bytes + 255) & ~(size_t)255;
        return p;
    };
    short*    z1b     = (short*)alloc((size_t)N * 2048 * 2);      // 32 MB
    short*    res1b   = (short*)alloc((size_t)N * 2048 * 2);      // 32 MB
    short*    h1b     = (short*)alloc((size_t)N * 2048 * 2);      // 32 MB
    short*    featb   = (short*)alloc((size_t)N * 256 * 2);       // 4 MB
    short*    W1t     = (short*)alloc((size_t)2048 * 256 * 2);
    short*    resW1t  = (short*)alloc((size_t)2048 * 256 * 2);
    short*    W2t     = (short*)alloc((size_t)128 * 512 * 2);
    short*    resW2t  = (short*)alloc((size_t)128 * 512 * 2);
    short*    Wtout   = (short*)alloc((size_t)128 * 512 * 2);
    float*    wal1    = (float*)alloc((size_t)256 * 4 * 4);
    float*    war1    = (float*)alloc((size_t)256 * 4 * 4);
    float*    wal2    = (float*)alloc((size_t)512 * 4 * 4);
    float*    war2    = (float*)alloc((size_t)512 * 4 * 4);
    float*    el1     = (float*)alloc((size_t)N * 4 * 4);
    float*    er1     = (float*)alloc((size_t)N * 4 * 4);
    unsigned* emax1o  = (unsigned*)alloc((size_t)N * 4 * 4);
    float*    emax1f  = (float*)alloc((size_t)N * 4 * 4);
    float*    denom1  = (float*)alloc((size_t)N * 4 * 4);
    float*    e1      = (float*)alloc((size_t)E * 4 * 4);
    int*      deg     = (int*)alloc((size_t)N * 4);
    int*      off     = (int*)alloc((size_t)(N + 1) * 4);
    int*      cur     = (int*)alloc((size_t)N * 4);
    int*      eid     = (int*)alloc((size_t)E * 4);
    short*    z2b     = (short*)alloc((size_t)N * 4 * 128 * 2);   // 8 MB
    short*    res2b   = (short*)alloc((size_t)N * 4 * 128 * 2);   // 8 MB
    short*    h2b     = (short*)alloc((size_t)N * 512 * 2);       // 8 MB
    float*    el2     = (float*)alloc((size_t)N * 16 * 4);
    float*    er2     = (float*)alloc((size_t)N * 16 * 4);
    unsigned* emax2o  = (unsigned*)alloc((size_t)N * 16 * 4);
    float*    emax2f  = (float*)alloc((size_t)N * 16 * 4);
    float*    denom2  = (float*)alloc((size_t)N * 16 * 4);
    float*    e2      = (float*)alloc((size_t)E * 16 * 4);        // 4 MB

    dim3 blk(256);

    // ===== CSR build =====
    hipMemsetAsync(deg, 0, (size_t)N * 4, stream);
    hipMemsetAsync(cur, 0, (size_t)N * 4, stream);
    hist_kernel<<<dim3((E + 255) / 256), blk, 0, stream>>>(dst, deg, E);
    scan_excl<<<dim3(1), dim3(1024), 0, stream>>>(deg, off, N);
    scatter_kernel<<<dim3((E + 255) / 256), blk, 0, stream>>>(dst, off, cur, eid, E);

    // ===== conversions & folds =====
    cvt_bf16<<<dim3((N * 256 / 4 + 255) / 256), blk, 0, stream>>>((const float4*)feat, (short4v*)featb, N * 256 / 4);
    cvt_t_bf16<<<dim3(2048 / 32, 256 / 32), blk, 0, stream>>>(W1, W1t, 256, 2048, 2048);
    cvt_t_bf16<<<dim3(2048 / 32, 256 / 32), blk, 0, stream>>>(resW1, resW1t, 256, 2048, 2048);
    cvt_t_bf16<<<dim3(128 / 32, 512 / 32), blk, 0, stream>>>(W2, W2t, 512, 128, 128);
    cvt_t_bf16<<<dim3(128 / 32, 512 / 32), blk, 0, stream>>>(resW2, resW2t, 512, 128, 128);
    cvt_t_bf16<<<dim3(128 / 32, 512 / 32), blk, 0, stream>>>(Wout, Wtout, 512, 40, 128);   // zero-padded
    fold_aw<<<dim3((256 * 4 * 64 + 255) / 256), blk, 0, stream>>>(W1, al1, ar1, wal1, war1, 256, 512);
    fold_aw<<<dim3((512 * 4 * 64 + 255) / 256), blk, 0, stream>>>(W2, al2, ar2, wal2, war2, 512, 32);

    // el1/er1 directly from fp32 features (exact w.r.t. reference linearity)
    el_er_fold<float><<<dim3(N / 4), blk, 0, stream>>>(feat, (const float4*)wal1, (const float4*)war1, el1, er1, 256);

    // ===== layer 1 GEMMs (bf16 out) =====
    gemm_bf16<<<dim3(2048 / 128, N / 128), blk, 0, stream>>>(featb, W1t, nullptr, z1b, N, 2048, 256, 2048, 2048, 1);
    gemm_bf16<<<dim3(2048 / 128, N / 128), blk, 0, stream>>>(featb, resW1t, b1, res1b, N, 2048, 256, 2048, 2048, 1);

    // ===== edge softmax L1 =====
    hipMemsetAsync(emax1o, 0, (size_t)N * 4 * 4, stream);
    hipMemsetAsync(denom1, 0, (size_t)N * 4 * 4, stream);
    edge_logits<4><<<dim3((E * 4 + 255) / 256), blk, 0, stream>>>(src, dst, el1, er1, e1, emax1o, E);
    finalize_max<<<dim3((N * 4 + 255) / 256), blk, 0, stream>>>(emax1o, emax1f, N * 4);
    edge_exp<4><<<dim3((E * 4 + 255) / 256), blk, 0, stream>>>(dst, e1, emax1f, denom1, E);
    aggregate1<<<dim3(N), blk, 0, stream>>>(off, eid, src, e1, denom1, z1b, res1b, h1b);
    // h1b = bf16 h1 [N,4,512]

    // el2/er2 from bf16 h1 via folded weights
    el_er_fold<short><<<dim3(N * 4 / 4), blk, 0, stream>>>(h1b, (const float4*)wal2, (const float4*)war2, el2, er2, 512);

    // ===== layer 2 GEMMs (bf16 out) =====
    gemm_bf16<<<dim3(128 / 128, (N * 4) / 128), blk, 0, stream>>>(h1b, W2t, nullptr, z2b, N * 4, 128, 512, 128, 128, 1);
    gemm_bf16<<<dim3(128 / 128, (N * 4) / 128), blk, 0, stream>>>(h1b, resW2t, b2, res2b, N * 4, 128, 512, 128, 128, 1);

    // ===== edge softmax L2 =====
    hipMemsetAsync(emax2o, 0, (size_t)N * 16 * 4, stream);
    hipMemsetAsync(denom2, 0, (size_t)N * 16 * 4, stream);
    edge_logits<16><<<dim3((E * 16 + 255) / 256), blk, 0, stream>>>(src, dst, el2, er2, e2, emax2o, E);
    finalize_max<<<dim3((N * 16 + 255) / 256), blk, 0, stream>>>(emax2o, emax2f, N * 16);
    edge_exp<16><<<dim3((E * 16 + 255) / 256), blk, 0, stream>>>(dst, e2, emax2f, denom2, E);
    aggregate2<<<dim3(N), blk, 0, stream>>>(off, eid, src, e2, denom2, z2b, res2b, h2b);
    // h2b = bf16 h2 [N,512]

    // ===== final linear (MFMA, Wout zero-padded to 128 cols): out = h2 @ Wout + bout =====
    gemm_bf16<<<dim3(1, N / 128), blk, 0, stream>>>(h2b, Wtout, bout, (float*)d_out, N, 128, 512, 40, 40, 0);
}

// Round 7
// 241.417 us; speedup vs baseline: 1.6879x; 1.2219x over previous
//
#include <hip/hip_runtime.h>
#include <cmath>

constexpr int IN_F  = 256;

typedef short bf16x8 __attribute__((ext_vector_type(8)));
typedef short short4v __attribute__((ext_vector_type(4)));
typedef float f32x4 __attribute__((ext_vector_type(4)));

__device__ __forceinline__ short f2bf(float f) {
    unsigned u = __float_as_uint(f);
    unsigned r = (u + 0x7FFFu + ((u >> 16) & 1)) >> 16;  // RNE
    return (short)r;
}
__device__ __forceinline__ float b2f(short s) {
    return __uint_as_float(((unsigned)(unsigned short)s) << 16);
}
__device__ __forceinline__ float ldx(const float* p, size_t i) { return p[i]; }
__device__ __forceinline__ float ldx(const short* p, size_t i) { return b2f(p[i]); }

// ---------------- fp32 -> bf16 flat conversion (vectorized) ----------------
__global__ void cvt_bf16(const float4* __restrict__ x, short4v* __restrict__ y, int n4)
{
    int i = blockIdx.x * blockDim.x + threadIdx.x;
    if (i < n4) {
        float4 v = x[i];
        short4v o;
        o[0] = f2bf(v.x); o[1] = f2bf(v.y); o[2] = f2bf(v.z); o[3] = f2bf(v.w);
        y[i] = o;
    }
}

// -- fp32 W[K,N] -> bf16 Wt rows=out-col, ld=ldwt, k at offset koff; zero-pad N..Np --
__global__ __launch_bounds__(256) void cvt_t_bf16(
    const float* __restrict__ W, short* __restrict__ Wt, int K, int N, int Np,
    int ldwt, int koff)
{
    __shared__ float tile[32][33];
    int bk = blockIdx.y * 32, bn = blockIdx.x * 32;
    int tx = threadIdx.x & 31, ty = threadIdx.x >> 5;  // ty 0..7
#pragma unroll
    for (int i = ty; i < 32; i += 8) {
        int gn = bn + tx;
        tile[i][tx] = (gn < N) ? W[(size_t)(bk + i) * N + gn] : 0.f;
    }
    __syncthreads();
#pragma unroll
    for (int i = ty; i < 32; i += 8)
        Wt[(size_t)(bn + i) * ldwt + koff + bk + tx] = f2bf(tile[tx][i]);
}

// ------- fold attention vectors through W (one wave per (k,h) output) -------
__global__ __launch_bounds__(256) void fold_aw(
    const float* __restrict__ W, const float* __restrict__ al,
    const float* __restrict__ ar, float* __restrict__ wal,
    float* __restrict__ war, int K, int klen)
{
    int wid  = (blockIdx.x * blockDim.x + threadIdx.x) >> 6;  // = k*4+h
    int lane = threadIdx.x & 63;
    if (wid >= K * 4) return;
    int k = wid >> 2, h = wid & 3;
    const float* wr  = W  + (size_t)k * (4 * klen) + h * klen;
    const float* alp = al + h * klen;
    const float* arp = ar + h * klen;
    float sl = 0.f, sr = 0.f;
    for (int j = lane; j < klen; j += 64) {
        float wv = wr[j];
        sl = fmaf(wv, alp[j], sl);
        sr = fmaf(wv, arp[j], sr);
    }
#pragma unroll
    for (int o = 32; o; o >>= 1) { sl += __shfl_down(sl, o); sr += __shfl_down(sr, o); }
    if (lane == 0) { wal[wid] = sl; war[wid] = sr; }
}

// ------- el/er = X @ wal / X @ war  (one wave per row, 4 heads) -------
template <typename T>
__global__ __launch_bounds__(256) void el_er_fold(
    const T* __restrict__ X, const float4* __restrict__ wal, const float4* __restrict__ war,
    float* __restrict__ el, float* __restrict__ er, int Kdim)
{
    int row  = blockIdx.x * 4 + (threadIdx.x >> 6);
    int lane = threadIdx.x & 63;
    float sl[4] = {}, sr[4] = {};
    for (int k = lane; k < Kdim; k += 64) {
        float f = ldx(X, (size_t)row * Kdim + k);
        float4 wl = wal[k], wr = war[k];
        sl[0] = fmaf(f, wl.x, sl[0]); sl[1] = fmaf(f, wl.y, sl[1]);
        sl[2] = fmaf(f, wl.z, sl[2]); sl[3] = fmaf(f, wl.w, sl[3]);
        sr[0] = fmaf(f, wr.x, sr[0]); sr[1] = fmaf(f, wr.y, sr[1]);
        sr[2] = fmaf(f, wr.z, sr[2]); sr[3] = fmaf(f, wr.w, sr[3]);
    }
#pragma unroll
    for (int o = 32; o; o >>= 1) {
#pragma unroll
        for (int h = 0; h < 4; h++) { sl[h] += __shfl_down(sl[h], o); sr[h] += __shfl_down(sr[h], o); }
    }
    if (lane == 0) {
#pragma unroll
        for (int h = 0; h < 4; h++) { el[row * 4 + h] = sl[h]; er[row * 4 + h] = sr[h]; }
    }
}

// ---------------- bf16 MFMA GEMM: A[M,K] x Bt[N,K]^T -> C[M,*] ----------------
// M%128==0, N%128==0 (padded), K%32==0. 128x128 tile, 4 waves, BK=32.
__global__ __launch_bounds__(256) void gemm_bf16(
    const short* __restrict__ A, const short* __restrict__ Bt,
    const float* __restrict__ bias, void* __restrict__ C,
    int M, int N, int K, int ldc, int nmax, int out_bf16)
{
    __shared__ short sA[128 * 32];
    __shared__ short sB[128 * 32];
    const int tid  = threadIdx.x;
    const int wave = tid >> 6, lane = tid & 63;
    const int wm = wave >> 1, wn = wave & 1;
    const int m0 = blockIdx.y * 128, n0 = blockIdx.x * 128;

    const int srow = tid >> 2;
    const int scol = (tid & 3) * 8;

    const int fr = lane & 15;
    const int fq = lane >> 4;

    f32x4 acc[4][4] = {};

    for (int k0 = 0; k0 < K; k0 += 32) {
        const short* ga0 = A  + (size_t)(m0 + srow) * K + k0 + scol;
        const short* ga1 = A  + (size_t)(m0 + 64 + srow) * K + k0 + scol;
        const short* gb0 = Bt + (size_t)(n0 + srow) * K + k0 + scol;
        const short* gb1 = Bt + (size_t)(n0 + 64 + srow) * K + k0 + scol;
        __builtin_amdgcn_global_load_lds((const __attribute__((address_space(1))) void*)ga0,
            (__attribute__((address_space(3))) void*)(sA + wave * 512), 16, 0, 0);
        __builtin_amdgcn_global_load_lds((const __attribute__((address_space(1))) void*)ga1,
            (__attribute__((address_space(3))) void*)(sA + 2048 + wave * 512), 16, 0, 0);
        __builtin_amdgcn_global_load_lds((const __attribute__((address_space(1))) void*)gb0,
            (__attribute__((address_space(3))) void*)(sB + wave * 512), 16, 0, 0);
        __builtin_amdgcn_global_load_lds((const __attribute__((address_space(1))) void*)gb1,
            (__attribute__((address_space(3))) void*)(sB + 2048 + wave * 512), 16, 0, 0);
        __syncthreads();

        bf16x8 af[4], bfr[4];
#pragma unroll
        for (int m = 0; m < 4; m++)
            af[m] = *(const bf16x8*)(sA + (wm * 64 + m * 16 + fr) * 32 + fq * 8);
#pragma unroll
        for (int n = 0; n < 4; n++)
            bfr[n] = *(const bf16x8*)(sB + (wn * 64 + n * 16 + fr) * 32 + fq * 8);
#pragma unroll
        for (int m = 0; m < 4; m++)
#pragma unroll
            for (int n = 0; n < 4; n++)
                acc[m][n] = __builtin_amdgcn_mfma_f32_16x16x32_bf16(af[m], bfr[n], acc[m][n], 0, 0, 0);
        __syncthreads();
    }

#pragma unroll
    for (int n = 0; n < 4; n++) {
        int gcol = n0 + wn * 64 + n * 16 + fr;
        if (gcol >= nmax) continue;
        float bv = bias ? bias[gcol] : 0.f;
#pragma unroll
        for (int m = 0; m < 4; m++) {
#pragma unroll
            for (int j = 0; j < 4; j++) {
                int grow = m0 + wm * 64 + m * 16 + fq * 4 + j;
                float v = acc[m][n][j] + bv;
                if (out_bf16) ((short*)C)[(size_t)grow * ldc + gcol] = f2bf(v);
                else          ((float*)C)[(size_t)grow * ldc + gcol] = v;
            }
        }
    }
}

// ---- batched-by-head GEMM: h1 = relu(Acomb_h[M,512] @ Wcomb_h[512cols,512]^T + b1) ----
// Acomb [M,4,512] (lda 2048, head offset h*512); Wcomb [2048 rows=outcol, 512]
// C = h1b [M, 2048] bf16, cols h*512..h*512+512. grid (4, M/128, 4heads)
__global__ __launch_bounds__(256) void gemm_h1(
    const short* __restrict__ Acomb, const short* __restrict__ Wcomb,
    const float* __restrict__ b1, short* __restrict__ h1b)
{
    __shared__ short sA[128 * 32];
    __shared__ short sB[128 * 32];
    const int tid  = threadIdx.x;
    const int wave = tid >> 6, lane = tid & 63;
    const int wm = wave >> 1, wn = wave & 1;
    const int h  = blockIdx.z;
    const int m0 = blockIdx.y * 128, n0 = blockIdx.x * 128;   // n0 in [0,512)
    const short* A  = Acomb + h * 512;                        // row stride 2048
    const short* Bt = Wcomb + (size_t)(h * 512) * 512;        // row stride 512

    const int srow = tid >> 2;
    const int scol = (tid & 3) * 8;
    const int fr = lane & 15;
    const int fq = lane >> 4;

    f32x4 acc[4][4] = {};

    for (int k0 = 0; k0 < 512; k0 += 32) {
        const short* ga0 = A  + (size_t)(m0 + srow) * 2048 + k0 + scol;
        const short* ga1 = A  + (size_t)(m0 + 64 + srow) * 2048 + k0 + scol;
        const short* gb0 = Bt + (size_t)(n0 + srow) * 512 + k0 + scol;
        const short* gb1 = Bt + (size_t)(n0 + 64 + srow) * 512 + k0 + scol;
        __builtin_amdgcn_global_load_lds((const __attribute__((address_space(1))) void*)ga0,
            (__attribute__((address_space(3))) void*)(sA + wave * 512), 16, 0, 0);
        __builtin_amdgcn_global_load_lds((const __attribute__((address_space(1))) void*)ga1,
            (__attribute__((address_space(3))) void*)(sA + 2048 + wave * 512), 16, 0, 0);
        __builtin_amdgcn_global_load_lds((const __attribute__((address_space(1))) void*)gb0,
            (__attribute__((address_space(3))) void*)(sB + wave * 512), 16, 0, 0);
        __builtin_amdgcn_global_load_lds((const __attribute__((address_space(1))) void*)gb1,
            (__attribute__((address_space(3))) void*)(sB + 2048 + wave * 512), 16, 0, 0);
        __syncthreads();

        bf16x8 af[4], bfr[4];
#pragma unroll
        for (int m = 0; m < 4; m++)
            af[m] = *(const bf16x8*)(sA + (wm * 64 + m * 16 + fr) * 32 + fq * 8);
#pragma unroll
        for (int n = 0; n < 4; n++)
            bfr[n] = *(const bf16x8*)(sB + (wn * 64 + n * 16 + fr) * 32 + fq * 8);
#pragma unroll
        for (int m = 0; m < 4; m++)
#pragma unroll
            for (int n = 0; n < 4; n++)
                acc[m][n] = __builtin_amdgcn_mfma_f32_16x16x32_bf16(af[m], bfr[n], acc[m][n], 0, 0, 0);
        __syncthreads();
    }

#pragma unroll
    for (int n = 0; n < 4; n++) {
        int gcol = h * 512 + n0 + wn * 64 + n * 16 + fr;
        float bv = b1[gcol];
#pragma unroll
        for (int m = 0; m < 4; m++) {
#pragma unroll
            for (int j = 0; j < 4; j++) {
                int grow = m0 + wm * 64 + m * 16 + fq * 4 + j;
                float v = acc[m][n][j] + bv;
                h1b[(size_t)grow * 2048 + gcol] = f2bf(v > 0.f ? v : 0.f);
            }
        }
    }
}

// ---------------- edge softmax helpers ----------------
__device__ __forceinline__ unsigned f2ord(float f) {
    unsigned u = __float_as_uint(f);
    return (u & 0x80000000u) ? ~u : (u | 0x80000000u);
}
__device__ __forceinline__ float ord2f(unsigned o) {
    unsigned u = (o & 0x80000000u) ? (o & 0x7FFFFFFFu) : ~o;
    return __uint_as_float(u);
}

template <int C>
__global__ void edge_logits(const int* __restrict__ src, const int* __restrict__ dst,
                            const float* __restrict__ el, const float* __restrict__ er,
                            float* __restrict__ ebuf, unsigned* __restrict__ emax, int E)
{
    int idx = blockIdx.x * blockDim.x + threadIdx.x;
    if (idx >= E * C) return;
    int e = idx / C, c = idx % C;
    float v = el[src[e] * C + c] + er[dst[e] * C + c];
    v = v > 0.f ? v : 0.2f * v;   // leaky_relu, slope 0.2
    ebuf[idx] = v;
    atomicMax(&emax[dst[e] * C + c], f2ord(v));
}

__global__ void finalize_max(const unsigned* __restrict__ emo, float* __restrict__ emf, int NC)
{
    int i = blockIdx.x * blockDim.x + threadIdx.x;
    if (i < NC) {
        float v = ord2f(emo[i]);
        emf[i] = isfinite(v) ? v : 0.f;
    }
}

template <int C>
__global__ void edge_exp(const int* __restrict__ dst, float* __restrict__ ebuf,
                         const float* __restrict__ emf, float* __restrict__ denom, int E)
{
    int idx = blockIdx.x * blockDim.x + threadIdx.x;
    if (idx >= E * C) return;
    int e = idx / C, c = idx % C;
    int d = dst[e];
    float ex = expf(ebuf[idx] - emf[d * C + c]);
    ebuf[idx] = ex;
    atomicAdd(&denom[d * C + c], ex);
}

// ---------------- CSR build (by dst) ----------------
__global__ void hist_kernel(const int* __restrict__ dst, int* __restrict__ deg, int E)
{
    int e = blockIdx.x * blockDim.x + threadIdx.x;
    if (e < E) atomicAdd(&deg[dst[e]], 1);
}

__global__ __launch_bounds__(1024) void scan_excl(const int* __restrict__ deg,
                                                  int* __restrict__ off, int N)
{
    __shared__ int part[1024];
    int t = threadIdx.x;
    int chunk = N >> 10;
    int base = t * chunk;
    int local[16];
    int s = 0;
    for (int i = 0; i < chunk; i++) { local[i] = s; s += deg[base + i]; }
    part[t] = s;
    __syncthreads();
    for (int o = 1; o < 1024; o <<= 1) {
        int v = (t >= o) ? part[t - o] : 0;
        __syncthreads();
        part[t] += v;
        __syncthreads();
    }
    int pre = (t == 0) ? 0 : part[t - 1];
    for (int i = 0; i < chunk; i++) off[base + i] = pre + local[i];
    if (t == 1023) off[N] = pre + s;
}

__global__ void scatter_kernel(const int* __restrict__ dst, const int* __restrict__ off,
                               int* __restrict__ cur, int* __restrict__ eid, int E)
{
    int e = blockIdx.x * blockDim.x + threadIdx.x;
    if (e < E) {
        int d = dst[e];
        int p = off[d] + atomicAdd(&cur[d], 1);
        eid[p] = e;
    }
}

// ------- L1 feature aggregation: Acomb[n,h,0:256] = (Σ_e ex_e^h featb[src_e]) / denom
//         Acomb[n,h,256:512] = featb[n]   (residual operand). 1 wave per node. -------
__global__ __launch_bounds__(256) void aggregate_feat(
    const int* __restrict__ off, const int* __restrict__ eid, const int* __restrict__ src,
    const float* __restrict__ ex, const float* __restrict__ denom,
    const short* __restrict__ featb, short* __restrict__ Acomb)
{
    int wv = threadIdx.x >> 6, lane = threadIdx.x & 63;
    int n = blockIdx.x * 4 + wv;
    int k4 = lane * 4;
    float acc[4][4] = {};   // [head][kk]
    int beg = off[n], end = off[n + 1];
    for (int j = beg; j < end; ++j) {
        int e = eid[j];
        float4 a = ((const float4*)ex)[e];
        short4v fv = *(const short4v*)(featb + (size_t)src[e] * 256 + k4);
        float f0 = b2f(fv[0]), f1 = b2f(fv[1]), f2 = b2f(fv[2]), f3 = b2f(fv[3]);
        acc[0][0] = fmaf(a.x, f0, acc[0][0]); acc[0][1] = fmaf(a.x, f1, acc[0][1]);
        acc[0][2] = fmaf(a.x, f2, acc[0][2]); acc[0][3] = fmaf(a.x, f3, acc[0][3]);
        acc[1][0] = fmaf(a.y, f0, acc[1][0]); acc[1][1] = fmaf(a.y, f1, acc[1][1]);
        acc[1][2] = fmaf(a.y, f2, acc[1][2]); acc[1][3] = fmaf(a.y, f3, acc[1][3]);
        acc[2][0] = fmaf(a.z, f0, acc[2][0]); acc[2][1] = fmaf(a.z, f1, acc[2][1]);
        acc[2][2] = fmaf(a.z, f2, acc[2][2]); acc[2][3] = fmaf(a.z, f3, acc[2][3]);
        acc[3][0] = fmaf(a.w, f0, acc[3][0]); acc[3][1] = fmaf(a.w, f1, acc[3][1]);
        acc[3][2] = fmaf(a.w, f2, acc[3][2]); acc[3][3] = fmaf(a.w, f3, acc[3][3]);
    }
    float4 dn = ((const float4*)denom)[n];
    float inv[4] = { 1.f / (dn.x == 0.f ? 1.f : dn.x), 1.f / (dn.y == 0.f ? 1.f : dn.y),
                     1.f / (dn.z == 0.f ? 1.f : dn.z), 1.f / (dn.w == 0.f ? 1.f : dn.w) };
    short4v selfv = *(const short4v*)(featb + (size_t)n * 256 + k4);
#pragma unroll
    for (int h = 0; h < 4; h++) {
        short4v o;
#pragma unroll
        for (int kk = 0; kk < 4; kk++) o[kk] = f2bf(acc[h][kk] * inv[h]);
        *(short4v*)(Acomb + (size_t)n * 2048 + h * 512 + k4) = o;
        *(short4v*)(Acomb + (size_t)n * 2048 + h * 512 + 256 + k4) = selfv;
    }
}

// ------- aggregation L2 on combined z2res[M=N*4, 256] = [z2 | res2+b2] -------
__global__ __launch_bounds__(256) void aggregate2(
    const int* __restrict__ off, const int* __restrict__ eid, const int* __restrict__ src,
    const float* __restrict__ ex, const float* __restrict__ denom,
    const short* __restrict__ z2res, short* __restrict__ h2)
{
    int n = blockIdx.x, t = threadIdx.x;
    int c = t >> 4;                   // channel (p,h) of both cols 2t,2t+1
    int p = t >> 6;
    int rem = (2 * t) & 127;          // col within 128-wide (h,j) block
    float r0 = 0.f, r1 = 0.f;
    int beg = off[n], end = off[n + 1];
    for (int j = beg; j < end; ++j) {
        int e = eid[j];
        unsigned zv = *(const unsigned*)(z2res + ((size_t)src[e] * 4 + p) * 256 + rem);
        float a = ex[e * 16 + c];
        r0 = fmaf(a, b2f((short)(zv & 0xFFFFu)), r0);
        r1 = fmaf(a, b2f((short)(zv >> 16)), r1);
    }
    float dn = denom[n * 16 + c];
    if (dn == 0.f) dn = 1.f;
    float inv = 1.f / dn;
    unsigned rv = *(const unsigned*)(z2res + ((size_t)n * 4 + p) * 256 + 128 + rem);
    float v0 = r0 * inv + b2f((short)(rv & 0xFFFFu));
    float v1 = r1 * inv + b2f((short)(rv >> 16));
    v0 = v0 > 0.f ? v0 : 0.f;
    v1 = v1 > 0.f ? v1 : 0.f;
    unsigned o = ((unsigned)(unsigned short)f2bf(v1) << 16) | (unsigned)(unsigned short)f2bf(v0);
    *(unsigned*)(h2 + (size_t)n * 512 + t * 2) = o;
}

// ---------------- launch ----------------
extern "C" void kernel_launch(void* const* d_in, const int* in_sizes, int n_in,
                              void* d_out, int out_size, void* d_ws, size_t ws_size,
                              hipStream_t stream)
{
    const float* feat  = (const float*)d_in[0];
    const int*   src   = (const int*)d_in[1];
    const int*   dst   = (const int*)d_in[2];
    const float* W1    = (const float*)d_in[3];
    const float* al1   = (const float*)d_in[4];
    const float* ar1   = (const float*)d_in[5];
    const float* resW1 = (const float*)d_in[6];
    const float* b1    = (const float*)d_in[7];
    const float* W2    = (const float*)d_in[8];
    const float* al2   = (const float*)d_in[9];
    const float* ar2   = (const float*)d_in[10];
    const float* resW2 = (const float*)d_in[11];
    const float* b2    = (const float*)d_in[12];
    const float* Wout  = (const float*)d_in[13];
    const float* bout  = (const float*)d_in[14];
    const int N = in_sizes[0] / IN_F;  // 8192
    const int E = in_sizes[1];         // 65536

    // ---- workspace layout (~100 MB) ----
    char* w = (char*)d_ws;
    auto alloc = [&](size_t bytes) -> char* {
        char* p = w;
        w += (bytes + 255) & ~(size_t)255;
        return p;
    };
    short*    Acomb   = (short*)alloc((size_t)N * 2048 * 2);      // 32 MB  [N,4,512]
    short*    h1b     = (short*)alloc((size_t)N * 2048 * 2);      // 32 MB
    short*    featb   = (short*)alloc((size_t)N * 256 * 2);       // 4 MB
    short*    Wcomb   = (short*)alloc((size_t)2048 * 512 * 2);    // 2 MB  [outcol, 512=W1|resW1]
    short*    W2comb  = (short*)alloc((size_t)256 * 512 * 2);     // 256 KB [outcol(z2|res2), 512]
    short*    Wtout   = (short*)alloc((size_t)128 * 512 * 2);
    float*    bias2c  = (float*)alloc((size_t)256 * 4);
    float*    wal1    = (float*)alloc((size_t)256 * 4 * 4);
    float*    war1    = (float*)alloc((size_t)256 * 4 * 4);
    float*    wal2    = (float*)alloc((size_t)512 * 4 * 4);
    float*    war2    = (float*)alloc((size_t)512 * 4 * 4);
    float*    el1     = (float*)alloc((size_t)N * 4 * 4);
    float*    er1     = (float*)alloc((size_t)N * 4 * 4);
    unsigned* emax1o  = (unsigned*)alloc((size_t)N * 4 * 4);
    float*    emax1f  = (float*)alloc((size_t)N * 4 * 4);
    float*    denom1  = (float*)alloc((size_t)N * 4 * 4);
    float*    e1      = (float*)alloc((size_t)E * 4 * 4);
    int*      deg     = (int*)alloc((size_t)N * 4);
    int*      off     = (int*)alloc((size_t)(N + 1) * 4);
    int*      cur     = (int*)alloc((size_t)N * 4);
    int*      eid     = (int*)alloc((size_t)E * 4);
    short*    z2res   = (short*)alloc((size_t)N * 4 * 256 * 2);   // 16 MB
    short*    h2b     = (short*)alloc((size_t)N * 512 * 2);       // 8 MB
    float*    el2     = (float*)alloc((size_t)N * 16 * 4);
    float*    er2     = (float*)alloc((size_t)N * 16 * 4);
    unsigned* emax2o  = (unsigned*)alloc((size_t)N * 16 * 4);
    float*    emax2f  = (float*)alloc((size_t)N * 16 * 4);
    float*    denom2  = (float*)alloc((size_t)N * 16 * 4);
    float*    e2      = (float*)alloc((size_t)E * 16 * 4);        // 4 MB

    dim3 blk(256);

    // ===== CSR build =====
    hipMemsetAsync(deg, 0, (size_t)N * 4, stream);
    hipMemsetAsync(cur, 0, (size_t)N * 4, stream);
    hist_kernel<<<dim3((E + 255) / 256), blk, 0, stream>>>(dst, deg, E);
    scan_excl<<<dim3(1), dim3(1024), 0, stream>>>(deg, off, N);
    scatter_kernel<<<dim3((E + 255) / 256), blk, 0, stream>>>(dst, off, cur, eid, E);

    // ===== conversions & folds =====
    cvt_bf16<<<dim3((N * 256 / 4 + 255) / 256), blk, 0, stream>>>((const float4*)feat, (short4v*)featb, N * 256 / 4);
    // Wcomb rows=outcol(2048), cols: [0:256]=W1^T, [256:512]=resW1^T
    cvt_t_bf16<<<dim3(2048 / 32, 256 / 32), blk, 0, stream>>>(W1,    Wcomb, 256, 2048, 2048, 512, 0);
    cvt_t_bf16<<<dim3(2048 / 32, 256 / 32), blk, 0, stream>>>(resW1, Wcomb, 256, 2048, 2048, 512, 256);
    // W2comb rows 0:128 = W2^T, rows 128:256 = resW2^T (K=512)
    cvt_t_bf16<<<dim3(128 / 32, 512 / 32), blk, 0, stream>>>(W2,    W2comb,             512, 128, 128, 512, 0);
    cvt_t_bf16<<<dim3(128 / 32, 512 / 32), blk, 0, stream>>>(resW2, W2comb + 128 * 512, 512, 128, 128, 512, 0);
    cvt_t_bf16<<<dim3(128 / 32, 512 / 32), blk, 0, stream>>>(Wout,  Wtout, 512, 40, 128, 512, 0);
    fold_aw<<<dim3((256 * 4 * 64 + 255) / 256), blk, 0, stream>>>(W1, al1, ar1, wal1, war1, 256, 512);
    fold_aw<<<dim3((512 * 4 * 64 + 255) / 256), blk, 0, stream>>>(W2, al2, ar2, wal2, war2, 512, 32);
    // combined layer-2 bias: [0:128]=0 (z2), [128:256]=b2 (res2)
    hipMemsetAsync(bias2c, 0, 128 * 4, stream);
    hipMemcpyAsync(bias2c + 128, b2, 128 * 4, hipMemcpyDeviceToDevice, stream);

    // ===== layer 1 =====
    el_er_fold<float><<<dim3(N / 4), blk, 0, stream>>>(feat, (const float4*)wal1, (const float4*)war1, el1, er1, 256);

    hipMemsetAsync(emax1o, 0, (size_t)N * 4 * 4, stream);
    hipMemsetAsync(denom1, 0, (size_t)N * 4 * 4, stream);
    edge_logits<4><<<dim3((E * 4 + 255) / 256), blk, 0, stream>>>(src, dst, el1, er1, e1, emax1o, E);
    finalize_max<<<dim3((N * 4 + 255) / 256), blk, 0, stream>>>(emax1o, emax1f, N * 4);
    edge_exp<4><<<dim3((E * 4 + 255) / 256), blk, 0, stream>>>(dst, e1, emax1f, denom1, E);

    // aggregate features (256-dim, L2-resident) then transform+residual in one batched GEMM
    aggregate_feat<<<dim3(N / 4), blk, 0, stream>>>(off, eid, src, e1, denom1, featb, Acomb);
    gemm_h1<<<dim3(4, N / 128, 4), blk, 0, stream>>>(Acomb, Wcomb, b1, h1b);
    // h1b = bf16 h1 [N,4,512]

    // ===== layer 2 =====
    el_er_fold<short><<<dim3(N * 4 / 4), blk, 0, stream>>>(h1b, (const float4*)wal2, (const float4*)war2, el2, er2, 512);
    // one GEMM: [z2 | res2+b2] = h1 @ [W2 | resW2] (+bias2c)
    gemm_bf16<<<dim3(2, (N * 4) / 128), blk, 0, stream>>>(h1b, W2comb, bias2c, z2res, N * 4, 256, 512, 256, 256, 1);

    hipMemsetAsync(emax2o, 0, (size_t)N * 16 * 4, stream);
    hipMemsetAsync(denom2, 0, (size_t)N * 16 * 4, stream);
    edge_logits<16><<<dim3((E * 16 + 255) / 256), blk, 0, stream>>>(src, dst, el2, er2, e2, emax2o, E);
    finalize_max<<<dim3((N * 16 + 255) / 256), blk, 0, stream>>>(emax2o, emax2f, N * 16);
    edge_exp<16><<<dim3((E * 16 + 255) / 256), blk, 0, stream>>>(dst, e2, emax2f, denom2, E);
    aggregate2<<<dim3(N), blk, 0, stream>>>(off, eid, src, e2, denom2, z2res, h2b);
    // h2b = bf16 h2 [N,512]

    // ===== final linear (MFMA, Wout zero-padded to 128 cols): out = h2 @ Wout + bout =====
    gemm_bf16<<<dim3(1, N / 128), blk, 0, stream>>>(h2b, Wtout, bout, (float*)d_out, N, 128, 512, 40, 40, 0);
}

// Round 8
// 190.069 us; speedup vs baseline: 2.1439x; 1.2702x over previous
//
#include <hip/hip_runtime.h>
#include <cmath>

constexpr int IN_F  = 256;

typedef short bf16x8 __attribute__((ext_vector_type(8)));
typedef short short4v __attribute__((ext_vector_type(4)));
typedef float f32x4 __attribute__((ext_vector_type(4)));

__device__ __forceinline__ short f2bf(float f) {
    unsigned u = __float_as_uint(f);
    unsigned r = (u + 0x7FFFu + ((u >> 16) & 1)) >> 16;  // RNE
    return (short)r;
}
__device__ __forceinline__ float b2f(short s) {
    return __uint_as_float(((unsigned)(unsigned short)s) << 16);
}

// ======== weight transpose to bf16 (device helper) ========
__device__ __forceinline__ void cvt_t_body(
    const float* __restrict__ W, short* __restrict__ Wt, int K, int N,
    int ldwt, int koff, int bk, int bn, int tx, int ty)
{
    __shared__ float tile[32][33];
    for (int i = ty; i < 32; i += 8) {
        int gn = bn + tx;
        tile[i][tx] = (gn < N) ? W[(size_t)(bk + i) * N + gn] : 0.f;
    }
    __syncthreads();
    for (int i = ty; i < 32; i += 8)
        Wt[(size_t)(bn + i) * ldwt + koff + bk + tx] = f2bf(tile[tx][i]);
}

// z=0: W1 -> Wcomb cols[0:256); z=1: resW1 -> Wcomb cols[256:512). K=256,N=2048
__global__ __launch_bounds__(256) void cvt_t_big(
    const float* __restrict__ W1, const float* __restrict__ resW1, short* __restrict__ Wcomb)
{
    const float* W = blockIdx.z ? resW1 : W1;
    int koff = blockIdx.z ? 256 : 0;
    cvt_t_body(W, Wcomb, 256, 2048, 512, koff,
               blockIdx.y * 32, blockIdx.x * 32, threadIdx.x & 31, threadIdx.x >> 5);
}

// z=0: W2 -> W2comb rows[0:128); z=1: resW2 -> W2comb rows[128:256); z=2: Wout(N=40,pad128) -> Wtout
__global__ __launch_bounds__(256) void cvt_t_small(
    const float* __restrict__ W2, const float* __restrict__ resW2,
    const float* __restrict__ Wout, short* __restrict__ W2comb, short* __restrict__ Wtout)
{
    const float* W; short* Wt; int N;
    if (blockIdx.z == 0)      { W = W2;    Wt = W2comb;             N = 128; }
    else if (blockIdx.z == 1) { W = resW2; Wt = W2comb + 128 * 512; N = 128; }
    else                      { W = Wout;  Wt = Wtout;              N = 40;  }
    cvt_t_body(W, Wt, 512, N, 512, 0,
               blockIdx.y * 32, blockIdx.x * 32, threadIdx.x & 31, threadIdx.x >> 5);
}

// ======== fold attention vectors through W (both layers, one wave per output) ========
__global__ __launch_bounds__(256) void fold_combined(
    const float* __restrict__ W1, const float* __restrict__ al1, const float* __restrict__ ar1,
    float* __restrict__ wal1, float* __restrict__ war1,
    const float* __restrict__ W2, const float* __restrict__ al2, const float* __restrict__ ar2,
    float* __restrict__ wal2, float* __restrict__ war2)
{
    int wid  = (blockIdx.x * 256 + threadIdx.x) >> 6;  // 0..3071
    int lane = threadIdx.x & 63;
    const float *W, *al, *ar; float *wal, *war; int klen, idx;
    if (wid < 1024) { W = W1; al = al1; ar = ar1; wal = wal1; war = war1; klen = 512; idx = wid; }
    else            { W = W2; al = al2; ar = ar2; wal = wal2; war = war2; klen = 32;  idx = wid - 1024; }
    int k = idx >> 2, h = idx & 3;
    const float* wr  = W  + (size_t)k * (4 * klen) + h * klen;
    const float* alp = al + h * klen;
    const float* arp = ar + h * klen;
    float sl = 0.f, sr = 0.f;
    for (int j = lane; j < klen; j += 64) {
        float wv = wr[j];
        sl = fmaf(wv, alp[j], sl);
        sr = fmaf(wv, arp[j], sr);
    }
#pragma unroll
    for (int o = 32; o; o >>= 1) { sl += __shfl_down(sl, o); sr += __shfl_down(sr, o); }
    if (lane == 0) { wal[idx] = sl; war[idx] = sr; }
}

// ======== fused: feat -> bf16 + el1/er1 = feat @ wal1/war1 (one wave per row) ========
__global__ __launch_bounds__(256) void feat_cvt_elr(
    const float* __restrict__ feat, const float4* __restrict__ wal, const float4* __restrict__ war,
    short* __restrict__ featb, float* __restrict__ el, float* __restrict__ er)
{
    int row  = blockIdx.x * 4 + (threadIdx.x >> 6);
    int lane = threadIdx.x & 63;
    float4 v = ((const float4*)feat)[(size_t)row * 64 + lane];
    short4v o;
    o[0] = f2bf(v.x); o[1] = f2bf(v.y); o[2] = f2bf(v.z); o[3] = f2bf(v.w);
    *(short4v*)(featb + (size_t)row * 256 + lane * 4) = o;

    float fj[4] = { v.x, v.y, v.z, v.w };
    int k = lane * 4;
    float sl[4] = {}, sr[4] = {};
#pragma unroll
    for (int j = 0; j < 4; j++) {
        float4 wl = wal[k + j], wr = war[k + j];
        sl[0] = fmaf(fj[j], wl.x, sl[0]); sl[1] = fmaf(fj[j], wl.y, sl[1]);
        sl[2] = fmaf(fj[j], wl.z, sl[2]); sl[3] = fmaf(fj[j], wl.w, sl[3]);
        sr[0] = fmaf(fj[j], wr.x, sr[0]); sr[1] = fmaf(fj[j], wr.y, sr[1]);
        sr[2] = fmaf(fj[j], wr.z, sr[2]); sr[3] = fmaf(fj[j], wr.w, sr[3]);
    }
#pragma unroll
    for (int o2 = 32; o2; o2 >>= 1) {
#pragma unroll
        for (int h = 0; h < 4; h++) { sl[h] += __shfl_down(sl[h], o2); sr[h] += __shfl_down(sr[h], o2); }
    }
    if (lane == 0) {
#pragma unroll
        for (int h = 0; h < 4; h++) { el[row * 4 + h] = sl[h]; er[row * 4 + h] = sr[h]; }
    }
}

// ======== el/er for layer 2 from bf16 h1 (one wave per row of [N*4, 512]) ========
__global__ __launch_bounds__(256) void el_er_fold_b(
    const short* __restrict__ X, const float4* __restrict__ wal, const float4* __restrict__ war,
    float* __restrict__ el, float* __restrict__ er)
{
    int row  = blockIdx.x * 4 + (threadIdx.x >> 6);
    int lane = threadIdx.x & 63;
    float sl[4] = {}, sr[4] = {};
    for (int k = lane; k < 512; k += 64) {
        float f = b2f(X[(size_t)row * 512 + k]);
        float4 wl = wal[k], wr = war[k];
        sl[0] = fmaf(f, wl.x, sl[0]); sl[1] = fmaf(f, wl.y, sl[1]);
        sl[2] = fmaf(f, wl.z, sl[2]); sl[3] = fmaf(f, wl.w, sl[3]);
        sr[0] = fmaf(f, wr.x, sr[0]); sr[1] = fmaf(f, wr.y, sr[1]);
        sr[2] = fmaf(f, wr.z, sr[2]); sr[3] = fmaf(f, wr.w, sr[3]);
    }
#pragma unroll
    for (int o = 32; o; o >>= 1) {
#pragma unroll
        for (int h = 0; h < 4; h++) { sl[h] += __shfl_down(sl[h], o); sr[h] += __shfl_down(sr[h], o); }
    }
    if (lane == 0) {
#pragma unroll
        for (int h = 0; h < 4; h++) { el[row * 4 + h] = sl[h]; er[row * 4 + h] = sr[h]; }
    }
}

// ======== bf16 MFMA GEMM: A[M,K] x Bt[N,K]^T -> C[M,*] ========
__global__ __launch_bounds__(256) void gemm_bf16(
    const short* __restrict__ A, const short* __restrict__ Bt,
    const float* __restrict__ bias, void* __restrict__ C,
    int M, int N, int K, int ldc, int nmax, int out_bf16)
{
    __shared__ short sA[128 * 32];
    __shared__ short sB[128 * 32];
    const int tid  = threadIdx.x;
    const int wave = tid >> 6, lane = tid & 63;
    const int wm = wave >> 1, wn = wave & 1;
    const int m0 = blockIdx.y * 128, n0 = blockIdx.x * 128;

    const int srow = tid >> 2;
    const int scol = (tid & 3) * 8;
    const int fr = lane & 15;
    const int fq = lane >> 4;

    f32x4 acc[4][4] = {};

    for (int k0 = 0; k0 < K; k0 += 32) {
        const short* ga0 = A  + (size_t)(m0 + srow) * K + k0 + scol;
        const short* ga1 = A  + (size_t)(m0 + 64 + srow) * K + k0 + scol;
        const short* gb0 = Bt + (size_t)(n0 + srow) * K + k0 + scol;
        const short* gb1 = Bt + (size_t)(n0 + 64 + srow) * K + k0 + scol;
        __builtin_amdgcn_global_load_lds((const __attribute__((address_space(1))) void*)ga0,
            (__attribute__((address_space(3))) void*)(sA + wave * 512), 16, 0, 0);
        __builtin_amdgcn_global_load_lds((const __attribute__((address_space(1))) void*)ga1,
            (__attribute__((address_space(3))) void*)(sA + 2048 + wave * 512), 16, 0, 0);
        __builtin_amdgcn_global_load_lds((const __attribute__((address_space(1))) void*)gb0,
            (__attribute__((address_space(3))) void*)(sB + wave * 512), 16, 0, 0);
        __builtin_amdgcn_global_load_lds((const __attribute__((address_space(1))) void*)gb1,
            (__attribute__((address_space(3))) void*)(sB + 2048 + wave * 512), 16, 0, 0);
        __syncthreads();

        bf16x8 af[4], bfr[4];
#pragma unroll
        for (int m = 0; m < 4; m++)
            af[m] = *(const bf16x8*)(sA + (wm * 64 + m * 16 + fr) * 32 + fq * 8);
#pragma unroll
        for (int n = 0; n < 4; n++)
            bfr[n] = *(const bf16x8*)(sB + (wn * 64 + n * 16 + fr) * 32 + fq * 8);
#pragma unroll
        for (int m = 0; m < 4; m++)
#pragma unroll
            for (int n = 0; n < 4; n++)
                acc[m][n] = __builtin_amdgcn_mfma_f32_16x16x32_bf16(af[m], bfr[n], acc[m][n], 0, 0, 0);
        __syncthreads();
    }

#pragma unroll
    for (int n = 0; n < 4; n++) {
        int gcol = n0 + wn * 64 + n * 16 + fr;
        if (gcol >= nmax) continue;
        float bv = bias ? bias[gcol] : 0.f;
#pragma unroll
        for (int m = 0; m < 4; m++) {
#pragma unroll
            for (int j = 0; j < 4; j++) {
                int grow = m0 + wm * 64 + m * 16 + fq * 4 + j;
                float v = acc[m][n][j] + bv;
                if (out_bf16) ((short*)C)[(size_t)grow * ldc + gcol] = f2bf(v);
                else          ((float*)C)[(size_t)grow * ldc + gcol] = v;
            }
        }
    }
}

// ======== batched-by-head GEMM: h1 = relu(Acomb_h @ Wcomb_h^T + b1) ========
__global__ __launch_bounds__(256) void gemm_h1(
    const short* __restrict__ Acomb, const short* __restrict__ Wcomb,
    const float* __restrict__ b1, short* __restrict__ h1b)
{
    __shared__ short sA[128 * 32];
    __shared__ short sB[128 * 32];
    const int tid  = threadIdx.x;
    const int wave = tid >> 6, lane = tid & 63;
    const int wm = wave >> 1, wn = wave & 1;
    const int h  = blockIdx.z;
    const int m0 = blockIdx.y * 128, n0 = blockIdx.x * 128;
    const short* A  = Acomb + h * 512;
    const short* Bt = Wcomb + (size_t)(h * 512) * 512;

    const int srow = tid >> 2;
    const int scol = (tid & 3) * 8;
    const int fr = lane & 15;
    const int fq = lane >> 4;

    f32x4 acc[4][4] = {};

    for (int k0 = 0; k0 < 512; k0 += 32) {
        const short* ga0 = A  + (size_t)(m0 + srow) * 2048 + k0 + scol;
        const short* ga1 = A  + (size_t)(m0 + 64 + srow) * 2048 + k0 + scol;
        const short* gb0 = Bt + (size_t)(n0 + srow) * 512 + k0 + scol;
        const short* gb1 = Bt + (size_t)(n0 + 64 + srow) * 512 + k0 + scol;
        __builtin_amdgcn_global_load_lds((const __attribute__((address_space(1))) void*)ga0,
            (__attribute__((address_space(3))) void*)(sA + wave * 512), 16, 0, 0);
        __builtin_amdgcn_global_load_lds((const __attribute__((address_space(1))) void*)ga1,
            (__attribute__((address_space(3))) void*)(sA + 2048 + wave * 512), 16, 0, 0);
        __builtin_amdgcn_global_load_lds((const __attribute__((address_space(1))) void*)gb0,
            (__attribute__((address_space(3))) void*)(sB + wave * 512), 16, 0, 0);
        __builtin_amdgcn_global_load_lds((const __attribute__((address_space(1))) void*)gb1,
            (__attribute__((address_space(3))) void*)(sB + 2048 + wave * 512), 16, 0, 0);
        __syncthreads();

        bf16x8 af[4], bfr[4];
#pragma unroll
        for (int m = 0; m < 4; m++)
            af[m] = *(const bf16x8*)(sA + (wm * 64 + m * 16 + fr) * 32 + fq * 8);
#pragma unroll
        for (int n = 0; n < 4; n++)
            bfr[n] = *(const bf16x8*)(sB + (wn * 64 + n * 16 + fr) * 32 + fq * 8);
#pragma unroll
        for (int m = 0; m < 4; m++)
#pragma unroll
            for (int n = 0; n < 4; n++)
                acc[m][n] = __builtin_amdgcn_mfma_f32_16x16x32_bf16(af[m], bfr[n], acc[m][n], 0, 0, 0);
        __syncthreads();
    }

#pragma unroll
    for (int n = 0; n < 4; n++) {
        int gcol = h * 512 + n0 + wn * 64 + n * 16 + fr;
        float bv = b1[gcol];
#pragma unroll
        for (int m = 0; m < 4; m++) {
#pragma unroll
            for (int j = 0; j < 4; j++) {
                int grow = m0 + wm * 64 + m * 16 + fq * 4 + j;
                float v = acc[m][n][j] + bv;
                h1b[(size_t)grow * 2048 + gcol] = f2bf(v > 0.f ? v : 0.f);
            }
        }
    }
}

// ======== CSR build (by dst) ========
__global__ void hist_kernel(const int* __restrict__ dst, int* __restrict__ deg, int E)
{
    int e = blockIdx.x * blockDim.x + threadIdx.x;
    if (e < E) atomicAdd(&deg[dst[e]], 1);
}

__global__ __launch_bounds__(1024) void scan_excl(const int* __restrict__ deg,
                                                  int* __restrict__ off, int N)
{
    __shared__ int part[1024];
    int t = threadIdx.x;
    int chunk = N >> 10;
    int base = t * chunk;
    int local[16];
    int s = 0;
    for (int i = 0; i < chunk; i++) { local[i] = s; s += deg[base + i]; }
    part[t] = s;
    __syncthreads();
    for (int o = 1; o < 1024; o <<= 1) {
        int v = (t >= o) ? part[t - o] : 0;
        __syncthreads();
        part[t] += v;
        __syncthreads();
    }
    int pre = (t == 0) ? 0 : part[t - 1];
    for (int i = 0; i < chunk; i++) off[base + i] = pre + local[i];
    if (t == 1023) off[N] = pre + s;
}

__global__ void scatter_kernel(const int* __restrict__ dst, const int* __restrict__ off,
                               int* __restrict__ cur, int* __restrict__ eid, int E)
{
    int e = blockIdx.x * blockDim.x + threadIdx.x;
    if (e < E) {
        int d = dst[e];
        int p = off[d] + atomicAdd(&cur[d], 1);
        eid[p] = e;
    }
}

// ======== bias2c init: [0:128)=0, [128:256)=b2 ========
__global__ void bias_init(const float* __restrict__ b2, float* __restrict__ bias2c)
{
    int t = threadIdx.x;
    bias2c[t] = (t < 128) ? 0.f : b2[t - 128];
}

// ======== L1: fused edge-softmax + feature aggregation (1 wave per node) ========
// Acomb[n,h,0:256] = (sum_e a_e^h * featb[src_e]) / denom_h ; Acomb[n,h,256:512] = featb[n]
// a_e^h = exp(leaky_relu(el[src_e,h] + er[n,h]))  (softmax shift-invariant; no max pass)
__global__ __launch_bounds__(256) void aggregate_feat_sm(
    const int* __restrict__ off, const int* __restrict__ eid, const int* __restrict__ src,
    const float* __restrict__ el, const float* __restrict__ er,
    const short* __restrict__ featb, short* __restrict__ Acomb)
{
    int wv = threadIdx.x >> 6, lane = threadIdx.x & 63;
    int n = blockIdx.x * 4 + wv;
    int k4 = lane * 4;
    float4 erv = ((const float4*)er)[n];
    float acc[4][4] = {};   // [head][kk]
    float accd[4] = {};     // denominators
    int beg = off[n], end = off[n + 1];
    for (int j = beg; j < end; ++j) {
        int e = eid[j];
        int s = src[e];
        float4 elv = ((const float4*)el)[s];
        float a0 = elv.x + erv.x, a1 = elv.y + erv.y, a2 = elv.z + erv.z, a3 = elv.w + erv.w;
        a0 = __expf(a0 > 0.f ? a0 : 0.2f * a0);
        a1 = __expf(a1 > 0.f ? a1 : 0.2f * a1);
        a2 = __expf(a2 > 0.f ? a2 : 0.2f * a2);
        a3 = __expf(a3 > 0.f ? a3 : 0.2f * a3);
        accd[0] += a0; accd[1] += a1; accd[2] += a2; accd[3] += a3;
        short4v fv = *(const short4v*)(featb + (size_t)s * 256 + k4);
        float f0 = b2f(fv[0]), f1 = b2f(fv[1]), f2 = b2f(fv[2]), f3 = b2f(fv[3]);
        acc[0][0] = fmaf(a0, f0, acc[0][0]); acc[0][1] = fmaf(a0, f1, acc[0][1]);
        acc[0][2] = fmaf(a0, f2, acc[0][2]); acc[0][3] = fmaf(a0, f3, acc[0][3]);
        acc[1][0] = fmaf(a1, f0, acc[1][0]); acc[1][1] = fmaf(a1, f1, acc[1][1]);
        acc[1][2] = fmaf(a1, f2, acc[1][2]); acc[1][3] = fmaf(a1, f3, acc[1][3]);
        acc[2][0] = fmaf(a2, f0, acc[2][0]); acc[2][1] = fmaf(a2, f1, acc[2][1]);
        acc[2][2] = fmaf(a2, f2, acc[2][2]); acc[2][3] = fmaf(a2, f3, acc[2][3]);
        acc[3][0] = fmaf(a3, f0, acc[3][0]); acc[3][1] = fmaf(a3, f1, acc[3][1]);
        acc[3][2] = fmaf(a3, f2, acc[3][2]); acc[3][3] = fmaf(a3, f3, acc[3][3]);
    }
    float inv[4];
#pragma unroll
    for (int h = 0; h < 4; h++) inv[h] = 1.f / (accd[h] == 0.f ? 1.f : accd[h]);
    short4v selfv = *(const short4v*)(featb + (size_t)n * 256 + k4);
#pragma unroll
    for (int h = 0; h < 4; h++) {
        short4v o;
#pragma unroll
        for (int kk = 0; kk < 4; kk++) o[kk] = f2bf(acc[h][kk] * inv[h]);
        *(short4v*)(Acomb + (size_t)n * 2048 + h * 512 + k4) = o;
        *(short4v*)(Acomb + (size_t)n * 2048 + h * 512 + 256 + k4) = selfv;
    }
}

// ======== L2: fused edge-softmax + aggregation on z2res[M=N*4,256]=[z2|res2+b2] ========
__global__ __launch_bounds__(256) void aggregate2_sm(
    const int* __restrict__ off, const int* __restrict__ eid, const int* __restrict__ src,
    const float* __restrict__ el, const float* __restrict__ er,
    const short* __restrict__ z2res, short* __restrict__ h2)
{
    int n = blockIdx.x, t = threadIdx.x;
    int c = t >> 4;                   // channel (p,h) of cols 2t,2t+1
    int p = t >> 6;
    int rem = (2 * t) & 127;          // col within p's 128-wide z2 block
    float erv = er[n * 16 + c];
    float r0 = 0.f, r1 = 0.f, dn = 0.f;
    int beg = off[n], end = off[n + 1];
    for (int j = beg; j < end; ++j) {
        int e = eid[j];
        int s = src[e];
        float lv = el[s * 16 + c] + erv;
        float a = __expf(lv > 0.f ? lv : 0.2f * lv);
        dn += a;
        unsigned zv = *(const unsigned*)(z2res + ((size_t)s * 4 + p) * 256 + rem);
        r0 = fmaf(a, b2f((short)(zv & 0xFFFFu)), r0);
        r1 = fmaf(a, b2f((short)(zv >> 16)), r1);
    }
    if (dn == 0.f) dn = 1.f;
    float inv = 1.f / dn;
    unsigned rv = *(const unsigned*)(z2res + ((size_t)n * 4 + p) * 256 + 128 + rem);
    float v0 = r0 * inv + b2f((short)(rv & 0xFFFFu));
    float v1 = r1 * inv + b2f((short)(rv >> 16));
    v0 = v0 > 0.f ? v0 : 0.f;
    v1 = v1 > 0.f ? v1 : 0.f;
    unsigned o = ((unsigned)(unsigned short)f2bf(v1) << 16) | (unsigned)(unsigned short)f2bf(v0);
    *(unsigned*)(h2 + (size_t)n * 512 + t * 2) = o;
}

// ======== launch ========
extern "C" void kernel_launch(void* const* d_in, const int* in_sizes, int n_in,
                              void* d_out, int out_size, void* d_ws, size_t ws_size,
                              hipStream_t stream)
{
    const float* feat  = (const float*)d_in[0];
    const int*   src   = (const int*)d_in[1];
    const int*   dst   = (const int*)d_in[2];
    const float* W1    = (const float*)d_in[3];
    const float* al1   = (const float*)d_in[4];
    const float* ar1   = (const float*)d_in[5];
    const float* resW1 = (const float*)d_in[6];
    const float* b1    = (const float*)d_in[7];
    const float* W2    = (const float*)d_in[8];
    const float* al2   = (const float*)d_in[9];
    const float* ar2   = (const float*)d_in[10];
    const float* resW2 = (const float*)d_in[11];
    const float* b2    = (const float*)d_in[12];
    const float* Wout  = (const float*)d_in[13];
    const float* bout  = (const float*)d_in[14];
    const int N = in_sizes[0] / IN_F;  // 8192
    const int E = in_sizes[1];         // 65536

    // ---- workspace layout (~95 MB) ----
    char* w = (char*)d_ws;
    auto alloc = [&](size_t bytes) -> char* {
        char* p = w;
        w += (bytes + 255) & ~(size_t)255;
        return p;
    };
    short*    Acomb   = (short*)alloc((size_t)N * 2048 * 2);      // 32 MB
    short*    h1b     = (short*)alloc((size_t)N * 2048 * 2);      // 32 MB
    short*    featb   = (short*)alloc((size_t)N * 256 * 2);       // 4 MB
    short*    Wcomb   = (short*)alloc((size_t)2048 * 512 * 2);    // 2 MB
    short*    W2comb  = (short*)alloc((size_t)256 * 512 * 2);
    short*    Wtout   = (short*)alloc((size_t)128 * 512 * 2);
    float*    bias2c  = (float*)alloc((size_t)256 * 4);
    float*    wal1    = (float*)alloc((size_t)256 * 4 * 4);
    float*    war1    = (float*)alloc((size_t)256 * 4 * 4);
    float*    wal2    = (float*)alloc((size_t)512 * 4 * 4);
    float*    war2    = (float*)alloc((size_t)512 * 4 * 4);
    float*    el1     = (float*)alloc((size_t)N * 4 * 4);
    float*    er1     = (float*)alloc((size_t)N * 4 * 4);
    int*      deg     = (int*)alloc((size_t)N * 4);               // deg+cur contiguous:
    int*      cur     = (int*)alloc((size_t)N * 4);               //   one memset covers both
    int*      off     = (int*)alloc((size_t)(N + 1) * 4);
    int*      eid     = (int*)alloc((size_t)E * 4);
    short*    z2res   = (short*)alloc((size_t)N * 4 * 256 * 2);   // 16 MB
    short*    h2b     = (short*)alloc((size_t)N * 512 * 2);       // 8 MB
    float*    el2     = (float*)alloc((size_t)N * 16 * 4);
    float*    er2     = (float*)alloc((size_t)N * 16 * 4);

    dim3 blk(256);

    // ===== CSR build =====
    hipMemsetAsync(deg, 0, (size_t)2 * N * 4, stream);   // deg + cur
    hist_kernel<<<dim3((E + 255) / 256), blk, 0, stream>>>(dst, deg, E);
    scan_excl<<<dim3(1), dim3(1024), 0, stream>>>(deg, off, N);
    scatter_kernel<<<dim3((E + 255) / 256), blk, 0, stream>>>(dst, off, cur, eid, E);

    // ===== weight prep (independent of CSR) =====
    fold_combined<<<dim3(768), blk, 0, stream>>>(W1, al1, ar1, wal1, war1,
                                                 W2, al2, ar2, wal2, war2);
    cvt_t_big<<<dim3(2048 / 32, 256 / 32, 2), blk, 0, stream>>>(W1, resW1, Wcomb);
    cvt_t_small<<<dim3(128 / 32, 512 / 32, 3), blk, 0, stream>>>(W2, resW2, Wout, W2comb, Wtout);
    bias_init<<<dim3(1), blk, 0, stream>>>(b2, bias2c);

    // ===== layer 1 =====
    feat_cvt_elr<<<dim3(N / 4), blk, 0, stream>>>(feat, (const float4*)wal1, (const float4*)war1,
                                                  featb, el1, er1);
    aggregate_feat_sm<<<dim3(N / 4), blk, 0, stream>>>(off, eid, src, el1, er1, featb, Acomb);
    gemm_h1<<<dim3(4, N / 128, 4), blk, 0, stream>>>(Acomb, Wcomb, b1, h1b);
    // h1b = bf16 h1 [N,4,512]

    // ===== layer 2 =====
    el_er_fold_b<<<dim3(N * 4 / 4), blk, 0, stream>>>(h1b, (const float4*)wal2, (const float4*)war2,
                                                      el2, er2);
    gemm_bf16<<<dim3(2, (N * 4) / 128), blk, 0, stream>>>(h1b, W2comb, bias2c, z2res,
                                                          N * 4, 256, 512, 256, 256, 1);
    aggregate2_sm<<<dim3(N), blk, 0, stream>>>(off, eid, src, el2, er2, z2res, h2b);
    // h2b = bf16 h2 [N,512]

    // ===== final linear =====
    gemm_bf16<<<dim3(1, N / 128), blk, 0, stream>>>(h2b, Wtout, bout, (float*)d_out,
                                                    N, 128, 512, 40, 40, 0);
}

// Round 9
// 168.592 us; speedup vs baseline: 2.4170x; 1.1274x over previous
//
#include <hip/hip_runtime.h>
#include <cmath>

constexpr int IN_F  = 256;

typedef short bf16x8 __attribute__((ext_vector_type(8)));
typedef short short4v __attribute__((ext_vector_type(4)));
typedef float f32x4 __attribute__((ext_vector_type(4)));

__device__ __forceinline__ short f2bf(float f) {
    unsigned u = __float_as_uint(f);
    unsigned r = (u + 0x7FFFu + ((u >> 16) & 1)) >> 16;  // RNE
    return (short)r;
}
__device__ __forceinline__ float b2f(short s) {
    return __uint_as_float(((unsigned)(unsigned short)s) << 16);
}

// ======== XCD-chunked block swizzle (T1): logical tile id for this block ========
// nwg must be %8==0 (all our grids are). Consecutive logical ids -> same XCD.
__device__ __forceinline__ int xcd_logical_id()
{
    int nx = gridDim.x, ny = gridDim.y, nz = gridDim.z;
    int flat = blockIdx.x + nx * (blockIdx.y + ny * blockIdx.z);
    int nwg = nx * ny * nz;
    if (nwg & 7) return flat;
    int chunk = nwg >> 3;
    return (flat & 7) * chunk + (flat >> 3);
}

// ======== weight transpose to bf16 (device helper; 32x32 tile) ========
__device__ __forceinline__ void cvt_t_body(
    const float* __restrict__ W, short* __restrict__ Wt, int K, int N,
    int ldwt, int koff, int bk, int bn, int tx, int ty)
{
    __shared__ float tile[32][33];
    for (int i = ty; i < 32; i += 8) {
        int gn = bn + tx;
        tile[i][tx] = (gn < N) ? W[(size_t)(bk + i) * N + gn] : 0.f;
    }
    __syncthreads();
    for (int i = ty; i < 32; i += 8)
        Wt[(size_t)(bn + i) * ldwt + koff + bk + tx] = f2bf(tile[tx][i]);
}

// ======== mega prep kernel: fold + weight cvt + bias2c + zero(deg,cur) ========
// grid partition: [0,768) fold ; [768,1792) cvt_big ; [1792,1984) cvt_small ;
//                 1984 bias ; [1985,2001) zero 64KB at zero_base
__global__ __launch_bounds__(256) void prep_all(
    const float* __restrict__ W1, const float* __restrict__ al1, const float* __restrict__ ar1,
    const float* __restrict__ W2, const float* __restrict__ al2, const float* __restrict__ ar2,
    const float* __restrict__ resW1, const float* __restrict__ resW2,
    const float* __restrict__ Wout, const float* __restrict__ b2,
    short* __restrict__ Wcomb, short* __restrict__ W2comb, short* __restrict__ Wtout,
    float* __restrict__ wal1, float* __restrict__ war1,
    float* __restrict__ wal2, float* __restrict__ war2,
    float* __restrict__ bias2c, int* __restrict__ zero_base)
{
    int bid = blockIdx.x;
    int t   = threadIdx.x;
    if (bid < 768) {
        // ---- fold attention vectors through W (one wave per (k,h) output) ----
        int wid  = (bid * 256 + t) >> 6;  // 0..3071
        int lane = t & 63;
        const float *W, *al, *ar; float *wal, *war; int klen, idx;
        if (wid < 1024) { W = W1; al = al1; ar = ar1; wal = wal1; war = war1; klen = 512; idx = wid; }
        else            { W = W2; al = al2; ar = ar2; wal = wal2; war = war2; klen = 32;  idx = wid - 1024; }
        int k = idx >> 2, h = idx & 3;
        const float* wr  = W  + (size_t)k * (4 * klen) + h * klen;
        const float* alp = al + h * klen;
        const float* arp = ar + h * klen;
        float sl = 0.f, sr = 0.f;
        for (int j = lane; j < klen; j += 64) {
            float wv = wr[j];
            sl = fmaf(wv, alp[j], sl);
            sr = fmaf(wv, arp[j], sr);
        }
#pragma unroll
        for (int o = 32; o; o >>= 1) { sl += __shfl_down(sl, o); sr += __shfl_down(sr, o); }
        if (lane == 0) { wal[idx] = sl; war[idx] = sr; }
    } else if (bid < 1792) {
        // ---- W1/resW1 -> Wcomb [2048 rows, 512] (cols 0:256 / 256:512) ----
        int id = bid - 768;               // 1024 blocks: x=64, y=8, z=2
        int bx = id & 63, by = (id >> 6) & 7, bz = id >> 9;
        const float* W = bz ? resW1 : W1;
        cvt_t_body(W, Wcomb, 256, 2048, 512, bz ? 256 : 0,
                   by * 32, bx * 32, t & 31, t >> 5);
    } else if (bid < 1984) {
        // ---- W2/resW2 -> W2comb rows 0:128/128:256 ; Wout -> Wtout (pad 128) ----
        int id = bid - 1792;              // 192 blocks: x=4, y=16, z=3
        int bx = id & 3, by = (id >> 2) & 15, bz = id >> 6;
        const float* W; short* Wt; int N;
        if (bz == 0)      { W = W2;    Wt = W2comb;             N = 128; }
        else if (bz == 1) { W = resW2; Wt = W2comb + 128 * 512; N = 128; }
        else              { W = Wout;  Wt = Wtout;              N = 40;  }
        cvt_t_body(W, Wt, 512, N, 512, 0, by * 32, bx * 32, t & 31, t >> 5);
    } else if (bid == 1984) {
        // ---- bias2c: [0:128)=0, [128:256)=b2 ----
        bias2c[t] = (t < 128) ? 0.f : b2[t - 128];
    } else {
        // ---- zero deg+cur (64KB) ----
        int b = bid - 1985;               // 16 blocks * 256 thr * 16B
        int4 z; z.x = 0; z.y = 0; z.z = 0; z.w = 0;
        ((int4*)zero_base)[(size_t)b * 256 + t] = z;
    }
}

// ======== fused: feat -> bf16 + el1/er1 = feat @ wal1/war1 (one wave per row) ========
__global__ __launch_bounds__(256) void feat_cvt_elr(
    const float* __restrict__ feat, const float4* __restrict__ wal, const float4* __restrict__ war,
    short* __restrict__ featb, float* __restrict__ el, float* __restrict__ er)
{
    int row  = blockIdx.x * 4 + (threadIdx.x >> 6);
    int lane = threadIdx.x & 63;
    float4 v = ((const float4*)feat)[(size_t)row * 64 + lane];
    short4v o;
    o[0] = f2bf(v.x); o[1] = f2bf(v.y); o[2] = f2bf(v.z); o[3] = f2bf(v.w);
    *(short4v*)(featb + (size_t)row * 256 + lane * 4) = o;

    float fj[4] = { v.x, v.y, v.z, v.w };
    int k = lane * 4;
    float sl[4] = {}, sr[4] = {};
#pragma unroll
    for (int j = 0; j < 4; j++) {
        float4 wl = wal[k + j], wr = war[k + j];
        sl[0] = fmaf(fj[j], wl.x, sl[0]); sl[1] = fmaf(fj[j], wl.y, sl[1]);
        sl[2] = fmaf(fj[j], wl.z, sl[2]); sl[3] = fmaf(fj[j], wl.w, sl[3]);
        sr[0] = fmaf(fj[j], wr.x, sr[0]); sr[1] = fmaf(fj[j], wr.y, sr[1]);
        sr[2] = fmaf(fj[j], wr.z, sr[2]); sr[3] = fmaf(fj[j], wr.w, sr[3]);
    }
#pragma unroll
    for (int o2 = 32; o2; o2 >>= 1) {
#pragma unroll
        for (int h = 0; h < 4; h++) { sl[h] += __shfl_down(sl[h], o2); sr[h] += __shfl_down(sr[h], o2); }
    }
    if (lane == 0) {
#pragma unroll
        for (int h = 0; h < 4; h++) { el[row * 4 + h] = sl[h]; er[row * 4 + h] = sr[h]; }
    }
}

// ======== el/er for layer 2 from bf16 h1 (one wave per row of [N*4, 512]) ========
__global__ __launch_bounds__(256) void el_er_fold_b(
    const short* __restrict__ X, const float4* __restrict__ wal, const float4* __restrict__ war,
    float* __restrict__ el, float* __restrict__ er)
{
    int row  = blockIdx.x * 4 + (threadIdx.x >> 6);
    int lane = threadIdx.x & 63;
    float sl[4] = {}, sr[4] = {};
    for (int k = lane; k < 512; k += 64) {
        float f = b2f(X[(size_t)row * 512 + k]);
        float4 wl = wal[k], wr = war[k];
        sl[0] = fmaf(f, wl.x, sl[0]); sl[1] = fmaf(f, wl.y, sl[1]);
        sl[2] = fmaf(f, wl.z, sl[2]); sl[3] = fmaf(f, wl.w, sl[3]);
        sr[0] = fmaf(f, wr.x, sr[0]); sr[1] = fmaf(f, wr.y, sr[1]);
        sr[2] = fmaf(f, wr.z, sr[2]); sr[3] = fmaf(f, wr.w, sr[3]);
    }
#pragma unroll
    for (int o = 32; o; o >>= 1) {
#pragma unroll
        for (int h = 0; h < 4; h++) { sl[h] += __shfl_down(sl[h], o); sr[h] += __shfl_down(sr[h], o); }
    }
    if (lane == 0) {
#pragma unroll
        for (int h = 0; h < 4; h++) { el[row * 4 + h] = sl[h]; er[row * 4 + h] = sr[h]; }
    }
}

// ======== bf16 MFMA GEMM: A[M,K] x Bt[N,K]^T -> C[M,*] (XCD-swizzled) ========
__global__ __launch_bounds__(256) void gemm_bf16(
    const short* __restrict__ A, const short* __restrict__ Bt,
    const float* __restrict__ bias, void* __restrict__ C,
    int M, int N, int K, int ldc, int nmax, int out_bf16)
{
    __shared__ short sA[128 * 32];
    __shared__ short sB[128 * 32];
    const int tid  = threadIdx.x;
    const int wave = tid >> 6, lane = tid & 63;
    const int wm = wave >> 1, wn = wave & 1;
    int lid = xcd_logical_id();
    const int bx = lid % gridDim.x, by = lid / gridDim.x;
    const int m0 = by * 128, n0 = bx * 128;

    const int srow = tid >> 2;
    const int scol = (tid & 3) * 8;
    const int fr = lane & 15;
    const int fq = lane >> 4;

    f32x4 acc[4][4] = {};

    for (int k0 = 0; k0 < K; k0 += 32) {
        const short* ga0 = A  + (size_t)(m0 + srow) * K + k0 + scol;
        const short* ga1 = A  + (size_t)(m0 + 64 + srow) * K + k0 + scol;
        const short* gb0 = Bt + (size_t)(n0 + srow) * K + k0 + scol;
        const short* gb1 = Bt + (size_t)(n0 + 64 + srow) * K + k0 + scol;
        __builtin_amdgcn_global_load_lds((const __attribute__((address_space(1))) void*)ga0,
            (__attribute__((address_space(3))) void*)(sA + wave * 512), 16, 0, 0);
        __builtin_amdgcn_global_load_lds((const __attribute__((address_space(1))) void*)ga1,
            (__attribute__((address_space(3))) void*)(sA + 2048 + wave * 512), 16, 0, 0);
        __builtin_amdgcn_global_load_lds((const __attribute__((address_space(1))) void*)gb0,
            (__attribute__((address_space(3))) void*)(sB + wave * 512), 16, 0, 0);
        __builtin_amdgcn_global_load_lds((const __attribute__((address_space(1))) void*)gb1,
            (__attribute__((address_space(3))) void*)(sB + 2048 + wave * 512), 16, 0, 0);
        __syncthreads();

        bf16x8 af[4], bfr[4];
#pragma unroll
        for (int m = 0; m < 4; m++)
            af[m] = *(const bf16x8*)(sA + (wm * 64 + m * 16 + fr) * 32 + fq * 8);
#pragma unroll
        for (int n = 0; n < 4; n++)
            bfr[n] = *(const bf16x8*)(sB + (wn * 64 + n * 16 + fr) * 32 + fq * 8);
#pragma unroll
        for (int m = 0; m < 4; m++)
#pragma unroll
            for (int n = 0; n < 4; n++)
                acc[m][n] = __builtin_amdgcn_mfma_f32_16x16x32_bf16(af[m], bfr[n], acc[m][n], 0, 0, 0);
        __syncthreads();
    }

#pragma unroll
    for (int n = 0; n < 4; n++) {
        int gcol = n0 + wn * 64 + n * 16 + fr;
        if (gcol >= nmax) continue;
        float bv = bias ? bias[gcol] : 0.f;
#pragma unroll
        for (int m = 0; m < 4; m++) {
#pragma unroll
            for (int j = 0; j < 4; j++) {
                int grow = m0 + wm * 64 + m * 16 + fq * 4 + j;
                float v = acc[m][n][j] + bv;
                if (out_bf16) ((short*)C)[(size_t)grow * ldc + gcol] = f2bf(v);
                else          ((float*)C)[(size_t)grow * ldc + gcol] = v;
            }
        }
    }
}

// ======== batched-by-head GEMM: h1 = relu(Acomb_h @ Wcomb_h^T + b1) (XCD-swizzled) ========
__global__ __launch_bounds__(256) void gemm_h1(
    const short* __restrict__ Acomb, const short* __restrict__ Wcomb,
    const float* __restrict__ b1, short* __restrict__ h1b)
{
    __shared__ short sA[128 * 32];
    __shared__ short sB[128 * 32];
    const int tid  = threadIdx.x;
    const int wave = tid >> 6, lane = tid & 63;
    const int wm = wave >> 1, wn = wave & 1;
    int lid = xcd_logical_id();                  // grid (4, M/128, 4)
    const int bx = lid & 3;
    const int by = (lid >> 2) % gridDim.y;
    const int h  = lid / (gridDim.y * 4);
    const int m0 = by * 128, n0 = bx * 128;      // n0 in [0,512)
    const short* A  = Acomb + h * 512;
    const short* Bt = Wcomb + (size_t)(h * 512) * 512;

    const int srow = tid >> 2;
    const int scol = (tid & 3) * 8;
    const int fr = lane & 15;
    const int fq = lane >> 4;

    f32x4 acc[4][4] = {};

    for (int k0 = 0; k0 < 512; k0 += 32) {
        const short* ga0 = A  + (size_t)(m0 + srow) * 2048 + k0 + scol;
        const short* ga1 = A  + (size_t)(m0 + 64 + srow) * 2048 + k0 + scol;
        const short* gb0 = Bt + (size_t)(n0 + srow) * 512 + k0 + scol;
        const short* gb1 = Bt + (size_t)(n0 + 64 + srow) * 512 + k0 + scol;
        __builtin_amdgcn_global_load_lds((const __attribute__((address_space(1))) void*)ga0,
            (__attribute__((address_space(3))) void*)(sA + wave * 512), 16, 0, 0);
        __builtin_amdgcn_global_load_lds((const __attribute__((address_space(1))) void*)ga1,
            (__attribute__((address_space(3))) void*)(sA + 2048 + wave * 512), 16, 0, 0);
        __builtin_amdgcn_global_load_lds((const __attribute__((address_space(1))) void*)gb0,
            (__attribute__((address_space(3))) void*)(sB + wave * 512), 16, 0, 0);
        __builtin_amdgcn_global_load_lds((const __attribute__((address_space(1))) void*)gb1,
            (__attribute__((address_space(3))) void*)(sB + 2048 + wave * 512), 16, 0, 0);
        __syncthreads();

        bf16x8 af[4], bfr[4];
#pragma unroll
        for (int m = 0; m < 4; m++)
            af[m] = *(const bf16x8*)(sA + (wm * 64 + m * 16 + fr) * 32 + fq * 8);
#pragma unroll
        for (int n = 0; n < 4; n++)
            bfr[n] = *(const bf16x8*)(sB + (wn * 64 + n * 16 + fr) * 32 + fq * 8);
#pragma unroll
        for (int m = 0; m < 4; m++)
#pragma unroll
            for (int n = 0; n < 4; n++)
                acc[m][n] = __builtin_amdgcn_mfma_f32_16x16x32_bf16(af[m], bfr[n], acc[m][n], 0, 0, 0);
        __syncthreads();
    }

#pragma unroll
    for (int n = 0; n < 4; n++) {
        int gcol = h * 512 + n0 + wn * 64 + n * 16 + fr;
        float bv = b1[gcol];
#pragma unroll
        for (int m = 0; m < 4; m++) {
#pragma unroll
            for (int j = 0; j < 4; j++) {
                int grow = m0 + wm * 64 + m * 16 + fq * 4 + j;
                float v = acc[m][n][j] + bv;
                h1b[(size_t)grow * 2048 + gcol] = f2bf(v > 0.f ? v : 0.f);
            }
        }
    }
}

// ======== CSR build (by dst) ========
__global__ void hist_kernel(const int* __restrict__ dst, int* __restrict__ deg, int E)
{
    int e = blockIdx.x * blockDim.x + threadIdx.x;
    if (e < E) atomicAdd(&deg[dst[e]], 1);
}

__global__ __launch_bounds__(1024) void scan_excl(const int* __restrict__ deg,
                                                  int* __restrict__ off, int N)
{
    __shared__ int part[1024];
    int t = threadIdx.x;
    int chunk = N >> 10;
    int base = t * chunk;
    int local[16];
    int s = 0;
    for (int i = 0; i < chunk; i++) { local[i] = s; s += deg[base + i]; }
    part[t] = s;
    __syncthreads();
    for (int o = 1; o < 1024; o <<= 1) {
        int v = (t >= o) ? part[t - o] : 0;
        __syncthreads();
        part[t] += v;
        __syncthreads();
    }
    int pre = (t == 0) ? 0 : part[t - 1];
    for (int i = 0; i < chunk; i++) off[base + i] = pre + local[i];
    if (t == 1023) off[N] = pre + s;
}

__global__ void scatter_kernel(const int* __restrict__ dst, const int* __restrict__ off,
                               int* __restrict__ cur, int* __restrict__ eid, int E)
{
    int e = blockIdx.x * blockDim.x + threadIdx.x;
    if (e < E) {
        int d = dst[e];
        int p = off[d] + atomicAdd(&cur[d], 1);
        eid[p] = e;
    }
}

// ======== L1: fused edge-softmax + feature aggregation (1 wave per node) ========
__global__ __launch_bounds__(256) void aggregate_feat_sm(
    const int* __restrict__ off, const int* __restrict__ eid, const int* __restrict__ src,
    const float* __restrict__ el, const float* __restrict__ er,
    const short* __restrict__ featb, short* __restrict__ Acomb)
{
    int wv = threadIdx.x >> 6, lane = threadIdx.x & 63;
    int n = blockIdx.x * 4 + wv;
    int k4 = lane * 4;
    float4 erv = ((const float4*)er)[n];
    float acc[4][4] = {};   // [head][kk]
    float accd[4] = {};     // denominators
    int beg = off[n], end = off[n + 1];
    for (int j = beg; j < end; ++j) {
        int e = eid[j];
        int s = src[e];
        float4 elv = ((const float4*)el)[s];
        float a0 = elv.x + erv.x, a1 = elv.y + erv.y, a2 = elv.z + erv.z, a3 = elv.w + erv.w;
        a0 = __expf(a0 > 0.f ? a0 : 0.2f * a0);
        a1 = __expf(a1 > 0.f ? a1 : 0.2f * a1);
        a2 = __expf(a2 > 0.f ? a2 : 0.2f * a2);
        a3 = __expf(a3 > 0.f ? a3 : 0.2f * a3);
        accd[0] += a0; accd[1] += a1; accd[2] += a2; accd[3] += a3;
        short4v fv = *(const short4v*)(featb + (size_t)s * 256 + k4);
        float f0 = b2f(fv[0]), f1 = b2f(fv[1]), f2 = b2f(fv[2]), f3 = b2f(fv[3]);
        acc[0][0] = fmaf(a0, f0, acc[0][0]); acc[0][1] = fmaf(a0, f1, acc[0][1]);
        acc[0][2] = fmaf(a0, f2, acc[0][2]); acc[0][3] = fmaf(a0, f3, acc[0][3]);
        acc[1][0] = fmaf(a1, f0, acc[1][0]); acc[1][1] = fmaf(a1, f1, acc[1][1]);
        acc[1][2] = fmaf(a1, f2, acc[1][2]); acc[1][3] = fmaf(a1, f3, acc[1][3]);
        acc[2][0] = fmaf(a2, f0, acc[2][0]); acc[2][1] = fmaf(a2, f1, acc[2][1]);
        acc[2][2] = fmaf(a2, f2, acc[2][2]); acc[2][3] = fmaf(a2, f3, acc[2][3]);
        acc[3][0] = fmaf(a3, f0, acc[3][0]); acc[3][1] = fmaf(a3, f1, acc[3][1]);
        acc[3][2] = fmaf(a3, f2, acc[3][2]); acc[3][3] = fmaf(a3, f3, acc[3][3]);
    }
    float inv[4];
#pragma unroll
    for (int h = 0; h < 4; h++) inv[h] = 1.f / (accd[h] == 0.f ? 1.f : accd[h]);
    short4v selfv = *(const short4v*)(featb + (size_t)n * 256 + k4);
#pragma unroll
    for (int h = 0; h < 4; h++) {
        short4v o;
#pragma unroll
        for (int kk = 0; kk < 4; kk++) o[kk] = f2bf(acc[h][kk] * inv[h]);
        *(short4v*)(Acomb + (size_t)n * 2048 + h * 512 + k4) = o;
        *(short4v*)(Acomb + (size_t)n * 2048 + h * 512 + 256 + k4) = selfv;
    }
}

// ======== L2: fused edge-softmax + aggregation on z2res[M=N*4,256]=[z2|res2+b2] ========
__global__ __launch_bounds__(256) void aggregate2_sm(
    const int* __restrict__ off, const int* __restrict__ eid, const int* __restrict__ src,
    const float* __restrict__ el, const float* __restrict__ er,
    const short* __restrict__ z2res, short* __restrict__ h2)
{
    int n = blockIdx.x, t = threadIdx.x;
    int c = t >> 4;                   // channel (p,h) of cols 2t,2t+1
    int p = t >> 6;
    int rem = (2 * t) & 127;          // col within p's 128-wide z2 block
    float erv = er[n * 16 + c];
    float r0 = 0.f, r1 = 0.f, dn = 0.f;
    int beg = off[n], end = off[n + 1];
    for (int j = beg; j < end; ++j) {
        int e = eid[j];
        int s = src[e];
        float lv = el[s * 16 + c] + erv;
        float a = __expf(lv > 0.f ? lv : 0.2f * lv);
        dn += a;
        unsigned zv = *(const unsigned*)(z2res + ((size_t)s * 4 + p) * 256 + rem);
        r0 = fmaf(a, b2f((short)(zv & 0xFFFFu)), r0);
        r1 = fmaf(a, b2f((short)(zv >> 16)), r1);
    }
    if (dn == 0.f) dn = 1.f;
    float inv = 1.f / dn;
    unsigned rv = *(const unsigned*)(z2res + ((size_t)n * 4 + p) * 256 + 128 + rem);
    float v0 = r0 * inv + b2f((short)(rv & 0xFFFFu));
    float v1 = r1 * inv + b2f((short)(rv >> 16));
    v0 = v0 > 0.f ? v0 : 0.f;
    v1 = v1 > 0.f ? v1 : 0.f;
    unsigned o = ((unsigned)(unsigned short)f2bf(v1) << 16) | (unsigned)(unsigned short)f2bf(v0);
    *(unsigned*)(h2 + (size_t)n * 512 + t * 2) = o;
}

// ======== launch ========
extern "C" void kernel_launch(void* const* d_in, const int* in_sizes, int n_in,
                              void* d_out, int out_size, void* d_ws, size_t ws_size,
                              hipStream_t stream)
{
    const float* feat  = (const float*)d_in[0];
    const int*   src   = (const int*)d_in[1];
    const int*   dst   = (const int*)d_in[2];
    const float* W1    = (const float*)d_in[3];
    const float* al1   = (const float*)d_in[4];
    const float* ar1   = (const float*)d_in[5];
    const float* resW1 = (const float*)d_in[6];
    const float* b1    = (const float*)d_in[7];
    const float* W2    = (const float*)d_in[8];
    const float* al2   = (const float*)d_in[9];
    const float* ar2   = (const float*)d_in[10];
    const float* resW2 = (const float*)d_in[11];
    const float* b2    = (const float*)d_in[12];
    const float* Wout  = (const float*)d_in[13];
    const float* bout  = (const float*)d_in[14];
    const int N = in_sizes[0] / IN_F;  // 8192
    const int E = in_sizes[1];         // 65536

    // ---- workspace layout (~95 MB) ----
    char* w = (char*)d_ws;
    auto alloc = [&](size_t bytes) -> char* {
        char* p = w;
        w += (bytes + 255) & ~(size_t)255;
        return p;
    };
    short*    Acomb   = (short*)alloc((size_t)N * 2048 * 2);      // 32 MB
    short*    h1b     = (short*)alloc((size_t)N * 2048 * 2);      // 32 MB
    short*    featb   = (short*)alloc((size_t)N * 256 * 2);       // 4 MB
    short*    Wcomb   = (short*)alloc((size_t)2048 * 512 * 2);    // 2 MB
    short*    W2comb  = (short*)alloc((size_t)256 * 512 * 2);
    short*    Wtout   = (short*)alloc((size_t)128 * 512 * 2);
    float*    bias2c  = (float*)alloc((size_t)256 * 4);
    float*    wal1    = (float*)alloc((size_t)256 * 4 * 4);
    float*    war1    = (float*)alloc((size_t)256 * 4 * 4);
    float*    wal2    = (float*)alloc((size_t)512 * 4 * 4);
    float*    war2    = (float*)alloc((size_t)512 * 4 * 4);
    float*    el1     = (float*)alloc((size_t)N * 4 * 4);
    float*    er1     = (float*)alloc((size_t)N * 4 * 4);
    int*      deg     = (int*)alloc((size_t)N * 4);               // deg+cur contiguous:
    int*      cur     = (int*)alloc((size_t)N * 4);               //   prep_all zeroes both
    int*      off     = (int*)alloc((size_t)(N + 1) * 4);
    int*      eid     = (int*)alloc((size_t)E * 4);
    short*    z2res   = (short*)alloc((size_t)N * 4 * 256 * 2);   // 16 MB
    short*    h2b     = (short*)alloc((size_t)N * 512 * 2);       // 8 MB
    float*    el2     = (float*)alloc((size_t)N * 16 * 4);
    float*    er2     = (float*)alloc((size_t)N * 16 * 4);

    dim3 blk(256);

    // ===== prep: folds + weight cvt + bias2c + zero(deg,cur) — one kernel =====
    prep_all<<<dim3(2001), blk, 0, stream>>>(W1, al1, ar1, W2, al2, ar2,
                                             resW1, resW2, Wout, b2,
                                             Wcomb, W2comb, Wtout,
                                             wal1, war1, wal2, war2, bias2c, deg);

    // ===== CSR build =====
    hist_kernel<<<dim3((E + 255) / 256), blk, 0, stream>>>(dst, deg, E);
    scan_excl<<<dim3(1), dim3(1024), 0, stream>>>(deg, off, N);
    scatter_kernel<<<dim3((E + 255) / 256), blk, 0, stream>>>(dst, off, cur, eid, E);

    // ===== layer 1 =====
    feat_cvt_elr<<<dim3(N / 4), blk, 0, stream>>>(feat, (const float4*)wal1, (const float4*)war1,
                                                  featb, el1, er1);
    aggregate_feat_sm<<<dim3(N / 4), blk, 0, stream>>>(off, eid, src, el1, er1, featb, Acomb);
    gemm_h1<<<dim3(4, N / 128, 4), blk, 0, stream>>>(Acomb, Wcomb, b1, h1b);
    // h1b = bf16 h1 [N,4,512]

    // ===== layer 2 =====
    el_er_fold_b<<<dim3(N * 4 / 4), blk, 0, stream>>>(h1b, (const float4*)wal2, (const float4*)war2,
                                                      el2, er2);
    gemm_bf16<<<dim3(2, (N * 4) / 128), blk, 0, stream>>>(h1b, W2comb, bias2c, z2res,
                                                          N * 4, 256, 512, 256, 256, 1);
    aggregate2_sm<<<dim3(N), blk, 0, stream>>>(off, eid, src, el2, er2, z2res, h2b);
    // h2b = bf16 h2 [N,512]

    // ===== final linear =====
    gemm_bf16<<<dim3(1, N / 128), blk, 0, stream>>>(h2b, Wtout, bout, (float*)d_out,
                                                    N, 128, 512, 40, 40, 0);
}

// Round 10
// 147.557 us; speedup vs baseline: 2.7615x; 1.1426x over previous
//
#include <hip/hip_runtime.h>
#include <cmath>

constexpr int IN_F  = 256;

typedef short bf16x8 __attribute__((ext_vector_type(8)));
typedef short short4v __attribute__((ext_vector_type(4)));
typedef float f32x4 __attribute__((ext_vector_type(4)));

__device__ __forceinline__ short f2bf(float f) {
    unsigned u = __float_as_uint(f);
    unsigned r = (u + 0x7FFFu + ((u >> 16) & 1)) >> 16;  // RNE
    return (short)r;
}
__device__ __forceinline__ float b2f(short s) {
    return __uint_as_float(((unsigned)(unsigned short)s) << 16);
}

// ======== XCD-chunked block swizzle (T1) ========
__device__ __forceinline__ int xcd_logical_id()
{
    int nx = gridDim.x, ny = gridDim.y, nz = gridDim.z;
    int flat = blockIdx.x + nx * (blockIdx.y + ny * blockIdx.z);
    int nwg = nx * ny * nz;
    if (nwg & 7) return flat;
    int chunk = nwg >> 3;
    return (flat & 7) * chunk + (flat >> 3);
}

// ======== weight transpose to bf16 (device helper; 32x32 tile) ========
__device__ __forceinline__ void cvt_t_body(
    const float* __restrict__ W, short* __restrict__ Wt, int K, int N,
    int ldwt, int koff, int bk, int bn, int tx, int ty)
{
    __shared__ float tile[32][33];
    for (int i = ty; i < 32; i += 8) {
        int gn = bn + tx;
        tile[i][tx] = (gn < N) ? W[(size_t)(bk + i) * N + gn] : 0.f;
    }
    __syncthreads();
    for (int i = ty; i < 32; i += 8)
        Wt[(size_t)(bn + i) * ldwt + koff + bk + tx] = f2bf(tile[tx][i]);
}

// ======== mega prep kernel: fold1 + weight cvt + bias2c + zero(deg,cur) ========
// partition: [0,256) fold1 ; [256,1280) cvt_big ; [1280,1472) cvt_small ;
//            1472 bias ; [1473,1489) zero 64KB
__global__ __launch_bounds__(256) void prep_all(
    const float* __restrict__ W1, const float* __restrict__ al1, const float* __restrict__ ar1,
    const float* __restrict__ resW1, const float* __restrict__ resW2,
    const float* __restrict__ W2, const float* __restrict__ Wout, const float* __restrict__ b2,
    short* __restrict__ Wcomb, short* __restrict__ W2comb, short* __restrict__ Wtout,
    float* __restrict__ wal1, float* __restrict__ war1,
    float* __restrict__ bias2c, int* __restrict__ zero_base)
{
    int bid = blockIdx.x;
    int t   = threadIdx.x;
    if (bid < 256) {
        // ---- fold layer-1 attention vectors through W1 (one wave per (k,h)) ----
        int wid  = (bid * 256 + t) >> 6;  // 0..1023
        int lane = t & 63;
        int k = wid >> 2, h = wid & 3;
        const float* wr  = W1  + (size_t)k * 2048 + h * 512;
        const float* alp = al1 + h * 512;
        const float* arp = ar1 + h * 512;
        float sl = 0.f, sr = 0.f;
        for (int j = lane; j < 512; j += 64) {
            float wv = wr[j];
            sl = fmaf(wv, alp[j], sl);
            sr = fmaf(wv, arp[j], sr);
        }
#pragma unroll
        for (int o = 32; o; o >>= 1) { sl += __shfl_down(sl, o); sr += __shfl_down(sr, o); }
        if (lane == 0) { wal1[wid] = sl; war1[wid] = sr; }
    } else if (bid < 1280) {
        // ---- W1/resW1 -> Wcomb [2048 rows, 512] (cols 0:256 / 256:512) ----
        int id = bid - 256;               // 1024 blocks: x=64, y=8, z=2
        int bx = id & 63, by = (id >> 6) & 7, bz = id >> 9;
        const float* W = bz ? resW1 : W1;
        cvt_t_body(W, Wcomb, 256, 2048, 512, bz ? 256 : 0,
                   by * 32, bx * 32, t & 31, t >> 5);
    } else if (bid < 1472) {
        // ---- W2/resW2 -> W2comb rows 0:128/128:256 ; Wout -> Wtout (pad 128) ----
        int id = bid - 1280;              // 192 blocks: x=4, y=16, z=3
        int bx = id & 3, by = (id >> 2) & 15, bz = id >> 6;
        const float* W; short* Wt; int N;
        if (bz == 0)      { W = W2;    Wt = W2comb;             N = 128; }
        else if (bz == 1) { W = resW2; Wt = W2comb + 128 * 512; N = 128; }
        else              { W = Wout;  Wt = Wtout;              N = 40;  }
        cvt_t_body(W, Wt, 512, N, 512, 0, by * 32, bx * 32, t & 31, t >> 5);
    } else if (bid == 1472) {
        bias2c[t] = (t < 128) ? 0.f : b2[t - 128];
    } else {
        int b = bid - 1473;               // 16 blocks * 256 thr * 16B = 64KB
        int4 z; z.x = 0; z.y = 0; z.z = 0; z.w = 0;
        ((int4*)zero_base)[(size_t)b * 256 + t] = z;
    }
}

// ======== fused front: feat->bf16 + el1/er1 fold + dst histogram ========
// partition: [0, nfeat) feat rows (4/block) ; [nfeat, nfeat+E/256) histogram
__global__ __launch_bounds__(256) void l1_front(
    const float* __restrict__ feat, const float4* __restrict__ wal, const float4* __restrict__ war,
    short* __restrict__ featb, float* __restrict__ el, float* __restrict__ er,
    const int* __restrict__ dst, int* __restrict__ deg, int E, int nfeat)
{
    if ((int)blockIdx.x >= nfeat) {
        int e = (blockIdx.x - nfeat) * 256 + threadIdx.x;
        if (e < E) atomicAdd(&deg[dst[e]], 1);
        return;
    }
    int row  = blockIdx.x * 4 + (threadIdx.x >> 6);
    int lane = threadIdx.x & 63;
    float4 v = ((const float4*)feat)[(size_t)row * 64 + lane];
    short4v o;
    o[0] = f2bf(v.x); o[1] = f2bf(v.y); o[2] = f2bf(v.z); o[3] = f2bf(v.w);
    *(short4v*)(featb + (size_t)row * 256 + lane * 4) = o;

    float fj[4] = { v.x, v.y, v.z, v.w };
    int k = lane * 4;
    float sl[4] = {}, sr[4] = {};
#pragma unroll
    for (int j = 0; j < 4; j++) {
        float4 wl = wal[k + j], wr = war[k + j];
        sl[0] = fmaf(fj[j], wl.x, sl[0]); sl[1] = fmaf(fj[j], wl.y, sl[1]);
        sl[2] = fmaf(fj[j], wl.z, sl[2]); sl[3] = fmaf(fj[j], wl.w, sl[3]);
        sr[0] = fmaf(fj[j], wr.x, sr[0]); sr[1] = fmaf(fj[j], wr.y, sr[1]);
        sr[2] = fmaf(fj[j], wr.z, sr[2]); sr[3] = fmaf(fj[j], wr.w, sr[3]);
    }
#pragma unroll
    for (int o2 = 32; o2; o2 >>= 1) {
#pragma unroll
        for (int h = 0; h < 4; h++) { sl[h] += __shfl_down(sl[h], o2); sr[h] += __shfl_down(sr[h], o2); }
    }
    if (lane == 0) {
#pragma unroll
        for (int h = 0; h < 4; h++) { el[row * 4 + h] = sl[h]; er[row * 4 + h] = sr[h]; }
    }
}

// ======== el2/er2 directly from z2 (one wave per row of [N*4], 16-lane-group reduce) ========
__global__ __launch_bounds__(256) void el2_from_z2(
    const short* __restrict__ z2res, const float* __restrict__ al2, const float* __restrict__ ar2,
    float* __restrict__ el, float* __restrict__ er)
{
    int m    = blockIdx.x * 4 + (threadIdx.x >> 6);
    int lane = threadIdx.x & 63;
    unsigned zv = *(const unsigned*)(z2res + (size_t)m * 256 + lane * 2);
    float z0 = b2f((short)(zv & 0xFFFFu)), z1 = b2f((short)(zv >> 16));
    int c = lane >> 4;            // head h' (16 lanes per head)
    int j = (lane & 15) * 2;      // col within 32
    float sl = fmaf(z1, al2[c * 32 + j + 1], z0 * al2[c * 32 + j]);
    float sr = fmaf(z1, ar2[c * 32 + j + 1], z0 * ar2[c * 32 + j]);
#pragma unroll
    for (int o = 8; o; o >>= 1) { sl += __shfl_xor(sl, o); sr += __shfl_xor(sr, o); }
    if ((lane & 15) == 0) { el[m * 4 + c] = sl; er[m * 4 + c] = sr; }
}

// ======== bf16 MFMA GEMM, BK=64 (two [128][32] sub-buffers; half the barriers) ========
__global__ __launch_bounds__(256) void gemm_bf16(
    const short* __restrict__ A, const short* __restrict__ Bt,
    const float* __restrict__ bias, void* __restrict__ C,
    int M, int N, int K, int ldc, int nmax, int out_bf16)
{
    __shared__ short sA[2][128 * 32];
    __shared__ short sB[2][128 * 32];
    const int tid  = threadIdx.x;
    const int wave = tid >> 6, lane = tid & 63;
    const int wm = wave >> 1, wn = wave & 1;
    int lid = xcd_logical_id();
    const int bx = lid % gridDim.x, by = lid / gridDim.x;
    const int m0 = by * 128, n0 = bx * 128;

    const int srow = tid >> 2;
    const int scol = (tid & 3) * 8;
    const int fr = lane & 15;
    const int fq = lane >> 4;

    f32x4 acc[4][4] = {};

    for (int k0 = 0; k0 < K; k0 += 64) {
#pragma unroll
        for (int hh = 0; hh < 2; hh++) {
            int kc = k0 + hh * 32 + scol;
            const short* ga0 = A  + (size_t)(m0 + srow) * K + kc;
            const short* ga1 = A  + (size_t)(m0 + 64 + srow) * K + kc;
            const short* gb0 = Bt + (size_t)(n0 + srow) * K + kc;
            const short* gb1 = Bt + (size_t)(n0 + 64 + srow) * K + kc;
            __builtin_amdgcn_global_load_lds((const __attribute__((address_space(1))) void*)ga0,
                (__attribute__((address_space(3))) void*)(sA[hh] + wave * 512), 16, 0, 0);
            __builtin_amdgcn_global_load_lds((const __attribute__((address_space(1))) void*)ga1,
                (__attribute__((address_space(3))) void*)(sA[hh] + 2048 + wave * 512), 16, 0, 0);
            __builtin_amdgcn_global_load_lds((const __attribute__((address_space(1))) void*)gb0,
                (__attribute__((address_space(3))) void*)(sB[hh] + wave * 512), 16, 0, 0);
            __builtin_amdgcn_global_load_lds((const __attribute__((address_space(1))) void*)gb1,
                (__attribute__((address_space(3))) void*)(sB[hh] + 2048 + wave * 512), 16, 0, 0);
        }
        __syncthreads();

#pragma unroll
        for (int hh = 0; hh < 2; hh++) {
            bf16x8 af[4], bfr[4];
#pragma unroll
            for (int m = 0; m < 4; m++)
                af[m] = *(const bf16x8*)(sA[hh] + (wm * 64 + m * 16 + fr) * 32 + fq * 8);
#pragma unroll
            for (int n = 0; n < 4; n++)
                bfr[n] = *(const bf16x8*)(sB[hh] + (wn * 64 + n * 16 + fr) * 32 + fq * 8);
#pragma unroll
            for (int m = 0; m < 4; m++)
#pragma unroll
                for (int n = 0; n < 4; n++)
                    acc[m][n] = __builtin_amdgcn_mfma_f32_16x16x32_bf16(af[m], bfr[n], acc[m][n], 0, 0, 0);
        }
        __syncthreads();
    }

#pragma unroll
    for (int n = 0; n < 4; n++) {
        int gcol = n0 + wn * 64 + n * 16 + fr;
        if (gcol >= nmax) continue;
        float bv = bias ? bias[gcol] : 0.f;
#pragma unroll
        for (int m = 0; m < 4; m++) {
#pragma unroll
            for (int j = 0; j < 4; j++) {
                int grow = m0 + wm * 64 + m * 16 + fq * 4 + j;
                float v = acc[m][n][j] + bv;
                if (out_bf16) ((short*)C)[(size_t)grow * ldc + gcol] = f2bf(v);
                else          ((float*)C)[(size_t)grow * ldc + gcol] = v;
            }
        }
    }
}

// ======== batched-by-head GEMM, BK=64: h1 = relu(Acomb_h @ Wcomb_h^T + b1) ========
__global__ __launch_bounds__(256) void gemm_h1(
    const short* __restrict__ Acomb, const short* __restrict__ Wcomb,
    const float* __restrict__ b1, short* __restrict__ h1b)
{
    __shared__ short sA[2][128 * 32];
    __shared__ short sB[2][128 * 32];
    const int tid  = threadIdx.x;
    const int wave = tid >> 6, lane = tid & 63;
    const int wm = wave >> 1, wn = wave & 1;
    int lid = xcd_logical_id();                  // grid (4, M/128, 4)
    const int bx = lid & 3;
    const int by = (lid >> 2) % gridDim.y;
    const int h  = lid / (gridDim.y * 4);
    const int m0 = by * 128, n0 = bx * 128;
    const short* A  = Acomb + h * 512;           // row stride 2048
    const short* Bt = Wcomb + (size_t)(h * 512) * 512;

    const int srow = tid >> 2;
    const int scol = (tid & 3) * 8;
    const int fr = lane & 15;
    const int fq = lane >> 4;

    f32x4 acc[4][4] = {};

    for (int k0 = 0; k0 < 512; k0 += 64) {
#pragma unroll
        for (int hh = 0; hh < 2; hh++) {
            int kc = k0 + hh * 32 + scol;
            const short* ga0 = A  + (size_t)(m0 + srow) * 2048 + kc;
            const short* ga1 = A  + (size_t)(m0 + 64 + srow) * 2048 + kc;
            const short* gb0 = Bt + (size_t)(n0 + srow) * 512 + kc;
            const short* gb1 = Bt + (size_t)(n0 + 64 + srow) * 512 + kc;
            __builtin_amdgcn_global_load_lds((const __attribute__((address_space(1))) void*)ga0,
                (__attribute__((address_space(3))) void*)(sA[hh] + wave * 512), 16, 0, 0);
            __builtin_amdgcn_global_load_lds((const __attribute__((address_space(1))) void*)ga1,
                (__attribute__((address_space(3))) void*)(sA[hh] + 2048 + wave * 512), 16, 0, 0);
            __builtin_amdgcn_global_load_lds((const __attribute__((address_space(1))) void*)gb0,
                (__attribute__((address_space(3))) void*)(sB[hh] + wave * 512), 16, 0, 0);
            __builtin_amdgcn_global_load_lds((const __attribute__((address_space(1))) void*)gb1,
                (__attribute__((address_space(3))) void*)(sB[hh] + 2048 + wave * 512), 16, 0, 0);
        }
        __syncthreads();

#pragma unroll
        for (int hh = 0; hh < 2; hh++) {
            bf16x8 af[4], bfr[4];
#pragma unroll
            for (int m = 0; m < 4; m++)
                af[m] = *(const bf16x8*)(sA[hh] + (wm * 64 + m * 16 + fr) * 32 + fq * 8);
#pragma unroll
            for (int n = 0; n < 4; n++)
                bfr[n] = *(const bf16x8*)(sB[hh] + (wn * 64 + n * 16 + fr) * 32 + fq * 8);
#pragma unroll
            for (int m = 0; m < 4; m++)
#pragma unroll
                for (int n = 0; n < 4; n++)
                    acc[m][n] = __builtin_amdgcn_mfma_f32_16x16x32_bf16(af[m], bfr[n], acc[m][n], 0, 0, 0);
        }
        __syncthreads();
    }

#pragma unroll
    for (int n = 0; n < 4; n++) {
        int gcol = h * 512 + n0 + wn * 64 + n * 16 + fr;
        float bv = b1[gcol];
#pragma unroll
        for (int m = 0; m < 4; m++) {
#pragma unroll
            for (int j = 0; j < 4; j++) {
                int grow = m0 + wm * 64 + m * 16 + fq * 4 + j;
                float v = acc[m][n][j] + bv;
                h1b[(size_t)grow * 2048 + gcol] = f2bf(v > 0.f ? v : 0.f);
            }
        }
    }
}

// ======== CSR scan + scatter ========
__global__ __launch_bounds__(1024) void scan_excl(const int* __restrict__ deg,
                                                  int* __restrict__ off, int N)
{
    __shared__ int part[1024];
    int t = threadIdx.x;
    int chunk = N >> 10;
    int base = t * chunk;
    int local[16];
    int s = 0;
    for (int i = 0; i < chunk; i++) { local[i] = s; s += deg[base + i]; }
    part[t] = s;
    __syncthreads();
    for (int o = 1; o < 1024; o <<= 1) {
        int v = (t >= o) ? part[t - o] : 0;
        __syncthreads();
        part[t] += v;
        __syncthreads();
    }
    int pre = (t == 0) ? 0 : part[t - 1];
    for (int i = 0; i < chunk; i++) off[base + i] = pre + local[i];
    if (t == 1023) off[N] = pre + s;
}

__global__ void scatter_kernel(const int* __restrict__ dst, const int* __restrict__ off,
                               int* __restrict__ cur, int* __restrict__ eid, int E)
{
    int e = blockIdx.x * blockDim.x + threadIdx.x;
    if (e < E) {
        int d = dst[e];
        int p = off[d] + atomicAdd(&cur[d], 1);
        eid[p] = e;
    }
}

// ======== L1: fused edge-softmax + feature aggregation (1 wave per node) ========
__global__ __launch_bounds__(256) void aggregate_feat_sm(
    const int* __restrict__ off, const int* __restrict__ eid, const int* __restrict__ src,
    const float* __restrict__ el, const float* __restrict__ er,
    const short* __restrict__ featb, short* __restrict__ Acomb)
{
    int wv = threadIdx.x >> 6, lane = threadIdx.x & 63;
    int n = blockIdx.x * 4 + wv;
    int k4 = lane * 4;
    float4 erv = ((const float4*)er)[n];
    float acc[4][4] = {};
    float accd[4] = {};
    int beg = off[n], end = off[n + 1];
    for (int j = beg; j < end; ++j) {
        int e = eid[j];
        int s = src[e];
        float4 elv = ((const float4*)el)[s];
        float a0 = elv.x + erv.x, a1 = elv.y + erv.y, a2 = elv.z + erv.z, a3 = elv.w + erv.w;
        a0 = __expf(a0 > 0.f ? a0 : 0.2f * a0);
        a1 = __expf(a1 > 0.f ? a1 : 0.2f * a1);
        a2 = __expf(a2 > 0.f ? a2 : 0.2f * a2);
        a3 = __expf(a3 > 0.f ? a3 : 0.2f * a3);
        accd[0] += a0; accd[1] += a1; accd[2] += a2; accd[3] += a3;
        short4v fv = *(const short4v*)(featb + (size_t)s * 256 + k4);
        float f0 = b2f(fv[0]), f1 = b2f(fv[1]), f2 = b2f(fv[2]), f3 = b2f(fv[3]);
        acc[0][0] = fmaf(a0, f0, acc[0][0]); acc[0][1] = fmaf(a0, f1, acc[0][1]);
        acc[0][2] = fmaf(a0, f2, acc[0][2]); acc[0][3] = fmaf(a0, f3, acc[0][3]);
        acc[1][0] = fmaf(a1, f0, acc[1][0]); acc[1][1] = fmaf(a1, f1, acc[1][1]);
        acc[1][2] = fmaf(a1, f2, acc[1][2]); acc[1][3] = fmaf(a1, f3, acc[1][3]);
        acc[2][0] = fmaf(a2, f0, acc[2][0]); acc[2][1] = fmaf(a2, f1, acc[2][1]);
        acc[2][2] = fmaf(a2, f2, acc[2][2]); acc[2][3] = fmaf(a2, f3, acc[2][3]);
        acc[3][0] = fmaf(a3, f0, acc[3][0]); acc[3][1] = fmaf(a3, f1, acc[3][1]);
        acc[3][2] = fmaf(a3, f2, acc[3][2]); acc[3][3] = fmaf(a3, f3, acc[3][3]);
    }
    float inv[4];
#pragma unroll
    for (int h = 0; h < 4; h++) inv[h] = 1.f / (accd[h] == 0.f ? 1.f : accd[h]);
    short4v selfv = *(const short4v*)(featb + (size_t)n * 256 + k4);
#pragma unroll
    for (int h = 0; h < 4; h++) {
        short4v o;
#pragma unroll
        for (int kk = 0; kk < 4; kk++) o[kk] = f2bf(acc[h][kk] * inv[h]);
        *(short4v*)(Acomb + (size_t)n * 2048 + h * 512 + k4) = o;
        *(short4v*)(Acomb + (size_t)n * 2048 + h * 512 + 256 + k4) = selfv;
    }
}

// ======== L2: fused edge-softmax + aggregation on z2res[M=N*4,256]=[z2|res2+b2] ========
__global__ __launch_bounds__(256) void aggregate2_sm(
    const int* __restrict__ off, const int* __restrict__ eid, const int* __restrict__ src,
    const float* __restrict__ el, const float* __restrict__ er,
    const short* __restrict__ z2res, short* __restrict__ h2)
{
    int n = blockIdx.x, t = threadIdx.x;
    int c = t >> 4;
    int p = t >> 6;
    int rem = (2 * t) & 127;
    float erv = er[n * 16 + c];
    float r0 = 0.f, r1 = 0.f, dn = 0.f;
    int beg = off[n], end = off[n + 1];
    for (int j = beg; j < end; ++j) {
        int e = eid[j];
        int s = src[e];
        float lv = el[s * 16 + c] + erv;
        float a = __expf(lv > 0.f ? lv : 0.2f * lv);
        dn += a;
        unsigned zv = *(const unsigned*)(z2res + ((size_t)s * 4 + p) * 256 + rem);
        r0 = fmaf(a, b2f((short)(zv & 0xFFFFu)), r0);
        r1 = fmaf(a, b2f((short)(zv >> 16)), r1);
    }
    if (dn == 0.f) dn = 1.f;
    float inv = 1.f / dn;
    unsigned rv = *(const unsigned*)(z2res + ((size_t)n * 4 + p) * 256 + 128 + rem);
    float v0 = r0 * inv + b2f((short)(rv & 0xFFFFu));
    float v1 = r1 * inv + b2f((short)(rv >> 16));
    v0 = v0 > 0.f ? v0 : 0.f;
    v1 = v1 > 0.f ? v1 : 0.f;
    unsigned o = ((unsigned)(unsigned short)f2bf(v1) << 16) | (unsigned)(unsigned short)f2bf(v0);
    *(unsigned*)(h2 + (size_t)n * 512 + t * 2) = o;
}

// ======== launch ========
extern "C" void kernel_launch(void* const* d_in, const int* in_sizes, int n_in,
                              void* d_out, int out_size, void* d_ws, size_t ws_size,
                              hipStream_t stream)
{
    const float* feat  = (const float*)d_in[0];
    const int*   src   = (const int*)d_in[1];
    const int*   dst   = (const int*)d_in[2];
    const float* W1    = (const float*)d_in[3];
    const float* al1   = (const float*)d_in[4];
    const float* ar1   = (const float*)d_in[5];
    const float* resW1 = (const float*)d_in[6];
    const float* b1    = (const float*)d_in[7];
    const float* W2    = (const float*)d_in[8];
    const float* al2   = (const float*)d_in[9];
    const float* ar2   = (const float*)d_in[10];
    const float* resW2 = (const float*)d_in[11];
    const float* b2    = (const float*)d_in[12];
    const float* Wout  = (const float*)d_in[13];
    const float* bout  = (const float*)d_in[14];
    const int N = in_sizes[0] / IN_F;  // 8192
    const int E = in_sizes[1];         // 65536

    // ---- workspace layout (~95 MB) ----
    char* w = (char*)d_ws;
    auto alloc = [&](size_t bytes) -> char* {
        char* p = w;
        w += (bytes + 255) & ~(size_t)255;
        return p;
    };
    short*    Acomb   = (short*)alloc((size_t)N * 2048 * 2);      // 32 MB
    short*    h1b     = (short*)alloc((size_t)N * 2048 * 2);      // 32 MB
    short*    featb   = (short*)alloc((size_t)N * 256 * 2);       // 4 MB
    short*    Wcomb   = (short*)alloc((size_t)2048 * 512 * 2);    // 2 MB
    short*    W2comb  = (short*)alloc((size_t)256 * 512 * 2);
    short*    Wtout   = (short*)alloc((size_t)128 * 512 * 2);
    float*    bias2c  = (float*)alloc((size_t)256 * 4);
    float*    wal1    = (float*)alloc((size_t)256 * 4 * 4);
    float*    war1    = (float*)alloc((size_t)256 * 4 * 4);
    float*    el1     = (float*)alloc((size_t)N * 4 * 4);
    float*    er1     = (float*)alloc((size_t)N * 4 * 4);
    int*      deg     = (int*)alloc((size_t)N * 4);               // deg+cur contiguous:
    int*      cur     = (int*)alloc((size_t)N * 4);               //   prep_all zeroes both
    int*      off     = (int*)alloc((size_t)(N + 1) * 4);
    int*      eid     = (int*)alloc((size_t)E * 4);
    short*    z2res   = (short*)alloc((size_t)N * 4 * 256 * 2);   // 16 MB
    short*    h2b     = (short*)alloc((size_t)N * 512 * 2);       // 8 MB
    float*    el2     = (float*)alloc((size_t)N * 16 * 4);
    float*    er2     = (float*)alloc((size_t)N * 16 * 4);

    dim3 blk(256);

    // ===== prep: fold1 + weight cvt + bias2c + zero(deg,cur) =====
    prep_all<<<dim3(1489), blk, 0, stream>>>(W1, al1, ar1, resW1, resW2, W2, Wout, b2,
                                             Wcomb, W2comb, Wtout,
                                             wal1, war1, bias2c, deg);

    // ===== front: feat cvt + el1/er1 + dst histogram (one dispatch) =====
    l1_front<<<dim3(N / 4 + E / 256), blk, 0, stream>>>(feat, (const float4*)wal1, (const float4*)war1,
                                                        featb, el1, er1, dst, deg, E, N / 4);
    scan_excl<<<dim3(1), dim3(1024), 0, stream>>>(deg, off, N);
    scatter_kernel<<<dim3((E + 255) / 256), blk, 0, stream>>>(dst, off, cur, eid, E);

    // ===== layer 1 =====
    aggregate_feat_sm<<<dim3(N / 4), blk, 0, stream>>>(off, eid, src, el1, er1, featb, Acomb);
    gemm_h1<<<dim3(4, N / 128, 4), blk, 0, stream>>>(Acomb, Wcomb, b1, h1b);
    // h1b = bf16 h1 [N,4,512]

    // ===== layer 2 =====
    gemm_bf16<<<dim3(2, (N * 4) / 128), blk, 0, stream>>>(h1b, W2comb, bias2c, z2res,
                                                          N * 4, 256, 512, 256, 256, 1);
    el2_from_z2<<<dim3(N), blk, 0, stream>>>(z2res, al2, ar2, el2, er2);
    aggregate2_sm<<<dim3(N), blk, 0, stream>>>(off, eid, src, el2, er2, z2res, h2b);
    // h2b = bf16 h2 [N,512]

    // ===== final linear =====
    gemm_bf16<<<dim3(1, N / 128), blk, 0, stream>>>(h2b, Wtout, bout, (float*)d_out,
                                                    N, 128, 512, 40, 40, 0);
}

// Round 11
// 143.700 us; speedup vs baseline: 2.8356x; 1.0268x over previous
//
#include <hip/hip_runtime.h>
#include <cmath>

constexpr int IN_F  = 256;

typedef short bf16x8 __attribute__((ext_vector_type(8)));
typedef short short4v __attribute__((ext_vector_type(4)));
typedef float f32x4 __attribute__((ext_vector_type(4)));

__device__ __forceinline__ short f2bf(float f) {
    unsigned u = __float_as_uint(f);
    unsigned r = (u + 0x7FFFu + ((u >> 16) & 1)) >> 16;  // RNE
    return (short)r;
}
__device__ __forceinline__ float b2f(short s) {
    return __uint_as_float(((unsigned)(unsigned short)s) << 16);
}

// ======== XCD-chunked block swizzle (T1) ========
__device__ __forceinline__ int xcd_logical_id()
{
    int nx = gridDim.x, ny = gridDim.y, nz = gridDim.z;
    int flat = blockIdx.x + nx * (blockIdx.y + ny * blockIdx.z);
    int nwg = nx * ny * nz;
    if (nwg & 7) return flat;
    int chunk = nwg >> 3;
    return (flat & 7) * chunk + (flat >> 3);
}

// ======== weight transpose to bf16 (device helper; 32x32 tile) ========
__device__ __forceinline__ void cvt_t_body(
    const float* __restrict__ W, short* __restrict__ Wt, int K, int N,
    int ldwt, int koff, int bk, int bn, int tx, int ty)
{
    __shared__ float tile[32][33];
    for (int i = ty; i < 32; i += 8) {
        int gn = bn + tx;
        tile[i][tx] = (gn < N) ? W[(size_t)(bk + i) * N + gn] : 0.f;
    }
    __syncthreads();
    for (int i = ty; i < 32; i += 8)
        Wt[(size_t)(bn + i) * ldwt + koff + bk + tx] = f2bf(tile[tx][i]);
}

// ======== mega prep kernel: fold1 + weight cvt + bias2c + zero(deg,cur) ========
__global__ __launch_bounds__(256) void prep_all(
    const float* __restrict__ W1, const float* __restrict__ al1, const float* __restrict__ ar1,
    const float* __restrict__ resW1, const float* __restrict__ resW2,
    const float* __restrict__ W2, const float* __restrict__ Wout, const float* __restrict__ b2,
    short* __restrict__ Wcomb, short* __restrict__ W2comb, short* __restrict__ Wtout,
    float* __restrict__ wal1, float* __restrict__ war1,
    float* __restrict__ bias2c, int* __restrict__ zero_base)
{
    int bid = blockIdx.x;
    int t   = threadIdx.x;
    if (bid < 256) {
        int wid  = (bid * 256 + t) >> 6;  // 0..1023
        int lane = t & 63;
        int k = wid >> 2, h = wid & 3;
        const float* wr  = W1  + (size_t)k * 2048 + h * 512;
        const float* alp = al1 + h * 512;
        const float* arp = ar1 + h * 512;
        float sl = 0.f, sr = 0.f;
        for (int j = lane; j < 512; j += 64) {
            float wv = wr[j];
            sl = fmaf(wv, alp[j], sl);
            sr = fmaf(wv, arp[j], sr);
        }
#pragma unroll
        for (int o = 32; o; o >>= 1) { sl += __shfl_down(sl, o); sr += __shfl_down(sr, o); }
        if (lane == 0) { wal1[wid] = sl; war1[wid] = sr; }
    } else if (bid < 1280) {
        int id = bid - 256;               // 1024 blocks: x=64, y=8, z=2
        int bx = id & 63, by = (id >> 6) & 7, bz = id >> 9;
        const float* W = bz ? resW1 : W1;
        cvt_t_body(W, Wcomb, 256, 2048, 512, bz ? 256 : 0,
                   by * 32, bx * 32, t & 31, t >> 5);
    } else if (bid < 1472) {
        int id = bid - 1280;              // 192 blocks: x=4, y=16, z=3
        int bx = id & 3, by = (id >> 2) & 15, bz = id >> 6;
        const float* W; short* Wt; int N;
        if (bz == 0)      { W = W2;    Wt = W2comb;             N = 128; }
        else if (bz == 1) { W = resW2; Wt = W2comb + 128 * 512; N = 128; }
        else              { W = Wout;  Wt = Wtout;              N = 40;  }
        cvt_t_body(W, Wt, 512, N, 512, 0, by * 32, bx * 32, t & 31, t >> 5);
    } else if (bid == 1472) {
        bias2c[t] = (t < 128) ? 0.f : b2[t - 128];
    } else {
        int b = bid - 1473;               // 16 blocks * 256 thr * 16B = 64KB
        int4 z; z.x = 0; z.y = 0; z.z = 0; z.w = 0;
        ((int4*)zero_base)[(size_t)b * 256 + t] = z;
    }
}

// ======== fused front: feat->bf16 + el1/er1 fold + dst histogram ========
__global__ __launch_bounds__(256) void l1_front(
    const float* __restrict__ feat, const float4* __restrict__ wal, const float4* __restrict__ war,
    short* __restrict__ featb, float* __restrict__ el, float* __restrict__ er,
    const int* __restrict__ dst, int* __restrict__ deg, int E, int nfeat)
{
    if ((int)blockIdx.x >= nfeat) {
        int e = (blockIdx.x - nfeat) * 256 + threadIdx.x;
        if (e < E) atomicAdd(&deg[dst[e]], 1);
        return;
    }
    int row  = blockIdx.x * 4 + (threadIdx.x >> 6);
    int lane = threadIdx.x & 63;
    float4 v = ((const float4*)feat)[(size_t)row * 64 + lane];
    short4v o;
    o[0] = f2bf(v.x); o[1] = f2bf(v.y); o[2] = f2bf(v.z); o[3] = f2bf(v.w);
    *(short4v*)(featb + (size_t)row * 256 + lane * 4) = o;

    float fj[4] = { v.x, v.y, v.z, v.w };
    int k = lane * 4;
    float sl[4] = {}, sr[4] = {};
#pragma unroll
    for (int j = 0; j < 4; j++) {
        float4 wl = wal[k + j], wr = war[k + j];
        sl[0] = fmaf(fj[j], wl.x, sl[0]); sl[1] = fmaf(fj[j], wl.y, sl[1]);
        sl[2] = fmaf(fj[j], wl.z, sl[2]); sl[3] = fmaf(fj[j], wl.w, sl[3]);
        sr[0] = fmaf(fj[j], wr.x, sr[0]); sr[1] = fmaf(fj[j], wr.y, sr[1]);
        sr[2] = fmaf(fj[j], wr.z, sr[2]); sr[3] = fmaf(fj[j], wr.w, sr[3]);
    }
#pragma unroll
    for (int o2 = 32; o2; o2 >>= 1) {
#pragma unroll
        for (int h = 0; h < 4; h++) { sl[h] += __shfl_down(sl[h], o2); sr[h] += __shfl_down(sr[h], o2); }
    }
    if (lane == 0) {
#pragma unroll
        for (int h = 0; h < 4; h++) { el[row * 4 + h] = sl[h]; er[row * 4 + h] = sr[h]; }
    }
}

// ======== bf16 MFMA GEMM, BK=64; optional fused el2/er2 epilogue on n0==0 tiles ========
__global__ __launch_bounds__(256) void gemm_bf16(
    const short* __restrict__ A, const short* __restrict__ Bt,
    const float* __restrict__ bias, void* __restrict__ C,
    int M, int N, int K, int ldc, int nmax, int out_bf16,
    float* __restrict__ el2, float* __restrict__ er2,
    const float* __restrict__ al2, const float* __restrict__ ar2, int do_el)
{
    __shared__ short sA[2][128 * 32];
    __shared__ short sB[2][128 * 32];
    const int tid  = threadIdx.x;
    const int wave = tid >> 6, lane = tid & 63;
    const int wm = wave >> 1, wn = wave & 1;
    int lid = xcd_logical_id();
    const int bx = lid % gridDim.x, by = lid / gridDim.x;
    const int m0 = by * 128, n0 = bx * 128;

    const int srow = tid >> 2;
    const int scol = (tid & 3) * 8;
    const int fr = lane & 15;
    const int fq = lane >> 4;

    f32x4 acc[4][4] = {};

    for (int k0 = 0; k0 < K; k0 += 64) {
#pragma unroll
        for (int hh = 0; hh < 2; hh++) {
            int kc = k0 + hh * 32 + scol;
            const short* ga0 = A  + (size_t)(m0 + srow) * K + kc;
            const short* ga1 = A  + (size_t)(m0 + 64 + srow) * K + kc;
            const short* gb0 = Bt + (size_t)(n0 + srow) * K + kc;
            const short* gb1 = Bt + (size_t)(n0 + 64 + srow) * K + kc;
            __builtin_amdgcn_global_load_lds((const __attribute__((address_space(1))) void*)ga0,
                (__attribute__((address_space(3))) void*)(sA[hh] + wave * 512), 16, 0, 0);
            __builtin_amdgcn_global_load_lds((const __attribute__((address_space(1))) void*)ga1,
                (__attribute__((address_space(3))) void*)(sA[hh] + 2048 + wave * 512), 16, 0, 0);
            __builtin_amdgcn_global_load_lds((const __attribute__((address_space(1))) void*)gb0,
                (__attribute__((address_space(3))) void*)(sB[hh] + wave * 512), 16, 0, 0);
            __builtin_amdgcn_global_load_lds((const __attribute__((address_space(1))) void*)gb1,
                (__attribute__((address_space(3))) void*)(sB[hh] + 2048 + wave * 512), 16, 0, 0);
        }
        __syncthreads();

#pragma unroll
        for (int hh = 0; hh < 2; hh++) {
            bf16x8 af[4], bfr[4];
#pragma unroll
            for (int m = 0; m < 4; m++)
                af[m] = *(const bf16x8*)(sA[hh] + (wm * 64 + m * 16 + fr) * 32 + fq * 8);
#pragma unroll
            for (int n = 0; n < 4; n++)
                bfr[n] = *(const bf16x8*)(sB[hh] + (wn * 64 + n * 16 + fr) * 32 + fq * 8);
#pragma unroll
            for (int m = 0; m < 4; m++)
#pragma unroll
                for (int n = 0; n < 4; n++)
                    acc[m][n] = __builtin_amdgcn_mfma_f32_16x16x32_bf16(af[m], bfr[n], acc[m][n], 0, 0, 0);
        }
        __syncthreads();
    }

    // ---- fused el2/er2: only z2-tiles (n0==0) hold all 128 z2 cols in acc ----
    // channel of col C = wn*2 + (n>=2); coef al2[wn*64 + n*16 + fr]
    if (do_el && bx == 0) {
        float cal[4], car[4];
#pragma unroll
        for (int n = 0; n < 4; n++) {
            cal[n] = al2[wn * 64 + n * 16 + fr];
            car[n] = ar2[wn * 64 + n * 16 + fr];
        }
#pragma unroll
        for (int m = 0; m < 4; m++) {
#pragma unroll
            for (int j = 0; j < 4; j++) {
                float ell = acc[m][0][j] * cal[0] + acc[m][1][j] * cal[1];
                float elh = acc[m][2][j] * cal[2] + acc[m][3][j] * cal[3];
                float erl = acc[m][0][j] * car[0] + acc[m][1][j] * car[1];
                float erh = acc[m][2][j] * car[2] + acc[m][3][j] * car[3];
#pragma unroll
                for (int o = 1; o < 16; o <<= 1) {
                    ell += __shfl_xor(ell, o);
                    elh += __shfl_xor(elh, o);
                    erl += __shfl_xor(erl, o);
                    erh += __shfl_xor(erh, o);
                }
                if (fr == 0) {
                    int R = m0 + wm * 64 + m * 16 + fq * 4 + j;
                    el2[R * 4 + wn * 2]     = ell;
                    el2[R * 4 + wn * 2 + 1] = elh;
                    er2[R * 4 + wn * 2]     = erl;
                    er2[R * 4 + wn * 2 + 1] = erh;
                }
            }
        }
    }

#pragma unroll
    for (int n = 0; n < 4; n++) {
        int gcol = n0 + wn * 64 + n * 16 + fr;
        if (gcol >= nmax) continue;
        float bv = bias ? bias[gcol] : 0.f;
#pragma unroll
        for (int m = 0; m < 4; m++) {
#pragma unroll
            for (int j = 0; j < 4; j++) {
                int grow = m0 + wm * 64 + m * 16 + fq * 4 + j;
                float v = acc[m][n][j] + bv;
                if (out_bf16) ((short*)C)[(size_t)grow * ldc + gcol] = f2bf(v);
                else          ((float*)C)[(size_t)grow * ldc + gcol] = v;
            }
        }
    }
}

// ======== batched-by-head GEMM, BK=64: h1 = relu([agg|feat] @ [W1|resW1]_h^T + b1) ========
// A: k<256 from Acomb [N*4,256] (row n*4+h); k>=256 from featb [N,256] (residual)
__global__ __launch_bounds__(256) void gemm_h1(
    const short* __restrict__ Acomb, const short* __restrict__ featb,
    const short* __restrict__ Wcomb, const float* __restrict__ b1, short* __restrict__ h1b)
{
    __shared__ short sA[2][128 * 32];
    __shared__ short sB[2][128 * 32];
    const int tid  = threadIdx.x;
    const int wave = tid >> 6, lane = tid & 63;
    const int wm = wave >> 1, wn = wave & 1;
    int lid = xcd_logical_id();                  // grid (4, M/128, 4)
    const int bx = lid & 3;
    const int by = (lid >> 2) % gridDim.y;
    const int h  = lid / (gridDim.y * 4);
    const int m0 = by * 128, n0 = bx * 128;
    const short* Bt = Wcomb + (size_t)(h * 512) * 512;

    const int srow = tid >> 2;
    const int scol = (tid & 3) * 8;
    const int fr = lane & 15;
    const int fq = lane >> 4;

    f32x4 acc[4][4] = {};

    for (int k0 = 0; k0 < 512; k0 += 64) {
        const int res_half = (k0 >= 256);
#pragma unroll
        for (int hh = 0; hh < 2; hh++) {
            int kc = k0 + hh * 32 + scol;
            const short* ga0;
            const short* ga1;
            if (!res_half) {
                ga0 = Acomb + ((size_t)(m0 + srow) * 4 + h) * 256 + kc;
                ga1 = Acomb + ((size_t)(m0 + 64 + srow) * 4 + h) * 256 + kc;
            } else {
                ga0 = featb + (size_t)(m0 + srow) * 256 + (kc - 256);
                ga1 = featb + (size_t)(m0 + 64 + srow) * 256 + (kc - 256);
            }
            const short* gb0 = Bt + (size_t)(n0 + srow) * 512 + kc;
            const short* gb1 = Bt + (size_t)(n0 + 64 + srow) * 512 + kc;
            __builtin_amdgcn_global_load_lds((const __attribute__((address_space(1))) void*)ga0,
                (__attribute__((address_space(3))) void*)(sA[hh] + wave * 512), 16, 0, 0);
            __builtin_amdgcn_global_load_lds((const __attribute__((address_space(1))) void*)ga1,
                (__attribute__((address_space(3))) void*)(sA[hh] + 2048 + wave * 512), 16, 0, 0);
            __builtin_amdgcn_global_load_lds((const __attribute__((address_space(1))) void*)gb0,
                (__attribute__((address_space(3))) void*)(sB[hh] + wave * 512), 16, 0, 0);
            __builtin_amdgcn_global_load_lds((const __attribute__((address_space(1))) void*)gb1,
                (__attribute__((address_space(3))) void*)(sB[hh] + 2048 + wave * 512), 16, 0, 0);
        }
        __syncthreads();

#pragma unroll
        for (int hh = 0; hh < 2; hh++) {
            bf16x8 af[4], bfr[4];
#pragma unroll
            for (int m = 0; m < 4; m++)
                af[m] = *(const bf16x8*)(sA[hh] + (wm * 64 + m * 16 + fr) * 32 + fq * 8);
#pragma unroll
            for (int n = 0; n < 4; n++)
                bfr[n] = *(const bf16x8*)(sB[hh] + (wn * 64 + n * 16 + fr) * 32 + fq * 8);
#pragma unroll
            for (int m = 0; m < 4; m++)
#pragma unroll
                for (int n = 0; n < 4; n++)
                    acc[m][n] = __builtin_amdgcn_mfma_f32_16x16x32_bf16(af[m], bfr[n], acc[m][n], 0, 0, 0);
        }
        __syncthreads();
    }

#pragma unroll
    for (int n = 0; n < 4; n++) {
        int gcol = h * 512 + n0 + wn * 64 + n * 16 + fr;
        float bv = b1[gcol];
#pragma unroll
        for (int m = 0; m < 4; m++) {
#pragma unroll
            for (int j = 0; j < 4; j++) {
                int grow = m0 + wm * 64 + m * 16 + fq * 4 + j;
                float v = acc[m][n][j] + bv;
                h1b[(size_t)grow * 2048 + gcol] = f2bf(v > 0.f ? v : 0.f);
            }
        }
    }
}

// ======== CSR scan + scatter ========
__global__ __launch_bounds__(1024) void scan_excl(const int* __restrict__ deg,
                                                  int* __restrict__ off, int N)
{
    __shared__ int part[1024];
    int t = threadIdx.x;
    int chunk = N >> 10;
    int base = t * chunk;
    int local[16];
    int s = 0;
    for (int i = 0; i < chunk; i++) { local[i] = s; s += deg[base + i]; }
    part[t] = s;
    __syncthreads();
    for (int o = 1; o < 1024; o <<= 1) {
        int v = (t >= o) ? part[t - o] : 0;
        __syncthreads();
        part[t] += v;
        __syncthreads();
    }
    int pre = (t == 0) ? 0 : part[t - 1];
    for (int i = 0; i < chunk; i++) off[base + i] = pre + local[i];
    if (t == 1023) off[N] = pre + s;
}

__global__ void scatter_kernel(const int* __restrict__ dst, const int* __restrict__ off,
                               int* __restrict__ cur, int* __restrict__ eid, int E)
{
    int e = blockIdx.x * blockDim.x + threadIdx.x;
    if (e < E) {
        int d = dst[e];
        int p = off[d] + atomicAdd(&cur[d], 1);
        eid[p] = e;
    }
}

// ======== L1: fused edge-softmax + feature aggregation -> slim Acomb [N*4,256] ========
__global__ __launch_bounds__(256) void aggregate_feat_sm(
    const int* __restrict__ off, const int* __restrict__ eid, const int* __restrict__ src,
    const float* __restrict__ el, const float* __restrict__ er,
    const short* __restrict__ featb, short* __restrict__ Acomb)
{
    int wv = threadIdx.x >> 6, lane = threadIdx.x & 63;
    int n = blockIdx.x * 4 + wv;
    int k4 = lane * 4;
    float4 erv = ((const float4*)er)[n];
    float acc[4][4] = {};
    float accd[4] = {};
    int beg = off[n], end = off[n + 1];
    for (int j = beg; j < end; ++j) {
        int e = eid[j];
        int s = src[e];
        float4 elv = ((const float4*)el)[s];
        float a0 = elv.x + erv.x, a1 = elv.y + erv.y, a2 = elv.z + erv.z, a3 = elv.w + erv.w;
        a0 = __expf(a0 > 0.f ? a0 : 0.2f * a0);
        a1 = __expf(a1 > 0.f ? a1 : 0.2f * a1);
        a2 = __expf(a2 > 0.f ? a2 : 0.2f * a2);
        a3 = __expf(a3 > 0.f ? a3 : 0.2f * a3);
        accd[0] += a0; accd[1] += a1; accd[2] += a2; accd[3] += a3;
        short4v fv = *(const short4v*)(featb + (size_t)s * 256 + k4);
        float f0 = b2f(fv[0]), f1 = b2f(fv[1]), f2 = b2f(fv[2]), f3 = b2f(fv[3]);
        acc[0][0] = fmaf(a0, f0, acc[0][0]); acc[0][1] = fmaf(a0, f1, acc[0][1]);
        acc[0][2] = fmaf(a0, f2, acc[0][2]); acc[0][3] = fmaf(a0, f3, acc[0][3]);
        acc[1][0] = fmaf(a1, f0, acc[1][0]); acc[1][1] = fmaf(a1, f1, acc[1][1]);
        acc[1][2] = fmaf(a1, f2, acc[1][2]); acc[1][3] = fmaf(a1, f3, acc[1][3]);
        acc[2][0] = fmaf(a2, f0, acc[2][0]); acc[2][1] = fmaf(a2, f1, acc[2][1]);
        acc[2][2] = fmaf(a2, f2, acc[2][2]); acc[2][3] = fmaf(a2, f3, acc[2][3]);
        acc[3][0] = fmaf(a3, f0, acc[3][0]); acc[3][1] = fmaf(a3, f1, acc[3][1]);
        acc[3][2] = fmaf(a3, f2, acc[3][2]); acc[3][3] = fmaf(a3, f3, acc[3][3]);
    }
    float inv[4];
#pragma unroll
    for (int h = 0; h < 4; h++) inv[h] = 1.f / (accd[h] == 0.f ? 1.f : accd[h]);
#pragma unroll
    for (int h = 0; h < 4; h++) {
        short4v o;
#pragma unroll
        for (int kk = 0; kk < 4; kk++) o[kk] = f2bf(acc[h][kk] * inv[h]);
        *(short4v*)(Acomb + ((size_t)n * 4 + h) * 256 + k4) = o;
    }
}

// ======== L2: fused edge-softmax + aggregation on z2res[M=N*4,256]=[z2|res2+b2] ========
__global__ __launch_bounds__(256) void aggregate2_sm(
    const int* __restrict__ off, const int* __restrict__ eid, const int* __restrict__ src,
    const float* __restrict__ el, const float* __restrict__ er,
    const short* __restrict__ z2res, short* __restrict__ h2)
{
    int n = blockIdx.x, t = threadIdx.x;
    int c = t >> 4;
    int p = t >> 6;
    int rem = (2 * t) & 127;
    float erv = er[n * 16 + c];
    float r0 = 0.f, r1 = 0.f, dn = 0.f;
    int beg = off[n], end = off[n + 1];
    for (int j = beg; j < end; ++j) {
        int e = eid[j];
        int s = src[e];
        float lv = el[s * 16 + c] + erv;
        float a = __expf(lv > 0.f ? lv : 0.2f * lv);
        dn += a;
        unsigned zv = *(const unsigned*)(z2res + ((size_t)s * 4 + p) * 256 + rem);
        r0 = fmaf(a, b2f((short)(zv & 0xFFFFu)), r0);
        r1 = fmaf(a, b2f((short)(zv >> 16)), r1);
    }
    if (dn == 0.f) dn = 1.f;
    float inv = 1.f / dn;
    unsigned rv = *(const unsigned*)(z2res + ((size_t)n * 4 + p) * 256 + 128 + rem);
    float v0 = r0 * inv + b2f((short)(rv & 0xFFFFu));
    float v1 = r1 * inv + b2f((short)(rv >> 16));
    v0 = v0 > 0.f ? v0 : 0.f;
    v1 = v1 > 0.f ? v1 : 0.f;
    unsigned o = ((unsigned)(unsigned short)f2bf(v1) << 16) | (unsigned)(unsigned short)f2bf(v0);
    *(unsigned*)(h2 + (size_t)n * 512 + t * 2) = o;
}

// ======== launch ========
extern "C" void kernel_launch(void* const* d_in, const int* in_sizes, int n_in,
                              void* d_out, int out_size, void* d_ws, size_t ws_size,
                              hipStream_t stream)
{
    const float* feat  = (const float*)d_in[0];
    const int*   src   = (const int*)d_in[1];
    const int*   dst   = (const int*)d_in[2];
    const float* W1    = (const float*)d_in[3];
    const float* al1   = (const float*)d_in[4];
    const float* ar1   = (const float*)d_in[5];
    const float* resW1 = (const float*)d_in[6];
    const float* b1    = (const float*)d_in[7];
    const float* W2    = (const float*)d_in[8];
    const float* al2   = (const float*)d_in[9];
    const float* ar2   = (const float*)d_in[10];
    const float* resW2 = (const float*)d_in[11];
    const float* b2    = (const float*)d_in[12];
    const float* Wout  = (const float*)d_in[13];
    const float* bout  = (const float*)d_in[14];
    const int N = in_sizes[0] / IN_F;  // 8192
    const int E = in_sizes[1];         // 65536

    // ---- workspace layout (~80 MB) ----
    char* w = (char*)d_ws;
    auto alloc = [&](size_t bytes) -> char* {
        char* p = w;
        w += (bytes + 255) & ~(size_t)255;
        return p;
    };
    short*    Acomb   = (short*)alloc((size_t)N * 4 * 256 * 2);   // 16 MB (slim)
    short*    h1b     = (short*)alloc((size_t)N * 2048 * 2);      // 32 MB
    short*    featb   = (short*)alloc((size_t)N * 256 * 2);       // 4 MB
    short*    Wcomb   = (short*)alloc((size_t)2048 * 512 * 2);    // 2 MB
    short*    W2comb  = (short*)alloc((size_t)256 * 512 * 2);
    short*    Wtout   = (short*)alloc((size_t)128 * 512 * 2);
    float*    bias2c  = (float*)alloc((size_t)256 * 4);
    float*    wal1    = (float*)alloc((size_t)256 * 4 * 4);
    float*    war1    = (float*)alloc((size_t)256 * 4 * 4);
    float*    el1     = (float*)alloc((size_t)N * 4 * 4);
    float*    er1     = (float*)alloc((size_t)N * 4 * 4);
    int*      deg     = (int*)alloc((size_t)N * 4);               // deg+cur contiguous:
    int*      cur     = (int*)alloc((size_t)N * 4);               //   prep_all zeroes both
    int*      off     = (int*)alloc((size_t)(N + 1) * 4);
    int*      eid     = (int*)alloc((size_t)E * 4);
    short*    z2res   = (short*)alloc((size_t)N * 4 * 256 * 2);   // 16 MB
    short*    h2b     = (short*)alloc((size_t)N * 512 * 2);       // 8 MB
    float*    el2     = (float*)alloc((size_t)N * 16 * 4);
    float*    er2     = (float*)alloc((size_t)N * 16 * 4);

    dim3 blk(256);

    // ===== prep: fold1 + weight cvt + bias2c + zero(deg,cur) =====
    prep_all<<<dim3(1489), blk, 0, stream>>>(W1, al1, ar1, resW1, resW2, W2, Wout, b2,
                                             Wcomb, W2comb, Wtout,
                                             wal1, war1, bias2c, deg);

    // ===== front: feat cvt + el1/er1 + dst histogram (one dispatch) =====
    l1_front<<<dim3(N / 4 + E / 256), blk, 0, stream>>>(feat, (const float4*)wal1, (const float4*)war1,
                                                        featb, el1, er1, dst, deg, E, N / 4);
    scan_excl<<<dim3(1), dim3(1024), 0, stream>>>(deg, off, N);
    scatter_kernel<<<dim3((E + 255) / 256), blk, 0, stream>>>(dst, off, cur, eid, E);

    // ===== layer 1 =====
    aggregate_feat_sm<<<dim3(N / 4), blk, 0, stream>>>(off, eid, src, el1, er1, featb, Acomb);
    gemm_h1<<<dim3(4, N / 128, 4), blk, 0, stream>>>(Acomb, featb, Wcomb, b1, h1b);
    // h1b = bf16 h1 [N,4,512]

    // ===== layer 2 (GEMM with fused el2/er2 epilogue) =====
    gemm_bf16<<<dim3(2, (N * 4) / 128), blk, 0, stream>>>(h1b, W2comb, bias2c, z2res,
                                                          N * 4, 256, 512, 256, 256, 1,
                                                          el2, er2, al2, ar2, 1);
    aggregate2_sm<<<dim3(N), blk, 0, stream>>>(off, eid, src, el2, er2, z2res, h2b);
    // h2b = bf16 h2 [N,512]

    // ===== final linear =====
    gemm_bf16<<<dim3(1, N / 128), blk, 0, stream>>>(h2b, Wtout, bout, (float*)d_out,
                                                    N, 128, 512, 40, 40, 0,
                                                    nullptr, nullptr, nullptr, nullptr, 0);
}